// Round 15
// baseline (2594.297 us; speedup 1.0000x reference)
//
#include <hip/hip_runtime.h>

typedef __attribute__((ext_vector_type(8))) short bf16x8_t;
typedef __attribute__((ext_vector_type(4))) float f32x4_t;

__device__ __forceinline__ ushort f2bf(float x) {
  union { float f; unsigned u; } a; a.f = x;
  unsigned r = a.u + 0x7fffu + ((a.u >> 16) & 1u);
  return (ushort)(r >> 16);
}
__device__ __forceinline__ float bf2f(ushort s) {
  union { unsigned u; float f; } a; a.u = ((unsigned)s) << 16;
  return a.f;
}
__device__ __forceinline__ void gload_lds16(const void* g, void* l) {
  __builtin_amdgcn_global_load_lds(
      (const __attribute__((address_space(1))) unsigned int*)g,
      (__attribute__((address_space(3))) unsigned int*)l, 16, 0, 0);
}
__device__ __forceinline__ int swzkey(int r) { return ((r >> 2) ^ r) & 3; }

// ---------------- weight conversion ----------------
__global__ void cvt_kernel(const float* __restrict__ s, ushort* __restrict__ d, int n) {
  int i = blockIdx.x * 256 + threadIdx.x;
  if (i < n) d[i] = f2bf(s[i]);
}

// Wcat[l][r][c], r: 0-63 A_w, 64-127 B_w, 128-383 gate_w, 384-639 D_w
__global__ void build_wcat(const float* __restrict__ Aw, const float* __restrict__ Bw,
                           const float* __restrict__ gw, const float* __restrict__ Dw,
                           ushort* __restrict__ out) {
  int i = blockIdx.x * 256 + threadIdx.x;
  if (i >= 6 * 640 * 256) return;
  int l = i / (640 * 256), r = (i / 256) % 640, c = i % 256;
  float v;
  if (r < 64)        v = Aw[((l * 64 + r) * 256) + c];
  else if (r < 128)  v = Bw[((l * 64 + (r - 64)) * 256) + c];
  else if (r < 384)  v = gw[((l * 256 + (r - 128)) * 256) + c];
  else               v = Dw[((l * 256 + (r - 384)) * 256) + c];
  out[i] = f2bf(v);
}

// repack row-major [N][K] bf16 -> k-sliced [p][ks][r][s][e]; slice = 8KB contiguous.
__global__ void repack_gen(const ushort* __restrict__ src, ushort* __restrict__ dst,
                           int K, int perMat, int dstPerMat, int dstOff, long total) {
  const long i = (long)blockIdx.x * 256 + threadIdx.x;
  if (i >= total) return;
  const int m = (int)(i / perMat);
  const int idx = (int)(i % perMat);
  const int slice = idx >> 12;
  const int ksn = K >> 5;
  const int p = slice / ksn, ks = slice - p * ksn;
  const int r = (idx >> 5) & 127;
  const int s = (idx >> 3) & 3;
  const int e = idx & 7;
  const int k = ks * 32 + ((s ^ ((r >> 1) & 3)) << 3) + e;
  dst[(long)m * dstPerMat + dstOff + idx] = src[(long)m * perMat + (p * 128 + r) * K + k];
}

// ========== FUSED MAMBA LAYER v3: A-operand in registers, 30KB LDS, 5 blocks/CU ==========
__global__ __launch_bounds__(256, 5)
void mamba_fused(ushort* __restrict__ y, ushort* __restrict__ xP,
                 const ushort* __restrict__ Wk,
                 const float* __restrict__ gb, const float* __restrict__ db,
                 const float* __restrict__ lng, const float* __restrict__ lnb) {
  __shared__ __align__(16) char WsB[16384];
  __shared__ __align__(16) ushort ab[32 * 136];
  __shared__ __align__(16) char HsB[4096];
  __shared__ float lsum[32][2], lsq[32][2];

  const int t = threadIdx.x, lane = t & 63, wid = t >> 6;
  const long m0 = (long)blockIdx.x * 32;
  const int wr = (wid >> 1) * 16, wc = (wid & 1) * 64;
  const int co = wid * 2;
  const char* Wb = (const char*)Wk;

  const int krow = lane & 15, kslot = lane >> 4;
  const int ar = wr + krow;

  bf16x8_t afr[8];
  {
    const char* yrow = (const char*)y + (m0 + ar) * 512 + kslot * 16;
#pragma unroll
    for (int ks = 0; ks < 8; ++ks) afr[ks] = *(const bf16x8_t*)(yrow + ks * 64);
  }
  gload_lds16(Wb + co * 1024 + lane * 16, WsB + co * 1024);
  gload_lds16(Wb + (co + 1) * 1024 + lane * 16, WsB + (co + 1) * 1024);

  int boff[4];
#pragma unroll
  for (int i = 0; i < 4; ++i) {
    const int br = wc + i * 16 + krow;
    boff[i] = br * 64 + ((kslot ^ ((br >> 1) & 3)) << 4);
  }
  const int rbase = (lane >> 4) * 4, cbase = lane & 15;

  const f32x4_t zero = {0.f, 0.f, 0.f, 0.f};
  f32x4_t acc[4];
#pragma unroll
  for (int i = 0; i < 4; ++i) acc[i] = zero;

  int tau = 0;
  auto kstep = [&](bf16x8_t af) {
    __syncthreads();
    if (tau + 1 < 44) {
      const char* src = Wb + (long)(tau + 1) * 8192;
      char* dst = WsB + ((tau + 1) & 1) * 8192;
      gload_lds16(src + co * 1024 + lane * 16, dst + co * 1024);
      gload_lds16(src + (co + 1) * 1024 + lane * 16, dst + (co + 1) * 1024);
    }
    const char* Wc = WsB + (tau & 1) * 8192;
    bf16x8_t bv[4];
#pragma unroll
    for (int i = 0; i < 4; ++i) bv[i] = *(const bf16x8_t*)(Wc + boff[i]);
    __builtin_amdgcn_s_setprio(1);
#pragma unroll
    for (int ni = 0; ni < 4; ++ni)
      acc[ni] = __builtin_amdgcn_mfma_f32_16x16x32_bf16(af, bv[ni], acc[ni], 0, 0, 0);
    __builtin_amdgcn_s_setprio(0);
    ++tau;
  };

  // ---- phase AB ----
#pragma unroll
  for (int ks = 0; ks < 8; ++ks) kstep(afr[ks]);
#pragma unroll
  for (int ni = 0; ni < 4; ++ni) {
    const int col = wc + ni * 16 + cbase;
#pragma unroll
    for (int j = 0; j < 4; ++j) {
      const int row = wr + rbase + j;
      const float v = acc[ni][j];
      ab[row * 136 + col] = f2bf(col < 64 ? tanhf(v) : v);
    }
    acc[ni] = zero;
  }
  __syncthreads();
  // ---- scan ----
  if (t < 128) {
    const int b = t >> 6, d = t & 63;
    float av[16], btv[16];
#pragma unroll
    for (int s = 0; s < 16; ++s) {
      const int row = b * 16 + s;
      av[s]  = bf2f(ab[row * 136 + d]);
      btv[s] = bf2f(ab[row * 136 + 64 + d]);
    }
    float h = 0.f;
#pragma unroll
    for (int s = 0; s < 16; ++s) {
      h = fmaf(av[s], h, btv[s]);
      const int row = b * 16 + s;
      *(ushort*)(HsB + row * 128 + (((d >> 3) ^ (row & 7)) << 4) + (d & 7) * 2) = f2bf(h);
    }
  }

  f32x4_t gsv[2][4], dsv[2][4], xnv[2][4];
  // ---- phase G ----
#pragma unroll
  for (int pp = 0; pp < 2; ++pp) {
#pragma unroll
    for (int ks = 0; ks < 8; ++ks) kstep(afr[ks]);
#pragma unroll
    for (int ni = 0; ni < 4; ++ni) {
      const int col = pp * 128 + wc + ni * 16 + cbase;
#pragma unroll
      for (int j = 0; j < 4; ++j) {
        const float s = acc[ni][j] + gb[col];
        gsv[pp][ni][j] = 1.f / (1.f + expf(-s));
      }
      acc[ni] = zero;
    }
  }
  // ---- phase D ----
#pragma unroll
  for (int pp = 0; pp < 2; ++pp) {
#pragma unroll
    for (int ks = 0; ks < 8; ++ks) kstep(afr[ks]);
#pragma unroll
    for (int ni = 0; ni < 4; ++ni) {
      const int col = pp * 128 + wc + ni * 16 + cbase;
#pragma unroll
      for (int j = 0; j < 4; ++j) dsv[pp][ni][j] = acc[ni][j] + db[col];
      acc[ni] = zero;
    }
  }
  // ---- phase YS + combine ----
  const long rq16 = (m0 >> 4) + (wr >> 4);
#pragma unroll
  for (int pp = 0; pp < 2; ++pp) {
#pragma unroll
    for (int ks = 0; ks < 2; ++ks) {
      const bf16x8_t afh = *(const bf16x8_t*)(
          HsB + (ar << 7) + ((((ks << 2) | kslot) ^ (ar & 7)) << 4));
      kstep(afh);
    }
#pragma unroll
    for (int ni = 0; ni < 4; ++ni) {
      const int colq = pp * 8 + (wid & 1) * 4 + ni;
      const ushort4 x4 = *(const ushort4*)(xP + (rq16 * 16 + colq) * 256 + lane * 4);
#pragma unroll
      for (int j = 0; j < 4; ++j) {
        const float g = gsv[pp][ni][j], dv = dsv[pp][ni][j];
        const float xo = bf2f(j == 0 ? x4.x : (j == 1 ? x4.y : (j == 2 ? x4.z : x4.w)));
        xnv[pp][ni][j] = xo + acc[ni][j] * g + dv * (1.f - g);
      }
      acc[ni] = zero;
    }
  }
  // ---- LN stats ----
#pragma unroll
  for (int j = 0; j < 4; ++j) {
    float ps = 0.f, pq = 0.f;
#pragma unroll
    for (int pp = 0; pp < 2; ++pp)
#pragma unroll
      for (int ni = 0; ni < 4; ++ni) { const float v = xnv[pp][ni][j]; ps += v; pq += v * v; }
#pragma unroll
    for (int off = 1; off < 16; off <<= 1) {
      ps += __shfl_xor(ps, off, 64);
      pq += __shfl_xor(pq, off, 64);
    }
    if ((lane & 15) == 0) {
      const int row = wr + rbase + j;
      lsum[row][wid & 1] = ps;
      lsq[row][wid & 1] = pq;
    }
  }
  __syncthreads();
#pragma unroll
  for (int pp = 0; pp < 2; ++pp) {
#pragma unroll
    for (int ni = 0; ni < 4; ++ni) {
      const int colq = pp * 8 + (wid & 1) * 4 + ni;
      ushort4 o4;
      o4.x = f2bf(xnv[pp][ni][0]);
      o4.y = f2bf(xnv[pp][ni][1]);
      o4.z = f2bf(xnv[pp][ni][2]);
      o4.w = f2bf(xnv[pp][ni][3]);
      *(ushort4*)(xP + (rq16 * 16 + colq) * 256 + lane * 4) = o4;
    }
  }
#pragma unroll
  for (int j = 0; j < 4; ++j) {
    const int row = wr + rbase + j;
    const float sm = lsum[row][0] + lsum[row][1];
    const float q = lsq[row][0] + lsq[row][1];
    const float mean = sm * (1.f / 256.f);
    const float rstd = rsqrtf(q * (1.f / 256.f) - mean * mean + 1e-5f);
#pragma unroll
    for (int pp = 0; pp < 2; ++pp)
#pragma unroll
      for (int ni = 0; ni < 4; ++ni) {
        const int col = pp * 128 + wc + ni * 16 + cbase;
        *(ushort*)(WsB + row * 512 + col * 2) =
            f2bf((xnv[pp][ni][j] - mean) * rstd * lng[col] + lnb[col]);
      }
  }
  __syncthreads();
#pragma unroll
  for (int rr = 0; rr < 4; ++rr) {
    const int byte = rr * 4096 + t * 16;
    const int row = byte >> 9, off = byte & 511;
    const bf16x8_t v = *(const bf16x8_t*)(WsB + byte);
    *(bf16x8_t*)((char*)y + (m0 + row) * 512 + off) = v;
  }
}

// ========== gemm_ws: A-stationary GEMM, k-sliced W. MODE 2: gelu. MODE 3: relu. ==========
template <int NP, int MODE>
__global__ __launch_bounds__(256, 2)
void gemm_ws(const ushort* __restrict__ A, const ushort* __restrict__ Wks,
             const float* __restrict__ b1, ushort* __restrict__ outp) {
  constexpr int KS = 8;
  constexpr int N = NP * 128;
  constexpr int T = NP * KS;
  __shared__ __align__(16) char AsB[128 * 512];
  __shared__ __align__(16) char WsB[2 * 8192];

  const int t = threadIdx.x, lane = t & 63, wid = t >> 6;
  const long m0 = (long)blockIdx.x * 128;
  const int wr = (wid >> 1) * 64, wc = (wid & 1) * 64;
  const char* Ab = (const char*)A;
  const char* Wb = (const char*)Wks;

  {
    const int arow = lane >> 5;
    const int aps  = lane & 31;
#pragma unroll
    for (int j = 0; j < 16; ++j) {
      const int r = j * 8 + wid * 2 + arow;
      gload_lds16(Ab + (m0 + r) * 512 + (long)((aps ^ (r & 7)) << 4),
                  AsB + (j * 8 + wid * 2) * 512);
    }
  }
  {
    const int co = wid * 2;
    gload_lds16(Wb + co * 1024 + lane * 16, WsB + co * 1024);
    gload_lds16(Wb + (co + 1) * 1024 + lane * 16, WsB + (co + 1) * 1024);
  }

  const int krow = lane & 15, kslot = lane >> 4;
  int abase[4], akey[4], boff[4];
#pragma unroll
  for (int i = 0; i < 4; ++i) {
    const int ar = wr + i * 16 + krow;
    abase[i] = ar * 512;
    akey[i] = ar & 7;
    const int br = wc + i * 16 + krow;
    boff[i] = br * 64 + ((kslot ^ ((br >> 1) & 3)) << 4);
  }

  const f32x4_t zero = {0.f, 0.f, 0.f, 0.f};
  f32x4_t acc[4][4];
#pragma unroll
  for (int i = 0; i < 4; ++i)
#pragma unroll
    for (int j = 0; j < 4; ++j) acc[i][j] = zero;

  const int rbase = (lane >> 4) * 4, cbase = lane & 15;

  for (int tau = 0; tau < T; ++tau) {
    __syncthreads();
    if (tau + 1 < T) {
      const int co = wid * 2;
      char* dst = WsB + ((tau + 1) & 1) * 8192;
      const char* src = Wb + (long)(tau + 1) * 8192;
      gload_lds16(src + co * 1024 + lane * 16, dst + co * 1024);
      gload_lds16(src + (co + 1) * 1024 + lane * 16, dst + (co + 1) * 1024);
    }
    const int ks = tau & 7;
    const char* Wc = WsB + (tau & 1) * 8192;
    bf16x8_t af[4], bv[4];
#pragma unroll
    for (int i = 0; i < 4; ++i)
      af[i] = *(const bf16x8_t*)(AsB + abase[i] + ((((ks << 2) | kslot) ^ akey[i]) << 4));
#pragma unroll
    for (int i = 0; i < 4; ++i) bv[i] = *(const bf16x8_t*)(Wc + boff[i]);
    __builtin_amdgcn_s_setprio(1);
#pragma unroll
    for (int mi = 0; mi < 4; ++mi)
#pragma unroll
      for (int ni = 0; ni < 4; ++ni)
        acc[mi][ni] = __builtin_amdgcn_mfma_f32_16x16x32_bf16(af[mi], bv[ni], acc[mi][ni], 0, 0, 0);
    __builtin_amdgcn_s_setprio(0);

    if (ks == KS - 1) {
      const int np = tau >> 3;
#pragma unroll
      for (int mi = 0; mi < 4; ++mi) {
#pragma unroll
        for (int ni = 0; ni < 4; ++ni) {
          const int col = np * 128 + wc + ni * 16 + cbase;
#pragma unroll
          for (int j = 0; j < 4; ++j) {
            const long row = m0 + wr + mi * 16 + rbase + j;
            float s = acc[mi][ni][j] + b1[col];
            float o;
            if constexpr (MODE == 2) o = 0.5f * s * (1.f + erff(s * 0.70710678118654752f));
            else                     o = fmaxf(s, 0.f);
            outp[row * N + col] = f2bf(o);
          }
          acc[mi][ni] = zero;
        }
      }
    }
  }
}

// ========== G3: N=256 GEMM + fused residual + LayerNorm; x packed, y row-major ==========
// AFP32: A is fp32 (raw input data); staged via reg-convert + ds_write to swizzled slots.
template <int K, int MODE, bool AFP32>
__global__ __launch_bounds__(512)
void gemm_ln(const void* __restrict__ Ap, const ushort* __restrict__ W,
             const float* __restrict__ b1, ushort* __restrict__ xP,
             const float* __restrict__ lng, const float* __restrict__ lnb,
             ushort* __restrict__ y, int writex) {
  constexpr int KS = K / 32;
  __shared__ __align__(16) char WsB[2 * 16384];
  __shared__ __align__(16) char AsB[2 * 8192];
  __shared__ float lsum4[128][4], lsq4[128][4];

  const int t = threadIdx.x, lane = t & 63, wid = t >> 6;
  const int wr = (wid >> 2) * 64, wc = (wid & 3) * 64;
  const int lr = lane >> 2, lc = lane & 3;
  const int ra = wid * 16 + lr;
  const int slog = lc ^ swzkey(ra);
  const int saA = slog << 4;
  const int rw0 = wid * 32 + lr, rw1 = rw0 + 16;
  const int sw0 = (lc ^ swzkey(rw0)) << 4;
  const int sw1 = (lc ^ swzkey(rw1)) << 4;
  const char* Ab = (const char*)Ap;
  const char* Wb = (const char*)W;
  constexpr long K2 = (long)K * 2;
  const long m0 = (long)blockIdx.x * 128;

  auto stageA = [&](int tau2) {
    char* dst = AsB + (tau2 & 1) * 8192 + wid * 1024 + lane * 16;
    if constexpr (AFP32) {
      const float* src = (const float*)Ap + (m0 + ra) * K + tau2 * 32 + slog * 8;
      const float4 q0 = ((const float4*)src)[0];
      const float4 q1 = ((const float4*)src)[1];
      bf16x8_t v;
      v[0] = (short)f2bf(q0.x); v[1] = (short)f2bf(q0.y);
      v[2] = (short)f2bf(q0.z); v[3] = (short)f2bf(q0.w);
      v[4] = (short)f2bf(q1.x); v[5] = (short)f2bf(q1.y);
      v[6] = (short)f2bf(q1.z); v[7] = (short)f2bf(q1.w);
      *(bf16x8_t*)dst = v;
    } else {
      gload_lds16(Ab + (m0 + ra) * K2 + (long)tau2 * 64 + saA,
                  AsB + (tau2 & 1) * 8192 + wid * 1024);
    }
  };

  gload_lds16(Wb + (long)rw0 * K2 + sw0, WsB + wid * 2048);
  gload_lds16(Wb + (long)rw1 * K2 + sw1, WsB + wid * 2048 + 1024);
  stageA(0);

  const int krow = lane & 15, kslot = lane >> 4;
  int aoff[4], boff[4];
#pragma unroll
  for (int i = 0; i < 4; ++i) {
    int ar = wr + i * 16 + krow;
    aoff[i] = ar * 64 + ((kslot ^ swzkey(ar)) << 4);
    int br = wc + i * 16 + krow;
    boff[i] = br * 64 + ((kslot ^ swzkey(br)) << 4);
  }

  const f32x4_t zero = {0.f, 0.f, 0.f, 0.f};
  f32x4_t acc[4][4];
#pragma unroll
  for (int i = 0; i < 4; ++i)
#pragma unroll
    for (int j = 0; j < 4; ++j) acc[i][j] = zero;

  for (int tau = 0; tau < KS; ++tau) {
    __syncthreads();
    if (tau + 1 < KS) {
      stageA(tau + 1);
      const long kb = (long)(tau + 1) * 64;
      char* wd = WsB + ((tau + 1) & 1) * 16384 + wid * 2048;
      gload_lds16(Wb + (long)rw0 * K2 + kb + sw0, wd);
      gload_lds16(Wb + (long)rw1 * K2 + kb + sw1, wd + 1024);
    }
    const char* Ac = AsB + (tau & 1) * 8192;
    const char* Wc = WsB + (tau & 1) * 16384;
    bf16x8_t af[4], bv[4];
#pragma unroll
    for (int i = 0; i < 4; ++i) af[i] = *(const bf16x8_t*)(Ac + aoff[i]);
#pragma unroll
    for (int i = 0; i < 4; ++i) bv[i] = *(const bf16x8_t*)(Wc + boff[i]);
#pragma unroll
    for (int mi = 0; mi < 4; ++mi)
#pragma unroll
      for (int ni = 0; ni < 4; ++ni)
        acc[mi][ni] = __builtin_amdgcn_mfma_f32_16x16x32_bf16(af[mi], bv[ni], acc[mi][ni], 0, 0, 0);
  }

  const int rbase = (lane >> 4) * 4;
  const int cbase = lane & 15;
  const long xbB = (long)blockIdx.x * 32768;
#pragma unroll
  for (int mi = 0; mi < 4; ++mi) {
    const int rq = (wid >> 2) * 4 + mi;
#pragma unroll
    for (int ni = 0; ni < 4; ++ni) {
      const int col = wc + ni * 16 + cbase;
      const int cq = (wid & 3) * 4 + ni;
      ushort4 x4;
      if constexpr (MODE == 3) x4 = *(const ushort4*)(xP + xbB + ((rq * 16 + cq) * 64 + lane) * 4);
#pragma unroll
      for (int j = 0; j < 4; ++j) {
        float v = acc[mi][ni][j] + b1[col];
        if constexpr (MODE == 3)
          v += bf2f(j == 0 ? x4.x : (j == 1 ? x4.y : (j == 2 ? x4.z : x4.w)));
        acc[mi][ni][j] = v;
      }
    }
  }
#pragma unroll
  for (int mi = 0; mi < 4; ++mi) {
#pragma unroll
    for (int j = 0; j < 4; ++j) {
      float ps = 0.f, pq = 0.f;
#pragma unroll
      for (int ni = 0; ni < 4; ++ni) { float v = acc[mi][ni][j]; ps += v; pq += v * v; }
#pragma unroll
      for (int off = 1; off < 16; off <<= 1) {
        ps += __shfl_xor(ps, off, 64);
        pq += __shfl_xor(pq, off, 64);
      }
      if ((lane & 15) == 0) {
        int r = wr + mi * 16 + (lane >> 4) * 4 + j;
        lsum4[r][wid & 3] = ps;
        lsq4[r][wid & 3] = pq;
      }
    }
  }
  __syncthreads();
#pragma unroll
  for (int mi = 0; mi < 4; ++mi) {
    const int rq = (wid >> 2) * 4 + mi;
#pragma unroll
    for (int ni = 0; ni < 4; ++ni) {
      const int cq = (wid & 3) * 4 + ni;
      if (writex) {
        ushort4 o4;
        o4.x = f2bf(acc[mi][ni][0]);
        o4.y = f2bf(acc[mi][ni][1]);
        o4.z = f2bf(acc[mi][ni][2]);
        o4.w = f2bf(acc[mi][ni][3]);
        *(ushort4*)(xP + xbB + ((rq * 16 + cq) * 64 + lane) * 4) = o4;
      }
    }
  }
#pragma unroll
  for (int mi = 0; mi < 4; ++mi) {
#pragma unroll
    for (int j = 0; j < 4; ++j) {
      const int r = wr + mi * 16 + rbase + j;
      const float s = lsum4[r][0] + lsum4[r][1] + lsum4[r][2] + lsum4[r][3];
      const float q = lsq4[r][0] + lsq4[r][1] + lsq4[r][2] + lsq4[r][3];
      const float mean = s * (1.f / 256.f);
      const float rstd = rsqrtf(q * (1.f / 256.f) - mean * mean + 1e-5f);
      const long row = m0 + r;
#pragma unroll
      for (int ni = 0; ni < 4; ++ni) {
        const int col = wc + ni * 16 + cbase;
        y[row * 256 + col] = f2bf((acc[mi][ni][j] - mean) * rstd * lng[col] + lnb[col]);
      }
    }
  }
}

// ========== head_agg: per-batch neighbor attention; v = node + agg (bf16) ==========
__global__ __launch_bounds__(256)
void head_agg(const ushort* __restrict__ y, const float* __restrict__ attw,
              ushort* __restrict__ vb) {
  const int t = threadIdx.x, lane = t & 63, w = t >> 6;
  const long b = (long)blockIdx.x * 4 + w;
  const ushort* yb = y + b * 16 * 256;
  const float4 w2 = *(const float4*)(attw + 256 + lane * 4);

  float4 rows[16];
  float lg[16];
#pragma unroll
  for (int r = 0; r < 16; ++r) {
    const ushort4 u = *(const ushort4*)(yb + r * 256 + lane * 4);
    float4 v4;
    v4.x = bf2f(u.x); v4.y = bf2f(u.y); v4.z = bf2f(u.z); v4.w = bf2f(u.w);
    rows[r] = v4;
    if (r >= 1) {
      float s = v4.x * w2.x + v4.y * w2.y + v4.z * w2.z + v4.w * w2.w;
#pragma unroll
      for (int off = 32; off > 0; off >>= 1) s += __shfl_xor(s, off, 64);
      lg[r] = s;
    }
  }
  float mx = -1e30f;
#pragma unroll
  for (int r = 1; r < 16; ++r) mx = fmaxf(mx, lg[r]);
  float den = 0.f;
#pragma unroll
  for (int r = 1; r < 16; ++r) { lg[r] = expf(lg[r] - mx); den += lg[r]; }
  const float inv = 1.f / den;
  float4 v = rows[0];
#pragma unroll
  for (int r = 1; r < 16; ++r) {
    const float a = lg[r] * inv;
    v.x += a * rows[r].x; v.y += a * rows[r].y;
    v.z += a * rows[r].z; v.w += a * rows[r].w;
  }
  ushort4 o;
  o.x = f2bf(v.x); o.y = f2bf(v.y); o.z = f2bf(v.z); o.w = f2bf(v.w);
  *(ushort4*)(vb + b * 256 + lane * 4) = o;
}

// ========== head_cls: logits = o1 @ cls_w^T + cb; log_softmax ==========
__global__ __launch_bounds__(256)
void head_cls(const ushort* __restrict__ o1b, const float* __restrict__ cw,
              const float* __restrict__ cb, float* __restrict__ out) {
  __shared__ float lw[4][40];
  const int t = threadIdx.x, lane = t & 63, w = t >> 6;
  const long b = (long)blockIdx.x * 4 + w;
  const ushort2 u = *(const ushort2*)(o1b + b * 128 + lane * 2);
  const float o1x = bf2f(u.x), o1y = bf2f(u.y);

#pragma unroll
  for (int o = 0; o < 40; ++o) {
    const float2 c = *(const float2*)(cw + o * 128 + lane * 2);
    float p = o1x * c.x + o1y * c.y;
#pragma unroll
    for (int off = 32; off > 0; off >>= 1) p += __shfl_xor(p, off, 64);
    if (lane == 0) lw[w][o] = p + cb[o];
  }
  const float v = (lane < 40) ? lw[w][lane] : -1e30f;
  float mx = v;
#pragma unroll
  for (int off = 32; off > 0; off >>= 1) mx = fmaxf(mx, __shfl_xor(mx, off, 64));
  float e = (lane < 40) ? expf(v - mx) : 0.f;
  float den = e;
#pragma unroll
  for (int off = 32; off > 0; off >>= 1) den += __shfl_xor(den, off, 64);
  if (lane < 40) out[b * 40 + lane] = v - mx - logf(den);
}

// ---------------- host ----------------
extern "C" void kernel_launch(void* const* d_in, const int* in_sizes, int n_in,
                              void* d_out, int out_size, void* d_ws, size_t ws_size,
                              hipStream_t stream) {
  const float* data   = (const float*)d_in[0];
  const float* in_w   = (const float*)d_in[1];
  const float* in_b   = (const float*)d_in[2];
  const float* norm_g = (const float*)d_in[3];
  const float* norm_b = (const float*)d_in[4];
  const float* A_w    = (const float*)d_in[5];
  const float* B_w    = (const float*)d_in[6];
  const float* C_w    = (const float*)d_in[7];
  const float* D_w    = (const float*)d_in[8];
  const float* D_b    = (const float*)d_in[9];
  const float* gate_w = (const float*)d_in[10];
  const float* gate_b = (const float*)d_in[11];
  const float* ffn_w1 = (const float*)d_in[12];
  const float* ffn_b1 = (const float*)d_in[13];
  const float* ffn_w2 = (const float*)d_in[14];
  const float* ffn_b2 = (const float*)d_in[15];
  const float* fln_g  = (const float*)d_in[16];
  const float* fln_b  = (const float*)d_in[17];
  const float* out_w  = (const float*)d_in[18];
  const float* out_b  = (const float*)d_in[19];
  const float* cls_w  = (const float*)d_in[20];
  const float* cls_b  = (const float*)d_in[21];
  const float* attn_w = (const float*)d_in[22];
  const float* attn_b = (const float*)d_in[23];
  (void)in_sizes; (void)n_in; (void)out_size; (void)ws_size; (void)attn_b;

  char* ws = (char*)d_ws;
  ushort* xP     = (ushort*)(ws + 0);           // packed x
  ushort* y      = (ushort*)(ws + 67108864);    // row-major y
  ushort* tzp    = (ushort*)(ws + 134217728);   // t / vb+o1b (time-shared)
  ushort* wcat   = (ushort*)(ws + 318767104);
  ushort* inwb   = (ushort*)(ws + 320733184);
  ushort* w1b    = (ushort*)(ws + 320995328);
  ushort* w2b    = (ushort*)(ws + 322568192);
  ushort* cwb    = (ushort*)(ws + 324141056);
  ushort* mslice = (ushort*)(ws + 324337664);   // 6 layers x 44 slices x 4096 elems
  ushort* w1k    = (ushort*)(ws + 326500352);   // 6*512*256*2 (k-sliced)
  ushort* owb    = (ushort*)(ws + 328073216);   // out_w bf16 (128x256)
  ushort* owk    = (ushort*)(ws + 328138752);   // out_w k-sliced
  ushort* vb     = tzp;                         // 8192*256 bf16 (after t dead)
  ushort* o1b    = tzp + 2097152;               // 8192*128 bf16

  cvt_kernel<<<512, 256, 0, stream>>>(in_w, inwb, 131072);
  cvt_kernel<<<3072, 256, 0, stream>>>(ffn_w1, w1b, 786432);
  cvt_kernel<<<3072, 256, 0, stream>>>(ffn_w2, w2b, 786432);
  cvt_kernel<<<384, 256, 0, stream>>>(C_w, cwb, 98304);
  cvt_kernel<<<128, 256, 0, stream>>>(out_w, owb, 32768);
  build_wcat<<<3840, 256, 0, stream>>>(A_w, B_w, gate_w, D_w, wcat);
  repack_gen<<<3840, 256, 0, stream>>>(wcat, mslice, 256, 163840, 180224, 0, 6L * 163840);
  repack_gen<<<384, 256, 0, stream>>>(cwb, mslice, 64, 16384, 180224, 163840, 6L * 16384);
  repack_gen<<<3072, 256, 0, stream>>>(w1b, w1k, 256, 131072, 131072, 0, 6L * 131072);
  repack_gen<<<128, 256, 0, stream>>>(owb, owk, 256, 32768, 32768, 0, 32768);

  // input proj (fp32 A, fused convert) + fused LN(layer0): xP (packed), y
  gemm_ln<512, 0, true><<<dim3(1024), 512, 0, stream>>>(
      data, inwb, in_b, xP, norm_g, norm_b, y, 1);

  for (int l = 0; l < 6; ++l) {
    mamba_fused<<<4096, 256, 0, stream>>>(
        y, xP, mslice + (size_t)l * 180224,
        gate_b + l * 256, D_b + l * 256, norm_g + l * 256, norm_b + l * 256);
    gemm_ws<4, 2><<<1024, 256, 0, stream>>>(
        y, w1k + (size_t)l * 131072, ffn_b1 + l * 512, tzp);
    const float* lg2 = (l < 5) ? (norm_g + (l + 1) * 256) : fln_g;
    const float* lb2 = (l < 5) ? (norm_b + (l + 1) * 256) : fln_b;
    gemm_ln<512, 3, false><<<dim3(1024), 512, 0, stream>>>(
        tzp, w2b + (size_t)l * 256 * 512, ffn_b2 + l * 256, xP, lg2, lb2, y, (l < 5) ? 1 : 0);
  }

  // head: attention-agg -> out-proj GEMM (relu) -> cls + log_softmax
  head_agg<<<2048, 256, 0, stream>>>(y, attn_w, vb);
  gemm_ws<1, 3><<<64, 256, 0, stream>>>(vb, owk, out_b, o1b);
  head_cls<<<2048, 256, 0, stream>>>(o1b, cls_w, cls_b, (float*)d_out);
}

// Round 16
// 2202.557 us; speedup vs baseline: 1.1779x; 1.1779x over previous
//
#include <hip/hip_runtime.h>

typedef __attribute__((ext_vector_type(8))) short bf16x8_t;
typedef __attribute__((ext_vector_type(4))) float f32x4_t;

__device__ __forceinline__ ushort f2bf(float x) {
  union { float f; unsigned u; } a; a.f = x;
  unsigned r = a.u + 0x7fffu + ((a.u >> 16) & 1u);
  return (ushort)(r >> 16);
}
__device__ __forceinline__ float bf2f(ushort s) {
  union { unsigned u; float f; } a; a.u = ((unsigned)s) << 16;
  return a.f;
}
__device__ __forceinline__ void gload_lds16(const void* g, void* l) {
  __builtin_amdgcn_global_load_lds(
      (const __attribute__((address_space(1))) unsigned int*)g,
      (__attribute__((address_space(3))) unsigned int*)l, 16, 0, 0);
}
__device__ __forceinline__ int swzkey(int r) { return ((r >> 2) ^ r) & 3; }

// ---------------- weight conversion ----------------
__global__ void cvt_kernel(const float* __restrict__ s, ushort* __restrict__ d, int n) {
  int i = blockIdx.x * 256 + threadIdx.x;
  if (i < n) d[i] = f2bf(s[i]);
}

// Wcat[l][r][c], r: 0-63 A_w, 64-127 B_w, 128-383 gate_w, 384-639 D_w
__global__ void build_wcat(const float* __restrict__ Aw, const float* __restrict__ Bw,
                           const float* __restrict__ gw, const float* __restrict__ Dw,
                           ushort* __restrict__ out) {
  int i = blockIdx.x * 256 + threadIdx.x;
  if (i >= 6 * 640 * 256) return;
  int l = i / (640 * 256), r = (i / 256) % 640, c = i % 256;
  float v;
  if (r < 64)        v = Aw[((l * 64 + r) * 256) + c];
  else if (r < 128)  v = Bw[((l * 64 + (r - 64)) * 256) + c];
  else if (r < 384)  v = gw[((l * 256 + (r - 128)) * 256) + c];
  else               v = Dw[((l * 256 + (r - 384)) * 256) + c];
  out[i] = f2bf(v);
}

// repack row-major [N][K] bf16 -> k-sliced [p][ks][r][s][e]; slice = 8KB contiguous.
__global__ void repack_gen(const ushort* __restrict__ src, ushort* __restrict__ dst,
                           int K, int perMat, int dstPerMat, int dstOff, long total) {
  const long i = (long)blockIdx.x * 256 + threadIdx.x;
  if (i >= total) return;
  const int m = (int)(i / perMat);
  const int idx = (int)(i % perMat);
  const int slice = idx >> 12;
  const int ksn = K >> 5;
  const int p = slice / ksn, ks = slice - p * ksn;
  const int r = (idx >> 5) & 127;
  const int s = (idx >> 3) & 3;
  const int e = idx & 7;
  const int k = ks * 32 + ((s ^ ((r >> 1) & 3)) << 3) + e;
  dst[(long)m * dstPerMat + dstOff + idx] = src[(long)m * perMat + (p * 128 + r) * K + k];
}

// ========== FUSED MAMBA LAYER v3: A-operand in registers, 30KB LDS, 4 blocks/CU ==========
__global__ __launch_bounds__(256, 4)
void mamba_fused(ushort* __restrict__ y, ushort* __restrict__ xP,
                 const ushort* __restrict__ Wk,
                 const float* __restrict__ gb, const float* __restrict__ db,
                 const float* __restrict__ lng, const float* __restrict__ lnb) {
  __shared__ __align__(16) char WsB[16384];
  __shared__ __align__(16) ushort ab[32 * 136];
  __shared__ __align__(16) char HsB[4096];
  __shared__ float lsum[32][2], lsq[32][2];

  const int t = threadIdx.x, lane = t & 63, wid = t >> 6;
  const long m0 = (long)blockIdx.x * 32;
  const int wr = (wid >> 1) * 16, wc = (wid & 1) * 64;
  const int co = wid * 2;
  const char* Wb = (const char*)Wk;

  const int krow = lane & 15, kslot = lane >> 4;
  const int ar = wr + krow;

  bf16x8_t afr[8];
  {
    const char* yrow = (const char*)y + (m0 + ar) * 512 + kslot * 16;
#pragma unroll
    for (int ks = 0; ks < 8; ++ks) afr[ks] = *(const bf16x8_t*)(yrow + ks * 64);
  }
  gload_lds16(Wb + co * 1024 + lane * 16, WsB + co * 1024);
  gload_lds16(Wb + (co + 1) * 1024 + lane * 16, WsB + (co + 1) * 1024);

  int boff[4];
#pragma unroll
  for (int i = 0; i < 4; ++i) {
    const int br = wc + i * 16 + krow;
    boff[i] = br * 64 + ((kslot ^ ((br >> 1) & 3)) << 4);
  }
  const int rbase = (lane >> 4) * 4, cbase = lane & 15;

  const f32x4_t zero = {0.f, 0.f, 0.f, 0.f};
  f32x4_t acc[4];
#pragma unroll
  for (int i = 0; i < 4; ++i) acc[i] = zero;

  int tau = 0;
  auto kstep = [&](bf16x8_t af) {
    __syncthreads();
    if (tau + 1 < 44) {
      const char* src = Wb + (long)(tau + 1) * 8192;
      char* dst = WsB + ((tau + 1) & 1) * 8192;
      gload_lds16(src + co * 1024 + lane * 16, dst + co * 1024);
      gload_lds16(src + (co + 1) * 1024 + lane * 16, dst + (co + 1) * 1024);
    }
    const char* Wc = WsB + (tau & 1) * 8192;
    bf16x8_t bv[4];
#pragma unroll
    for (int i = 0; i < 4; ++i) bv[i] = *(const bf16x8_t*)(Wc + boff[i]);
    __builtin_amdgcn_s_setprio(1);
#pragma unroll
    for (int ni = 0; ni < 4; ++ni)
      acc[ni] = __builtin_amdgcn_mfma_f32_16x16x32_bf16(af, bv[ni], acc[ni], 0, 0, 0);
    __builtin_amdgcn_s_setprio(0);
    ++tau;
  };

  // ---- phase AB ----
#pragma unroll
  for (int ks = 0; ks < 8; ++ks) kstep(afr[ks]);
#pragma unroll
  for (int ni = 0; ni < 4; ++ni) {
    const int col = wc + ni * 16 + cbase;
#pragma unroll
    for (int j = 0; j < 4; ++j) {
      const int row = wr + rbase + j;
      const float v = acc[ni][j];
      ab[row * 136 + col] = f2bf(col < 64 ? tanhf(v) : v);
    }
    acc[ni] = zero;
  }
  __syncthreads();
  // ---- scan ----
  if (t < 128) {
    const int b = t >> 6, d = t & 63;
    float av[16], btv[16];
#pragma unroll
    for (int s = 0; s < 16; ++s) {
      const int row = b * 16 + s;
      av[s]  = bf2f(ab[row * 136 + d]);
      btv[s] = bf2f(ab[row * 136 + 64 + d]);
    }
    float h = 0.f;
#pragma unroll
    for (int s = 0; s < 16; ++s) {
      h = fmaf(av[s], h, btv[s]);
      const int row = b * 16 + s;
      *(ushort*)(HsB + row * 128 + (((d >> 3) ^ (row & 7)) << 4) + (d & 7) * 2) = f2bf(h);
    }
  }

  f32x4_t gsv[2][4], dsv[2][4], xnv[2][4];
  // ---- phase G ----
#pragma unroll
  for (int pp = 0; pp < 2; ++pp) {
#pragma unroll
    for (int ks = 0; ks < 8; ++ks) kstep(afr[ks]);
#pragma unroll
    for (int ni = 0; ni < 4; ++ni) {
      const int col = pp * 128 + wc + ni * 16 + cbase;
#pragma unroll
      for (int j = 0; j < 4; ++j) {
        const float s = acc[ni][j] + gb[col];
        gsv[pp][ni][j] = 1.f / (1.f + expf(-s));
      }
      acc[ni] = zero;
    }
  }
  // ---- phase D ----
#pragma unroll
  for (int pp = 0; pp < 2; ++pp) {
#pragma unroll
    for (int ks = 0; ks < 8; ++ks) kstep(afr[ks]);
#pragma unroll
    for (int ni = 0; ni < 4; ++ni) {
      const int col = pp * 128 + wc + ni * 16 + cbase;
#pragma unroll
      for (int j = 0; j < 4; ++j) dsv[pp][ni][j] = acc[ni][j] + db[col];
      acc[ni] = zero;
    }
  }
  // ---- phase YS + combine ----
  const long rq16 = (m0 >> 4) + (wr >> 4);
#pragma unroll
  for (int pp = 0; pp < 2; ++pp) {
#pragma unroll
    for (int ks = 0; ks < 2; ++ks) {
      const bf16x8_t afh = *(const bf16x8_t*)(
          HsB + (ar << 7) + ((((ks << 2) | kslot) ^ (ar & 7)) << 4));
      kstep(afh);
    }
#pragma unroll
    for (int ni = 0; ni < 4; ++ni) {
      const int colq = pp * 8 + (wid & 1) * 4 + ni;
      const ushort4 x4 = *(const ushort4*)(xP + (rq16 * 16 + colq) * 256 + lane * 4);
#pragma unroll
      for (int j = 0; j < 4; ++j) {
        const float g = gsv[pp][ni][j], dv = dsv[pp][ni][j];
        const float xo = bf2f(j == 0 ? x4.x : (j == 1 ? x4.y : (j == 2 ? x4.z : x4.w)));
        xnv[pp][ni][j] = xo + acc[ni][j] * g + dv * (1.f - g);
      }
      acc[ni] = zero;
    }
  }
  // ---- LN stats ----
#pragma unroll
  for (int j = 0; j < 4; ++j) {
    float ps = 0.f, pq = 0.f;
#pragma unroll
    for (int pp = 0; pp < 2; ++pp)
#pragma unroll
      for (int ni = 0; ni < 4; ++ni) { const float v = xnv[pp][ni][j]; ps += v; pq += v * v; }
#pragma unroll
    for (int off = 1; off < 16; off <<= 1) {
      ps += __shfl_xor(ps, off, 64);
      pq += __shfl_xor(pq, off, 64);
    }
    if ((lane & 15) == 0) {
      const int row = wr + rbase + j;
      lsum[row][wid & 1] = ps;
      lsq[row][wid & 1] = pq;
    }
  }
  __syncthreads();
#pragma unroll
  for (int pp = 0; pp < 2; ++pp) {
#pragma unroll
    for (int ni = 0; ni < 4; ++ni) {
      const int colq = pp * 8 + (wid & 1) * 4 + ni;
      ushort4 o4;
      o4.x = f2bf(xnv[pp][ni][0]);
      o4.y = f2bf(xnv[pp][ni][1]);
      o4.z = f2bf(xnv[pp][ni][2]);
      o4.w = f2bf(xnv[pp][ni][3]);
      *(ushort4*)(xP + (rq16 * 16 + colq) * 256 + lane * 4) = o4;
    }
  }
#pragma unroll
  for (int j = 0; j < 4; ++j) {
    const int row = wr + rbase + j;
    const float sm = lsum[row][0] + lsum[row][1];
    const float q = lsq[row][0] + lsq[row][1];
    const float mean = sm * (1.f / 256.f);
    const float rstd = rsqrtf(q * (1.f / 256.f) - mean * mean + 1e-5f);
#pragma unroll
    for (int pp = 0; pp < 2; ++pp)
#pragma unroll
      for (int ni = 0; ni < 4; ++ni) {
        const int col = pp * 128 + wc + ni * 16 + cbase;
        *(ushort*)(WsB + row * 512 + col * 2) =
            f2bf((xnv[pp][ni][j] - mean) * rstd * lng[col] + lnb[col]);
      }
  }
  __syncthreads();
#pragma unroll
  for (int rr = 0; rr < 4; ++rr) {
    const int byte = rr * 4096 + t * 16;
    const int row = byte >> 9, off = byte & 511;
    const bf16x8_t v = *(const bf16x8_t*)(WsB + byte);
    *(bf16x8_t*)((char*)y + (m0 + row) * 512 + off) = v;
  }
}

// ========== gemm_ws: A-stationary GEMM, k-sliced W. MODE 2: gelu. MODE 3: relu. ==========
template <int NP, int MODE>
__global__ __launch_bounds__(256, 2)
void gemm_ws(const ushort* __restrict__ A, const ushort* __restrict__ Wks,
             const float* __restrict__ b1, ushort* __restrict__ outp) {
  constexpr int KS = 8;
  constexpr int N = NP * 128;
  constexpr int T = NP * KS;
  __shared__ __align__(16) char AsB[128 * 512];
  __shared__ __align__(16) char WsB[2 * 8192];

  const int t = threadIdx.x, lane = t & 63, wid = t >> 6;
  const long m0 = (long)blockIdx.x * 128;
  const int wr = (wid >> 1) * 64, wc = (wid & 1) * 64;
  const char* Ab = (const char*)A;
  const char* Wb = (const char*)Wks;

  {
    const int arow = lane >> 5;
    const int aps  = lane & 31;
#pragma unroll
    for (int j = 0; j < 16; ++j) {
      const int r = j * 8 + wid * 2 + arow;
      gload_lds16(Ab + (m0 + r) * 512 + (long)((aps ^ (r & 7)) << 4),
                  AsB + (j * 8 + wid * 2) * 512);
    }
  }
  {
    const int co = wid * 2;
    gload_lds16(Wb + co * 1024 + lane * 16, WsB + co * 1024);
    gload_lds16(Wb + (co + 1) * 1024 + lane * 16, WsB + (co + 1) * 1024);
  }

  const int krow = lane & 15, kslot = lane >> 4;
  int abase[4], akey[4], boff[4];
#pragma unroll
  for (int i = 0; i < 4; ++i) {
    const int ar = wr + i * 16 + krow;
    abase[i] = ar * 512;
    akey[i] = ar & 7;
    const int br = wc + i * 16 + krow;
    boff[i] = br * 64 + ((kslot ^ ((br >> 1) & 3)) << 4);
  }

  const f32x4_t zero = {0.f, 0.f, 0.f, 0.f};
  f32x4_t acc[4][4];
#pragma unroll
  for (int i = 0; i < 4; ++i)
#pragma unroll
    for (int j = 0; j < 4; ++j) acc[i][j] = zero;

  const int rbase = (lane >> 4) * 4, cbase = lane & 15;

  for (int tau = 0; tau < T; ++tau) {
    __syncthreads();
    if (tau + 1 < T) {
      const int co = wid * 2;
      char* dst = WsB + ((tau + 1) & 1) * 8192;
      const char* src = Wb + (long)(tau + 1) * 8192;
      gload_lds16(src + co * 1024 + lane * 16, dst + co * 1024);
      gload_lds16(src + (co + 1) * 1024 + lane * 16, dst + (co + 1) * 1024);
    }
    const int ks = tau & 7;
    const char* Wc = WsB + (tau & 1) * 8192;
    bf16x8_t af[4], bv[4];
#pragma unroll
    for (int i = 0; i < 4; ++i)
      af[i] = *(const bf16x8_t*)(AsB + abase[i] + ((((ks << 2) | kslot) ^ akey[i]) << 4));
#pragma unroll
    for (int i = 0; i < 4; ++i) bv[i] = *(const bf16x8_t*)(Wc + boff[i]);
    __builtin_amdgcn_s_setprio(1);
#pragma unroll
    for (int mi = 0; mi < 4; ++mi)
#pragma unroll
      for (int ni = 0; ni < 4; ++ni)
        acc[mi][ni] = __builtin_amdgcn_mfma_f32_16x16x32_bf16(af[mi], bv[ni], acc[mi][ni], 0, 0, 0);
    __builtin_amdgcn_s_setprio(0);

    if (ks == KS - 1) {
      const int np = tau >> 3;
#pragma unroll
      for (int mi = 0; mi < 4; ++mi) {
#pragma unroll
        for (int ni = 0; ni < 4; ++ni) {
          const int col = np * 128 + wc + ni * 16 + cbase;
#pragma unroll
          for (int j = 0; j < 4; ++j) {
            const long row = m0 + wr + mi * 16 + rbase + j;
            float s = acc[mi][ni][j] + b1[col];
            float o;
            if constexpr (MODE == 2) o = 0.5f * s * (1.f + erff(s * 0.70710678118654752f));
            else                     o = fmaxf(s, 0.f);
            outp[row * N + col] = f2bf(o);
          }
          acc[mi][ni] = zero;
        }
      }
    }
  }
}

// ========== G3: N=256 GEMM + fused residual + LayerNorm; x packed, y row-major ==========
// AFP32: A is fp32 (raw input data); staged via reg-convert + ds_write to swizzled slots.
template <int K, int MODE, bool AFP32>
__global__ __launch_bounds__(512)
void gemm_ln(const void* __restrict__ Ap, const ushort* __restrict__ W,
             const float* __restrict__ b1, ushort* __restrict__ xP,
             const float* __restrict__ lng, const float* __restrict__ lnb,
             ushort* __restrict__ y, int writex) {
  constexpr int KS = K / 32;
  __shared__ __align__(16) char WsB[2 * 16384];
  __shared__ __align__(16) char AsB[2 * 8192];
  __shared__ float lsum4[128][4], lsq4[128][4];

  const int t = threadIdx.x, lane = t & 63, wid = t >> 6;
  const int wr = (wid >> 2) * 64, wc = (wid & 3) * 64;
  const int lr = lane >> 2, lc = lane & 3;
  const int ra = wid * 16 + lr;
  const int slog = lc ^ swzkey(ra);
  const int saA = slog << 4;
  const int rw0 = wid * 32 + lr, rw1 = rw0 + 16;
  const int sw0 = (lc ^ swzkey(rw0)) << 4;
  const int sw1 = (lc ^ swzkey(rw1)) << 4;
  const char* Ab = (const char*)Ap;
  const char* Wb = (const char*)W;
  constexpr long K2 = (long)K * 2;
  const long m0 = (long)blockIdx.x * 128;

  auto stageA = [&](int tau2) {
    char* dst = AsB + (tau2 & 1) * 8192 + wid * 1024 + lane * 16;
    if constexpr (AFP32) {
      const float* src = (const float*)Ap + (m0 + ra) * K + tau2 * 32 + slog * 8;
      const float4 q0 = ((const float4*)src)[0];
      const float4 q1 = ((const float4*)src)[1];
      bf16x8_t v;
      v[0] = (short)f2bf(q0.x); v[1] = (short)f2bf(q0.y);
      v[2] = (short)f2bf(q0.z); v[3] = (short)f2bf(q0.w);
      v[4] = (short)f2bf(q1.x); v[5] = (short)f2bf(q1.y);
      v[6] = (short)f2bf(q1.z); v[7] = (short)f2bf(q1.w);
      *(bf16x8_t*)dst = v;
    } else {
      gload_lds16(Ab + (m0 + ra) * K2 + (long)tau2 * 64 + saA,
                  AsB + (tau2 & 1) * 8192 + wid * 1024);
    }
  };

  gload_lds16(Wb + (long)rw0 * K2 + sw0, WsB + wid * 2048);
  gload_lds16(Wb + (long)rw1 * K2 + sw1, WsB + wid * 2048 + 1024);
  stageA(0);

  const int krow = lane & 15, kslot = lane >> 4;
  int aoff[4], boff[4];
#pragma unroll
  for (int i = 0; i < 4; ++i) {
    int ar = wr + i * 16 + krow;
    aoff[i] = ar * 64 + ((kslot ^ swzkey(ar)) << 4);
    int br = wc + i * 16 + krow;
    boff[i] = br * 64 + ((kslot ^ swzkey(br)) << 4);
  }

  const f32x4_t zero = {0.f, 0.f, 0.f, 0.f};
  f32x4_t acc[4][4];
#pragma unroll
  for (int i = 0; i < 4; ++i)
#pragma unroll
    for (int j = 0; j < 4; ++j) acc[i][j] = zero;

  for (int tau = 0; tau < KS; ++tau) {
    __syncthreads();
    if (tau + 1 < KS) {
      stageA(tau + 1);
      const long kb = (long)(tau + 1) * 64;
      char* wd = WsB + ((tau + 1) & 1) * 16384 + wid * 2048;
      gload_lds16(Wb + (long)rw0 * K2 + kb + sw0, wd);
      gload_lds16(Wb + (long)rw1 * K2 + kb + sw1, wd + 1024);
    }
    const char* Ac = AsB + (tau & 1) * 8192;
    const char* Wc = WsB + (tau & 1) * 16384;
    bf16x8_t af[4], bv[4];
#pragma unroll
    for (int i = 0; i < 4; ++i) af[i] = *(const bf16x8_t*)(Ac + aoff[i]);
#pragma unroll
    for (int i = 0; i < 4; ++i) bv[i] = *(const bf16x8_t*)(Wc + boff[i]);
#pragma unroll
    for (int mi = 0; mi < 4; ++mi)
#pragma unroll
      for (int ni = 0; ni < 4; ++ni)
        acc[mi][ni] = __builtin_amdgcn_mfma_f32_16x16x32_bf16(af[mi], bv[ni], acc[mi][ni], 0, 0, 0);
  }

  const int rbase = (lane >> 4) * 4;
  const int cbase = lane & 15;
  const long xbB = (long)blockIdx.x * 32768;
#pragma unroll
  for (int mi = 0; mi < 4; ++mi) {
    const int rq = (wid >> 2) * 4 + mi;
#pragma unroll
    for (int ni = 0; ni < 4; ++ni) {
      const int col = wc + ni * 16 + cbase;
      const int cq = (wid & 3) * 4 + ni;
      ushort4 x4;
      if constexpr (MODE == 3) x4 = *(const ushort4*)(xP + xbB + ((rq * 16 + cq) * 64 + lane) * 4);
#pragma unroll
      for (int j = 0; j < 4; ++j) {
        float v = acc[mi][ni][j] + b1[col];
        if constexpr (MODE == 3)
          v += bf2f(j == 0 ? x4.x : (j == 1 ? x4.y : (j == 2 ? x4.z : x4.w)));
        acc[mi][ni][j] = v;
      }
    }
  }
#pragma unroll
  for (int mi = 0; mi < 4; ++mi) {
#pragma unroll
    for (int j = 0; j < 4; ++j) {
      float ps = 0.f, pq = 0.f;
#pragma unroll
      for (int ni = 0; ni < 4; ++ni) { float v = acc[mi][ni][j]; ps += v; pq += v * v; }
#pragma unroll
      for (int off = 1; off < 16; off <<= 1) {
        ps += __shfl_xor(ps, off, 64);
        pq += __shfl_xor(pq, off, 64);
      }
      if ((lane & 15) == 0) {
        int r = wr + mi * 16 + (lane >> 4) * 4 + j;
        lsum4[r][wid & 3] = ps;
        lsq4[r][wid & 3] = pq;
      }
    }
  }
  __syncthreads();
#pragma unroll
  for (int mi = 0; mi < 4; ++mi) {
    const int rq = (wid >> 2) * 4 + mi;
#pragma unroll
    for (int ni = 0; ni < 4; ++ni) {
      const int cq = (wid & 3) * 4 + ni;
      if (writex) {
        ushort4 o4;
        o4.x = f2bf(acc[mi][ni][0]);
        o4.y = f2bf(acc[mi][ni][1]);
        o4.z = f2bf(acc[mi][ni][2]);
        o4.w = f2bf(acc[mi][ni][3]);
        *(ushort4*)(xP + xbB + ((rq * 16 + cq) * 64 + lane) * 4) = o4;
      }
    }
  }
#pragma unroll
  for (int mi = 0; mi < 4; ++mi) {
#pragma unroll
    for (int j = 0; j < 4; ++j) {
      const int r = wr + mi * 16 + rbase + j;
      const float s = lsum4[r][0] + lsum4[r][1] + lsum4[r][2] + lsum4[r][3];
      const float q = lsq4[r][0] + lsq4[r][1] + lsq4[r][2] + lsq4[r][3];
      const float mean = s * (1.f / 256.f);
      const float rstd = rsqrtf(q * (1.f / 256.f) - mean * mean + 1e-5f);
      const long row = m0 + r;
#pragma unroll
      for (int ni = 0; ni < 4; ++ni) {
        const int col = wc + ni * 16 + cbase;
        y[row * 256 + col] = f2bf((acc[mi][ni][j] - mean) * rstd * lng[col] + lnb[col]);
      }
    }
  }
}

// ========== head_agg: per-batch neighbor attention; v = node + agg (bf16) ==========
__global__ __launch_bounds__(256)
void head_agg(const ushort* __restrict__ y, const float* __restrict__ attw,
              ushort* __restrict__ vb) {
  const int t = threadIdx.x, lane = t & 63, w = t >> 6;
  const long b = (long)blockIdx.x * 4 + w;
  const ushort* yb = y + b * 16 * 256;
  const float4 w2 = *(const float4*)(attw + 256 + lane * 4);

  float4 rows[16];
  float lg[16];
#pragma unroll
  for (int r = 0; r < 16; ++r) {
    const ushort4 u = *(const ushort4*)(yb + r * 256 + lane * 4);
    float4 v4;
    v4.x = bf2f(u.x); v4.y = bf2f(u.y); v4.z = bf2f(u.z); v4.w = bf2f(u.w);
    rows[r] = v4;
    if (r >= 1) {
      float s = v4.x * w2.x + v4.y * w2.y + v4.z * w2.z + v4.w * w2.w;
#pragma unroll
      for (int off = 32; off > 0; off >>= 1) s += __shfl_xor(s, off, 64);
      lg[r] = s;
    }
  }
  float mx = -1e30f;
#pragma unroll
  for (int r = 1; r < 16; ++r) mx = fmaxf(mx, lg[r]);
  float den = 0.f;
#pragma unroll
  for (int r = 1; r < 16; ++r) { lg[r] = expf(lg[r] - mx); den += lg[r]; }
  const float inv = 1.f / den;
  float4 v = rows[0];
#pragma unroll
  for (int r = 1; r < 16; ++r) {
    const float a = lg[r] * inv;
    v.x += a * rows[r].x; v.y += a * rows[r].y;
    v.z += a * rows[r].z; v.w += a * rows[r].w;
  }
  ushort4 o;
  o.x = f2bf(v.x); o.y = f2bf(v.y); o.z = f2bf(v.z); o.w = f2bf(v.w);
  *(ushort4*)(vb + b * 256 + lane * 4) = o;
}

// ========== head_cls: logits = o1 @ cls_w^T + cb; log_softmax ==========
__global__ __launch_bounds__(256)
void head_cls(const ushort* __restrict__ o1b, const float* __restrict__ cw,
              const float* __restrict__ cb, float* __restrict__ out) {
  __shared__ float lw[4][40];
  const int t = threadIdx.x, lane = t & 63, w = t >> 6;
  const long b = (long)blockIdx.x * 4 + w;
  const ushort2 u = *(const ushort2*)(o1b + b * 128 + lane * 2);
  const float o1x = bf2f(u.x), o1y = bf2f(u.y);

#pragma unroll
  for (int o = 0; o < 40; ++o) {
    const float2 c = *(const float2*)(cw + o * 128 + lane * 2);
    float p = o1x * c.x + o1y * c.y;
#pragma unroll
    for (int off = 32; off > 0; off >>= 1) p += __shfl_xor(p, off, 64);
    if (lane == 0) lw[w][o] = p + cb[o];
  }
  const float v = (lane < 40) ? lw[w][lane] : -1e30f;
  float mx = v;
#pragma unroll
  for (int off = 32; off > 0; off >>= 1) mx = fmaxf(mx, __shfl_xor(mx, off, 64));
  float e = (lane < 40) ? expf(v - mx) : 0.f;
  float den = e;
#pragma unroll
  for (int off = 32; off > 0; off >>= 1) den += __shfl_xor(den, off, 64);
  if (lane < 40) out[b * 40 + lane] = v - mx - logf(den);
}

// ---------------- host ----------------
extern "C" void kernel_launch(void* const* d_in, const int* in_sizes, int n_in,
                              void* d_out, int out_size, void* d_ws, size_t ws_size,
                              hipStream_t stream) {
  const float* data   = (const float*)d_in[0];
  const float* in_w   = (const float*)d_in[1];
  const float* in_b   = (const float*)d_in[2];
  const float* norm_g = (const float*)d_in[3];
  const float* norm_b = (const float*)d_in[4];
  const float* A_w    = (const float*)d_in[5];
  const float* B_w    = (const float*)d_in[6];
  const float* C_w    = (const float*)d_in[7];
  const float* D_w    = (const float*)d_in[8];
  const float* D_b    = (const float*)d_in[9];
  const float* gate_w = (const float*)d_in[10];
  const float* gate_b = (const float*)d_in[11];
  const float* ffn_w1 = (const float*)d_in[12];
  const float* ffn_b1 = (const float*)d_in[13];
  const float* ffn_w2 = (const float*)d_in[14];
  const float* ffn_b2 = (const float*)d_in[15];
  const float* fln_g  = (const float*)d_in[16];
  const float* fln_b  = (const float*)d_in[17];
  const float* out_w  = (const float*)d_in[18];
  const float* out_b  = (const float*)d_in[19];
  const float* cls_w  = (const float*)d_in[20];
  const float* cls_b  = (const float*)d_in[21];
  const float* attn_w = (const float*)d_in[22];
  const float* attn_b = (const float*)d_in[23];
  (void)in_sizes; (void)n_in; (void)out_size; (void)ws_size; (void)attn_b;

  char* ws = (char*)d_ws;
  ushort* xP     = (ushort*)(ws + 0);           // packed x
  ushort* y      = (ushort*)(ws + 67108864);    // row-major y
  ushort* tzp    = (ushort*)(ws + 134217728);   // t / vb+o1b (time-shared)
  ushort* wcat   = (ushort*)(ws + 318767104);
  ushort* inwb   = (ushort*)(ws + 320733184);
  ushort* w1b    = (ushort*)(ws + 320995328);
  ushort* w2b    = (ushort*)(ws + 322568192);
  ushort* cwb    = (ushort*)(ws + 324141056);
  ushort* mslice = (ushort*)(ws + 324337664);   // 6 layers x 44 slices x 4096 elems
  ushort* w1k    = (ushort*)(ws + 326500352);   // 6*512*256*2 (k-sliced)
  ushort* owb    = (ushort*)(ws + 328073216);   // out_w bf16 (128x256)
  ushort* owk    = (ushort*)(ws + 328138752);   // out_w k-sliced
  ushort* vb     = tzp;                         // 8192*256 bf16 (after t dead)
  ushort* o1b    = tzp + 2097152;               // 8192*128 bf16

  cvt_kernel<<<512, 256, 0, stream>>>(in_w, inwb, 131072);
  cvt_kernel<<<3072, 256, 0, stream>>>(ffn_w1, w1b, 786432);
  cvt_kernel<<<3072, 256, 0, stream>>>(ffn_w2, w2b, 786432);
  cvt_kernel<<<384, 256, 0, stream>>>(C_w, cwb, 98304);
  cvt_kernel<<<128, 256, 0, stream>>>(out_w, owb, 32768);
  build_wcat<<<3840, 256, 0, stream>>>(A_w, B_w, gate_w, D_w, wcat);
  repack_gen<<<3840, 256, 0, stream>>>(wcat, mslice, 256, 163840, 180224, 0, 6L * 163840);
  repack_gen<<<384, 256, 0, stream>>>(cwb, mslice, 64, 16384, 180224, 163840, 6L * 16384);
  repack_gen<<<3072, 256, 0, stream>>>(w1b, w1k, 256, 131072, 131072, 0, 6L * 131072);
  repack_gen<<<128, 256, 0, stream>>>(owb, owk, 256, 32768, 32768, 0, 32768);

  // input proj (fp32 A, fused convert) + fused LN(layer0): xP (packed), y
  gemm_ln<512, 0, true><<<dim3(1024), 512, 0, stream>>>(
      data, inwb, in_b, xP, norm_g, norm_b, y, 1);

  for (int l = 0; l < 6; ++l) {
    mamba_fused<<<4096, 256, 0, stream>>>(
        y, xP, mslice + (size_t)l * 180224,
        gate_b + l * 256, D_b + l * 256, norm_g + l * 256, norm_b + l * 256);
    gemm_ws<4, 2><<<1024, 256, 0, stream>>>(
        y, w1k + (size_t)l * 131072, ffn_b1 + l * 512, tzp);
    const float* lg2 = (l < 5) ? (norm_g + (l + 1) * 256) : fln_g;
    const float* lb2 = (l < 5) ? (norm_b + (l + 1) * 256) : fln_b;
    gemm_ln<512, 3, false><<<dim3(1024), 512, 0, stream>>>(
        tzp, w2b + (size_t)l * 256 * 512, ffn_b2 + l * 256, xP, lg2, lb2, y, (l < 5) ? 1 : 0);
  }

  // head: attention-agg -> out-proj GEMM (relu) -> cls + log_softmax
  head_agg<<<2048, 256, 0, stream>>>(y, attn_w, vb);
  gemm_ws<1, 3><<<64, 256, 0, stream>>>(vb, owk, out_b, o1b);
  head_cls<<<2048, 256, 0, stream>>>(o1b, cls_w, cls_b, (float*)d_out);
}

// Round 17
// 2124.639 us; speedup vs baseline: 1.2211x; 1.0367x over previous
//
#include <hip/hip_runtime.h>

typedef __attribute__((ext_vector_type(8))) short bf16x8_t;
typedef __attribute__((ext_vector_type(4))) float f32x4_t;

__device__ __forceinline__ ushort f2bf(float x) {
  union { float f; unsigned u; } a; a.f = x;
  unsigned r = a.u + 0x7fffu + ((a.u >> 16) & 1u);
  return (ushort)(r >> 16);
}
__device__ __forceinline__ float bf2f(ushort s) {
  union { unsigned u; float f; } a; a.u = ((unsigned)s) << 16;
  return a.f;
}
__device__ __forceinline__ void gload_lds16(const void* g, void* l) {
  __builtin_amdgcn_global_load_lds(
      (const __attribute__((address_space(1))) unsigned int*)g,
      (__attribute__((address_space(3))) unsigned int*)l, 16, 0, 0);
}
__device__ __forceinline__ int swzkey(int r) { return ((r >> 2) ^ r) & 3; }

// ---------------- weight conversion ----------------
__global__ void cvt_kernel(const float* __restrict__ s, ushort* __restrict__ d, int n) {
  int i = blockIdx.x * 256 + threadIdx.x;
  if (i < n) d[i] = f2bf(s[i]);
}

// Wcat[l][r][c], r: 0-63 A_w, 64-127 B_w, 128-383 gate_w, 384-639 D_w
__global__ void build_wcat(const float* __restrict__ Aw, const float* __restrict__ Bw,
                           const float* __restrict__ gw, const float* __restrict__ Dw,
                           ushort* __restrict__ out) {
  int i = blockIdx.x * 256 + threadIdx.x;
  if (i >= 6 * 640 * 256) return;
  int l = i / (640 * 256), r = (i / 256) % 640, c = i % 256;
  float v;
  if (r < 64)        v = Aw[((l * 64 + r) * 256) + c];
  else if (r < 128)  v = Bw[((l * 64 + (r - 64)) * 256) + c];
  else if (r < 384)  v = gw[((l * 256 + (r - 128)) * 256) + c];
  else               v = Dw[((l * 256 + (r - 384)) * 256) + c];
  out[i] = f2bf(v);
}

// repack row-major [N][K] bf16 -> k-sliced [p][ks][r][s][e]; slice = 8KB contiguous.
__global__ void repack_gen(const ushort* __restrict__ src, ushort* __restrict__ dst,
                           int K, int perMat, int dstPerMat, int dstOff, long total) {
  const long i = (long)blockIdx.x * 256 + threadIdx.x;
  if (i >= total) return;
  const int m = (int)(i / perMat);
  const int idx = (int)(i % perMat);
  const int slice = idx >> 12;
  const int ksn = K >> 5;
  const int p = slice / ksn, ks = slice - p * ksn;
  const int r = (idx >> 5) & 127;
  const int s = (idx >> 3) & 3;
  const int e = idx & 7;
  const int k = ks * 32 + ((s ^ ((r >> 1) & 3)) << 3) + e;
  dst[(long)m * dstPerMat + dstOff + idx] = src[(long)m * perMat + (p * 128 + r) * K + k];
}

// ========== FUSED MAMBA LAYER v4: A in registers; DOUBLE-SLICE steps (22 barriers) ==========
__global__ __launch_bounds__(256, 3)
void mamba_fused(ushort* __restrict__ y, ushort* __restrict__ xP,
                 const ushort* __restrict__ Wk,
                 const float* __restrict__ gb, const float* __restrict__ db,
                 const float* __restrict__ lng, const float* __restrict__ lnb) {
  __shared__ __align__(16) char WsB[2 * 16384];  // double-buffered 16KB slice-pairs
  __shared__ __align__(16) ushort ab[32 * 136];
  __shared__ __align__(16) char HsB[4096];
  __shared__ float lsum[32][2], lsq[32][2];

  const int t = threadIdx.x, lane = t & 63, wid = t >> 6;
  const long m0 = (long)blockIdx.x * 32;
  const int wr = (wid >> 1) * 16, wc = (wid & 1) * 64;
  const int co4 = wid * 4;                       // 4 x 1KB chunks per wave per pair
  const char* Wb = (const char*)Wk;

  const int krow = lane & 15, kslot = lane >> 4;
  const int ar = wr + krow;

  bf16x8_t afr[8];
  {
    const char* yrow = (const char*)y + (m0 + ar) * 512 + kslot * 16;
#pragma unroll
    for (int ks = 0; ks < 8; ++ks) afr[ks] = *(const bf16x8_t*)(yrow + ks * 64);
  }
  // stage pair 0 into buf 0
#pragma unroll
  for (int c = 0; c < 4; ++c)
    gload_lds16(Wb + (co4 + c) * 1024 + lane * 16, WsB + (co4 + c) * 1024);

  int boff[4];
#pragma unroll
  for (int i = 0; i < 4; ++i) {
    const int br = wc + i * 16 + krow;
    boff[i] = br * 64 + ((kslot ^ ((br >> 1) & 3)) << 4);
  }
  const int rbase = (lane >> 4) * 4, cbase = lane & 15;

  const f32x4_t zero = {0.f, 0.f, 0.f, 0.f};
  f32x4_t acc[4];
#pragma unroll
  for (int i = 0; i < 4; ++i) acc[i] = zero;

  int pair = 0;
  auto kstep2 = [&](bf16x8_t afa, bf16x8_t afb) {
    __syncthreads();
    if (pair + 1 < 22) {
      const char* src = Wb + (long)(pair + 1) * 16384;
      char* dst = WsB + ((pair + 1) & 1) * 16384;
#pragma unroll
      for (int c = 0; c < 4; ++c)
        gload_lds16(src + (co4 + c) * 1024 + lane * 16, dst + (co4 + c) * 1024);
    }
    const char* Wc = WsB + (pair & 1) * 16384;
    bf16x8_t bva[4], bvb[4];
#pragma unroll
    for (int i = 0; i < 4; ++i) bva[i] = *(const bf16x8_t*)(Wc + boff[i]);
#pragma unroll
    for (int i = 0; i < 4; ++i) bvb[i] = *(const bf16x8_t*)(Wc + 8192 + boff[i]);
    __builtin_amdgcn_s_setprio(1);
#pragma unroll
    for (int ni = 0; ni < 4; ++ni)
      acc[ni] = __builtin_amdgcn_mfma_f32_16x16x32_bf16(afa, bva[ni], acc[ni], 0, 0, 0);
#pragma unroll
    for (int ni = 0; ni < 4; ++ni)
      acc[ni] = __builtin_amdgcn_mfma_f32_16x16x32_bf16(afb, bvb[ni], acc[ni], 0, 0, 0);
    __builtin_amdgcn_s_setprio(0);
    ++pair;
  };

  // ---- phase AB: pairs 0..3 ----
#pragma unroll
  for (int p = 0; p < 4; ++p) kstep2(afr[2 * p], afr[2 * p + 1]);
#pragma unroll
  for (int ni = 0; ni < 4; ++ni) {
    const int col = wc + ni * 16 + cbase;
#pragma unroll
    for (int j = 0; j < 4; ++j) {
      const int row = wr + rbase + j;
      const float v = acc[ni][j];
      ab[row * 136 + col] = f2bf(col < 64 ? tanhf(v) : v);
    }
    acc[ni] = zero;
  }
  __syncthreads();
  // ---- scan ----
  if (t < 128) {
    const int b = t >> 6, d = t & 63;
    float av[16], btv[16];
#pragma unroll
    for (int s = 0; s < 16; ++s) {
      const int row = b * 16 + s;
      av[s]  = bf2f(ab[row * 136 + d]);
      btv[s] = bf2f(ab[row * 136 + 64 + d]);
    }
    float h = 0.f;
#pragma unroll
    for (int s = 0; s < 16; ++s) {
      h = fmaf(av[s], h, btv[s]);
      const int row = b * 16 + s;
      *(ushort*)(HsB + row * 128 + (((d >> 3) ^ (row & 7)) << 4) + (d & 7) * 2) = f2bf(h);
    }
  }

  f32x4_t gsv[2][4], dsv[2][4], xnv[2][4];
  // ---- phase G: pairs 4..11 ----
#pragma unroll
  for (int pp = 0; pp < 2; ++pp) {
#pragma unroll
    for (int p = 0; p < 4; ++p) kstep2(afr[2 * p], afr[2 * p + 1]);
#pragma unroll
    for (int ni = 0; ni < 4; ++ni) {
      const int col = pp * 128 + wc + ni * 16 + cbase;
#pragma unroll
      for (int j = 0; j < 4; ++j) {
        const float s = acc[ni][j] + gb[col];
        gsv[pp][ni][j] = 1.f / (1.f + expf(-s));
      }
      acc[ni] = zero;
    }
  }
  // ---- phase D: pairs 12..19 ----
#pragma unroll
  for (int pp = 0; pp < 2; ++pp) {
#pragma unroll
    for (int p = 0; p < 4; ++p) kstep2(afr[2 * p], afr[2 * p + 1]);
#pragma unroll
    for (int ni = 0; ni < 4; ++ni) {
      const int col = pp * 128 + wc + ni * 16 + cbase;
#pragma unroll
      for (int j = 0; j < 4; ++j) dsv[pp][ni][j] = acc[ni][j] + db[col];
      acc[ni] = zero;
    }
  }
  // ---- phase YS: pairs 20..21 (one pair = both ks of one panel) ----
  const long rq16 = (m0 >> 4) + (wr >> 4);
#pragma unroll
  for (int pp = 0; pp < 2; ++pp) {
    const bf16x8_t afh0 = *(const bf16x8_t*)(
        HsB + (ar << 7) + ((kslot ^ (ar & 7)) << 4));
    const bf16x8_t afh1 = *(const bf16x8_t*)(
        HsB + (ar << 7) + (((4 | kslot) ^ (ar & 7)) << 4));
    kstep2(afh0, afh1);
#pragma unroll
    for (int ni = 0; ni < 4; ++ni) {
      const int colq = pp * 8 + (wid & 1) * 4 + ni;
      const ushort4 x4 = *(const ushort4*)(xP + (rq16 * 16 + colq) * 256 + lane * 4);
#pragma unroll
      for (int j = 0; j < 4; ++j) {
        const float g = gsv[pp][ni][j], dv = dsv[pp][ni][j];
        const float xo = bf2f(j == 0 ? x4.x : (j == 1 ? x4.y : (j == 2 ? x4.z : x4.w)));
        xnv[pp][ni][j] = xo + acc[ni][j] * g + dv * (1.f - g);
      }
      acc[ni] = zero;
    }
  }
  // ---- LN stats ----
#pragma unroll
  for (int j = 0; j < 4; ++j) {
    float ps = 0.f, pq = 0.f;
#pragma unroll
    for (int pp = 0; pp < 2; ++pp)
#pragma unroll
      for (int ni = 0; ni < 4; ++ni) { const float v = xnv[pp][ni][j]; ps += v; pq += v * v; }
#pragma unroll
    for (int off = 1; off < 16; off <<= 1) {
      ps += __shfl_xor(ps, off, 64);
      pq += __shfl_xor(pq, off, 64);
    }
    if ((lane & 15) == 0) {
      const int row = wr + rbase + j;
      lsum[row][wid & 1] = ps;
      lsq[row][wid & 1] = pq;
    }
  }
  __syncthreads();
#pragma unroll
  for (int pp = 0; pp < 2; ++pp) {
#pragma unroll
    for (int ni = 0; ni < 4; ++ni) {
      const int colq = pp * 8 + (wid & 1) * 4 + ni;
      ushort4 o4;
      o4.x = f2bf(xnv[pp][ni][0]);
      o4.y = f2bf(xnv[pp][ni][1]);
      o4.z = f2bf(xnv[pp][ni][2]);
      o4.w = f2bf(xnv[pp][ni][3]);
      *(ushort4*)(xP + (rq16 * 16 + colq) * 256 + lane * 4) = o4;
    }
  }
#pragma unroll
  for (int j = 0; j < 4; ++j) {
    const int row = wr + rbase + j;
    const float sm = lsum[row][0] + lsum[row][1];
    const float q = lsq[row][0] + lsq[row][1];
    const float mean = sm * (1.f / 256.f);
    const float rstd = rsqrtf(q * (1.f / 256.f) - mean * mean + 1e-5f);
#pragma unroll
    for (int pp = 0; pp < 2; ++pp)
#pragma unroll
      for (int ni = 0; ni < 4; ++ni) {
        const int col = pp * 128 + wc + ni * 16 + cbase;
        *(ushort*)(WsB + row * 512 + col * 2) =
            f2bf((xnv[pp][ni][j] - mean) * rstd * lng[col] + lnb[col]);
      }
  }
  __syncthreads();
#pragma unroll
  for (int rr = 0; rr < 4; ++rr) {
    const int byte = rr * 4096 + t * 16;
    const int row = byte >> 9, off = byte & 511;
    const bf16x8_t v = *(const bf16x8_t*)(WsB + byte);
    *(bf16x8_t*)((char*)y + (m0 + row) * 512 + off) = v;
  }
}

// ========== gemm_ws: A-stationary GEMM, k-sliced W. MODE 2: gelu. MODE 3: relu. ==========
template <int NP, int MODE>
__global__ __launch_bounds__(256, 2)
void gemm_ws(const ushort* __restrict__ A, const ushort* __restrict__ Wks,
             const float* __restrict__ b1, ushort* __restrict__ outp) {
  constexpr int KS = 8;
  constexpr int N = NP * 128;
  constexpr int T = NP * KS;
  __shared__ __align__(16) char AsB[128 * 512];
  __shared__ __align__(16) char WsB[2 * 8192];

  const int t = threadIdx.x, lane = t & 63, wid = t >> 6;
  const long m0 = (long)blockIdx.x * 128;
  const int wr = (wid >> 1) * 64, wc = (wid & 1) * 64;
  const char* Ab = (const char*)A;
  const char* Wb = (const char*)Wks;

  {
    const int arow = lane >> 5;
    const int aps  = lane & 31;
#pragma unroll
    for (int j = 0; j < 16; ++j) {
      const int r = j * 8 + wid * 2 + arow;
      gload_lds16(Ab + (m0 + r) * 512 + (long)((aps ^ (r & 7)) << 4),
                  AsB + (j * 8 + wid * 2) * 512);
    }
  }
  {
    const int co = wid * 2;
    gload_lds16(Wb + co * 1024 + lane * 16, WsB + co * 1024);
    gload_lds16(Wb + (co + 1) * 1024 + lane * 16, WsB + (co + 1) * 1024);
  }

  const int krow = lane & 15, kslot = lane >> 4;
  int abase[4], akey[4], boff[4];
#pragma unroll
  for (int i = 0; i < 4; ++i) {
    const int ar = wr + i * 16 + krow;
    abase[i] = ar * 512;
    akey[i] = ar & 7;
    const int br = wc + i * 16 + krow;
    boff[i] = br * 64 + ((kslot ^ ((br >> 1) & 3)) << 4);
  }

  const f32x4_t zero = {0.f, 0.f, 0.f, 0.f};
  f32x4_t acc[4][4];
#pragma unroll
  for (int i = 0; i < 4; ++i)
#pragma unroll
    for (int j = 0; j < 4; ++j) acc[i][j] = zero;

  const int rbase = (lane >> 4) * 4, cbase = lane & 15;

  for (int tau = 0; tau < T; ++tau) {
    __syncthreads();
    if (tau + 1 < T) {
      const int co = wid * 2;
      char* dst = WsB + ((tau + 1) & 1) * 8192;
      const char* src = Wb + (long)(tau + 1) * 8192;
      gload_lds16(src + co * 1024 + lane * 16, dst + co * 1024);
      gload_lds16(src + (co + 1) * 1024 + lane * 16, dst + (co + 1) * 1024);
    }
    const int ks = tau & 7;
    const char* Wc = WsB + (tau & 1) * 8192;
    bf16x8_t af[4], bv[4];
#pragma unroll
    for (int i = 0; i < 4; ++i)
      af[i] = *(const bf16x8_t*)(AsB + abase[i] + ((((ks << 2) | kslot) ^ akey[i]) << 4));
#pragma unroll
    for (int i = 0; i < 4; ++i) bv[i] = *(const bf16x8_t*)(Wc + boff[i]);
    __builtin_amdgcn_s_setprio(1);
#pragma unroll
    for (int mi = 0; mi < 4; ++mi)
#pragma unroll
      for (int ni = 0; ni < 4; ++ni)
        acc[mi][ni] = __builtin_amdgcn_mfma_f32_16x16x32_bf16(af[mi], bv[ni], acc[mi][ni], 0, 0, 0);
    __builtin_amdgcn_s_setprio(0);

    if (ks == KS - 1) {
      const int np = tau >> 3;
#pragma unroll
      for (int mi = 0; mi < 4; ++mi) {
#pragma unroll
        for (int ni = 0; ni < 4; ++ni) {
          const int col = np * 128 + wc + ni * 16 + cbase;
#pragma unroll
          for (int j = 0; j < 4; ++j) {
            const long row = m0 + wr + mi * 16 + rbase + j;
            float s = acc[mi][ni][j] + b1[col];
            float o;
            if constexpr (MODE == 2) o = 0.5f * s * (1.f + erff(s * 0.70710678118654752f));
            else                     o = fmaxf(s, 0.f);
            outp[row * N + col] = f2bf(o);
          }
          acc[mi][ni] = zero;
        }
      }
    }
  }
}

// ========== G3: N=256 GEMM + fused residual + LayerNorm; x packed, y row-major ==========
// AFP32: A is fp32 (raw input data); staged via reg-convert + ds_write to swizzled slots.
template <int K, int MODE, bool AFP32>
__global__ __launch_bounds__(512)
void gemm_ln(const void* __restrict__ Ap, const ushort* __restrict__ W,
             const float* __restrict__ b1, ushort* __restrict__ xP,
             const float* __restrict__ lng, const float* __restrict__ lnb,
             ushort* __restrict__ y, int writex) {
  constexpr int KS = K / 32;
  __shared__ __align__(16) char WsB[2 * 16384];
  __shared__ __align__(16) char AsB[2 * 8192];
  __shared__ float lsum4[128][4], lsq4[128][4];

  const int t = threadIdx.x, lane = t & 63, wid = t >> 6;
  const int wr = (wid >> 2) * 64, wc = (wid & 3) * 64;
  const int lr = lane >> 2, lc = lane & 3;
  const int ra = wid * 16 + lr;
  const int slog = lc ^ swzkey(ra);
  const int saA = slog << 4;
  const int rw0 = wid * 32 + lr, rw1 = rw0 + 16;
  const int sw0 = (lc ^ swzkey(rw0)) << 4;
  const int sw1 = (lc ^ swzkey(rw1)) << 4;
  const char* Ab = (const char*)Ap;
  const char* Wb = (const char*)W;
  constexpr long K2 = (long)K * 2;
  const long m0 = (long)blockIdx.x * 128;

  auto stageA = [&](int tau2) {
    char* dst = AsB + (tau2 & 1) * 8192 + wid * 1024 + lane * 16;
    if constexpr (AFP32) {
      const float* src = (const float*)Ap + (m0 + ra) * K + tau2 * 32 + slog * 8;
      const float4 q0 = ((const float4*)src)[0];
      const float4 q1 = ((const float4*)src)[1];
      bf16x8_t v;
      v[0] = (short)f2bf(q0.x); v[1] = (short)f2bf(q0.y);
      v[2] = (short)f2bf(q0.z); v[3] = (short)f2bf(q0.w);
      v[4] = (short)f2bf(q1.x); v[5] = (short)f2bf(q1.y);
      v[6] = (short)f2bf(q1.z); v[7] = (short)f2bf(q1.w);
      *(bf16x8_t*)dst = v;
    } else {
      gload_lds16(Ab + (m0 + ra) * K2 + (long)tau2 * 64 + saA,
                  AsB + (tau2 & 1) * 8192 + wid * 1024);
    }
  };

  gload_lds16(Wb + (long)rw0 * K2 + sw0, WsB + wid * 2048);
  gload_lds16(Wb + (long)rw1 * K2 + sw1, WsB + wid * 2048 + 1024);
  stageA(0);

  const int krow = lane & 15, kslot = lane >> 4;
  int aoff[4], boff[4];
#pragma unroll
  for (int i = 0; i < 4; ++i) {
    int ar = wr + i * 16 + krow;
    aoff[i] = ar * 64 + ((kslot ^ swzkey(ar)) << 4);
    int br = wc + i * 16 + krow;
    boff[i] = br * 64 + ((kslot ^ swzkey(br)) << 4);
  }

  const f32x4_t zero = {0.f, 0.f, 0.f, 0.f};
  f32x4_t acc[4][4];
#pragma unroll
  for (int i = 0; i < 4; ++i)
#pragma unroll
    for (int j = 0; j < 4; ++j) acc[i][j] = zero;

  for (int tau = 0; tau < KS; ++tau) {
    __syncthreads();
    if (tau + 1 < KS) {
      stageA(tau + 1);
      const long kb = (long)(tau + 1) * 64;
      char* wd = WsB + ((tau + 1) & 1) * 16384 + wid * 2048;
      gload_lds16(Wb + (long)rw0 * K2 + kb + sw0, wd);
      gload_lds16(Wb + (long)rw1 * K2 + kb + sw1, wd + 1024);
    }
    const char* Ac = AsB + (tau & 1) * 8192;
    const char* Wc = WsB + (tau & 1) * 16384;
    bf16x8_t af[4], bv[4];
#pragma unroll
    for (int i = 0; i < 4; ++i) af[i] = *(const bf16x8_t*)(Ac + aoff[i]);
#pragma unroll
    for (int i = 0; i < 4; ++i) bv[i] = *(const bf16x8_t*)(Wc + boff[i]);
#pragma unroll
    for (int mi = 0; mi < 4; ++mi)
#pragma unroll
      for (int ni = 0; ni < 4; ++ni)
        acc[mi][ni] = __builtin_amdgcn_mfma_f32_16x16x32_bf16(af[mi], bv[ni], acc[mi][ni], 0, 0, 0);
  }

  const int rbase = (lane >> 4) * 4;
  const int cbase = lane & 15;
  const long xbB = (long)blockIdx.x * 32768;
#pragma unroll
  for (int mi = 0; mi < 4; ++mi) {
    const int rq = (wid >> 2) * 4 + mi;
#pragma unroll
    for (int ni = 0; ni < 4; ++ni) {
      const int col = wc + ni * 16 + cbase;
      const int cq = (wid & 3) * 4 + ni;
      ushort4 x4;
      if constexpr (MODE == 3) x4 = *(const ushort4*)(xP + xbB + ((rq * 16 + cq) * 64 + lane) * 4);
#pragma unroll
      for (int j = 0; j < 4; ++j) {
        float v = acc[mi][ni][j] + b1[col];
        if constexpr (MODE == 3)
          v += bf2f(j == 0 ? x4.x : (j == 1 ? x4.y : (j == 2 ? x4.z : x4.w)));
        acc[mi][ni][j] = v;
      }
    }
  }
#pragma unroll
  for (int mi = 0; mi < 4; ++mi) {
#pragma unroll
    for (int j = 0; j < 4; ++j) {
      float ps = 0.f, pq = 0.f;
#pragma unroll
      for (int ni = 0; ni < 4; ++ni) { float v = acc[mi][ni][j]; ps += v; pq += v * v; }
#pragma unroll
      for (int off = 1; off < 16; off <<= 1) {
        ps += __shfl_xor(ps, off, 64);
        pq += __shfl_xor(pq, off, 64);
      }
      if ((lane & 15) == 0) {
        int r = wr + mi * 16 + (lane >> 4) * 4 + j;
        lsum4[r][wid & 3] = ps;
        lsq4[r][wid & 3] = pq;
      }
    }
  }
  __syncthreads();
#pragma unroll
  for (int mi = 0; mi < 4; ++mi) {
    const int rq = (wid >> 2) * 4 + mi;
#pragma unroll
    for (int ni = 0; ni < 4; ++ni) {
      const int cq = (wid & 3) * 4 + ni;
      if (writex) {
        ushort4 o4;
        o4.x = f2bf(acc[mi][ni][0]);
        o4.y = f2bf(acc[mi][ni][1]);
        o4.z = f2bf(acc[mi][ni][2]);
        o4.w = f2bf(acc[mi][ni][3]);
        *(ushort4*)(xP + xbB + ((rq * 16 + cq) * 64 + lane) * 4) = o4;
      }
    }
  }
#pragma unroll
  for (int mi = 0; mi < 4; ++mi) {
#pragma unroll
    for (int j = 0; j < 4; ++j) {
      const int r = wr + mi * 16 + rbase + j;
      const float s = lsum4[r][0] + lsum4[r][1] + lsum4[r][2] + lsum4[r][3];
      const float q = lsq4[r][0] + lsq4[r][1] + lsq4[r][2] + lsq4[r][3];
      const float mean = s * (1.f / 256.f);
      const float rstd = rsqrtf(q * (1.f / 256.f) - mean * mean + 1e-5f);
      const long row = m0 + r;
#pragma unroll
      for (int ni = 0; ni < 4; ++ni) {
        const int col = wc + ni * 16 + cbase;
        y[row * 256 + col] = f2bf((acc[mi][ni][j] - mean) * rstd * lng[col] + lnb[col]);
      }
    }
  }
}

// ========== head_agg: per-batch neighbor attention; v = node + agg (bf16) ==========
__global__ __launch_bounds__(256)
void head_agg(const ushort* __restrict__ y, const float* __restrict__ attw,
              ushort* __restrict__ vb) {
  const int t = threadIdx.x, lane = t & 63, w = t >> 6;
  const long b = (long)blockIdx.x * 4 + w;
  const ushort* yb = y + b * 16 * 256;
  const float4 w2 = *(const float4*)(attw + 256 + lane * 4);

  float4 rows[16];
  float lg[16];
#pragma unroll
  for (int r = 0; r < 16; ++r) {
    const ushort4 u = *(const ushort4*)(yb + r * 256 + lane * 4);
    float4 v4;
    v4.x = bf2f(u.x); v4.y = bf2f(u.y); v4.z = bf2f(u.z); v4.w = bf2f(u.w);
    rows[r] = v4;
    if (r >= 1) {
      float s = v4.x * w2.x + v4.y * w2.y + v4.z * w2.z + v4.w * w2.w;
#pragma unroll
      for (int off = 32; off > 0; off >>= 1) s += __shfl_xor(s, off, 64);
      lg[r] = s;
    }
  }
  float mx = -1e30f;
#pragma unroll
  for (int r = 1; r < 16; ++r) mx = fmaxf(mx, lg[r]);
  float den = 0.f;
#pragma unroll
  for (int r = 1; r < 16; ++r) { lg[r] = expf(lg[r] - mx); den += lg[r]; }
  const float inv = 1.f / den;
  float4 v = rows[0];
#pragma unroll
  for (int r = 1; r < 16; ++r) {
    const float a = lg[r] * inv;
    v.x += a * rows[r].x; v.y += a * rows[r].y;
    v.z += a * rows[r].z; v.w += a * rows[r].w;
  }
  ushort4 o;
  o.x = f2bf(v.x); o.y = f2bf(v.y); o.z = f2bf(v.z); o.w = f2bf(v.w);
  *(ushort4*)(vb + b * 256 + lane * 4) = o;
}

// ========== head_cls: logits = o1 @ cls_w^T + cb; log_softmax ==========
__global__ __launch_bounds__(256)
void head_cls(const ushort* __restrict__ o1b, const float* __restrict__ cw,
              const float* __restrict__ cb, float* __restrict__ out) {
  __shared__ float lw[4][40];
  const int t = threadIdx.x, lane = t & 63, w = t >> 6;
  const long b = (long)blockIdx.x * 4 + w;
  const ushort2 u = *(const ushort2*)(o1b + b * 128 + lane * 2);
  const float o1x = bf2f(u.x), o1y = bf2f(u.y);

#pragma unroll
  for (int o = 0; o < 40; ++o) {
    const float2 c = *(const float2*)(cw + o * 128 + lane * 2);
    float p = o1x * c.x + o1y * c.y;
#pragma unroll
    for (int off = 32; off > 0; off >>= 1) p += __shfl_xor(p, off, 64);
    if (lane == 0) lw[w][o] = p + cb[o];
  }
  const float v = (lane < 40) ? lw[w][lane] : -1e30f;
  float mx = v;
#pragma unroll
  for (int off = 32; off > 0; off >>= 1) mx = fmaxf(mx, __shfl_xor(mx, off, 64));
  float e = (lane < 40) ? expf(v - mx) : 0.f;
  float den = e;
#pragma unroll
  for (int off = 32; off > 0; off >>= 1) den += __shfl_xor(den, off, 64);
  if (lane < 40) out[b * 40 + lane] = v - mx - logf(den);
}

// ---------------- host ----------------
extern "C" void kernel_launch(void* const* d_in, const int* in_sizes, int n_in,
                              void* d_out, int out_size, void* d_ws, size_t ws_size,
                              hipStream_t stream) {
  const float* data   = (const float*)d_in[0];
  const float* in_w   = (const float*)d_in[1];
  const float* in_b   = (const float*)d_in[2];
  const float* norm_g = (const float*)d_in[3];
  const float* norm_b = (const float*)d_in[4];
  const float* A_w    = (const float*)d_in[5];
  const float* B_w    = (const float*)d_in[6];
  const float* C_w    = (const float*)d_in[7];
  const float* D_w    = (const float*)d_in[8];
  const float* D_b    = (const float*)d_in[9];
  const float* gate_w = (const float*)d_in[10];
  const float* gate_b = (const float*)d_in[11];
  const float* ffn_w1 = (const float*)d_in[12];
  const float* ffn_b1 = (const float*)d_in[13];
  const float* ffn_w2 = (const float*)d_in[14];
  const float* ffn_b2 = (const float*)d_in[15];
  const float* fln_g  = (const float*)d_in[16];
  const float* fln_b  = (const float*)d_in[17];
  const float* out_w  = (const float*)d_in[18];
  const float* out_b  = (const float*)d_in[19];
  const float* cls_w  = (const float*)d_in[20];
  const float* cls_b  = (const float*)d_in[21];
  const float* attn_w = (const float*)d_in[22];
  const float* attn_b = (const float*)d_in[23];
  (void)in_sizes; (void)n_in; (void)out_size; (void)ws_size; (void)attn_b;

  char* ws = (char*)d_ws;
  ushort* xP     = (ushort*)(ws + 0);           // packed x
  ushort* y      = (ushort*)(ws + 67108864);    // row-major y
  ushort* tzp    = (ushort*)(ws + 134217728);   // t / vb+o1b (time-shared)
  ushort* wcat   = (ushort*)(ws + 318767104);
  ushort* inwb   = (ushort*)(ws + 320733184);
  ushort* w1b    = (ushort*)(ws + 320995328);
  ushort* w2b    = (ushort*)(ws + 322568192);
  ushort* cwb    = (ushort*)(ws + 324141056);
  ushort* mslice = (ushort*)(ws + 324337664);   // 6 layers x 44 slices x 4096 elems
  ushort* w1k    = (ushort*)(ws + 326500352);   // 6*512*256*2 (k-sliced)
  ushort* owb    = (ushort*)(ws + 328073216);   // out_w bf16 (128x256)
  ushort* owk    = (ushort*)(ws + 328138752);   // out_w k-sliced
  ushort* vb     = tzp;                         // 8192*256 bf16 (after t dead)
  ushort* o1b    = tzp + 2097152;               // 8192*128 bf16

  cvt_kernel<<<512, 256, 0, stream>>>(in_w, inwb, 131072);
  cvt_kernel<<<3072, 256, 0, stream>>>(ffn_w1, w1b, 786432);
  cvt_kernel<<<3072, 256, 0, stream>>>(ffn_w2, w2b, 786432);
  cvt_kernel<<<384, 256, 0, stream>>>(C_w, cwb, 98304);
  cvt_kernel<<<128, 256, 0, stream>>>(out_w, owb, 32768);
  build_wcat<<<3840, 256, 0, stream>>>(A_w, B_w, gate_w, D_w, wcat);
  repack_gen<<<3840, 256, 0, stream>>>(wcat, mslice, 256, 163840, 180224, 0, 6L * 163840);
  repack_gen<<<384, 256, 0, stream>>>(cwb, mslice, 64, 16384, 180224, 163840, 6L * 16384);
  repack_gen<<<3072, 256, 0, stream>>>(w1b, w1k, 256, 131072, 131072, 0, 6L * 131072);
  repack_gen<<<128, 256, 0, stream>>>(owb, owk, 256, 32768, 32768, 0, 32768);

  // input proj (fp32 A, fused convert) + fused LN(layer0): xP (packed), y
  gemm_ln<512, 0, true><<<dim3(1024), 512, 0, stream>>>(
      data, inwb, in_b, xP, norm_g, norm_b, y, 1);

  for (int l = 0; l < 6; ++l) {
    mamba_fused<<<4096, 256, 0, stream>>>(
        y, xP, mslice + (size_t)l * 180224,
        gate_b + l * 256, D_b + l * 256, norm_g + l * 256, norm_b + l * 256);
    gemm_ws<4, 2><<<1024, 256, 0, stream>>>(
        y, w1k + (size_t)l * 131072, ffn_b1 + l * 512, tzp);
    const float* lg2 = (l < 5) ? (norm_g + (l + 1) * 256) : fln_g;
    const float* lb2 = (l < 5) ? (norm_b + (l + 1) * 256) : fln_b;
    gemm_ln<512, 3, false><<<dim3(1024), 512, 0, stream>>>(
        tzp, w2b + (size_t)l * 256 * 512, ffn_b2 + l * 256, xP, lg2, lb2, y, (l < 5) ? 1 : 0);
  }

  // head: attention-agg -> out-proj GEMM (relu) -> cls + log_softmax
  head_agg<<<2048, 256, 0, stream>>>(y, attn_w, vb);
  gemm_ws<1, 3><<<64, 256, 0, stream>>>(vb, owk, out_b, o1b);
  head_cls<<<2048, 256, 0, stream>>>(o1b, cls_w, cls_b, (float*)d_out);
}

// Round 18
// 2110.197 us; speedup vs baseline: 1.2294x; 1.0068x over previous
//
#include <hip/hip_runtime.h>

typedef __attribute__((ext_vector_type(8))) short bf16x8_t;
typedef __attribute__((ext_vector_type(4))) float f32x4_t;

__device__ __forceinline__ ushort f2bf(float x) {
  union { float f; unsigned u; } a; a.f = x;
  unsigned r = a.u + 0x7fffu + ((a.u >> 16) & 1u);
  return (ushort)(r >> 16);
}
__device__ __forceinline__ float bf2f(ushort s) {
  union { unsigned u; float f; } a; a.u = ((unsigned)s) << 16;
  return a.f;
}
__device__ __forceinline__ void gload_lds16(const void* g, void* l) {
  __builtin_amdgcn_global_load_lds(
      (const __attribute__((address_space(1))) unsigned int*)g,
      (__attribute__((address_space(3))) unsigned int*)l, 16, 0, 0);
}
__device__ __forceinline__ int swzkey(int r) { return ((r >> 2) ^ r) & 3; }

// ---------------- weight conversion ----------------
__global__ void cvt_kernel(const float* __restrict__ s, ushort* __restrict__ d, int n) {
  int i = blockIdx.x * 256 + threadIdx.x;
  if (i < n) d[i] = f2bf(s[i]);
}

// Wcat[l][r][c], r: 0-63 A_w, 64-127 B_w, 128-383 gate_w, 384-639 D_w
__global__ void build_wcat(const float* __restrict__ Aw, const float* __restrict__ Bw,
                           const float* __restrict__ gw, const float* __restrict__ Dw,
                           ushort* __restrict__ out) {
  int i = blockIdx.x * 256 + threadIdx.x;
  if (i >= 6 * 640 * 256) return;
  int l = i / (640 * 256), r = (i / 256) % 640, c = i % 256;
  float v;
  if (r < 64)        v = Aw[((l * 64 + r) * 256) + c];
  else if (r < 128)  v = Bw[((l * 64 + (r - 64)) * 256) + c];
  else if (r < 384)  v = gw[((l * 256 + (r - 128)) * 256) + c];
  else               v = Dw[((l * 256 + (r - 384)) * 256) + c];
  out[i] = f2bf(v);
}

// repack row-major [N][K] bf16 -> k-sliced [p][ks][r][s][e]; slice = 8KB contiguous.
__global__ void repack_gen(const ushort* __restrict__ src, ushort* __restrict__ dst,
                           int K, int perMat, int dstPerMat, int dstOff, long total) {
  const long i = (long)blockIdx.x * 256 + threadIdx.x;
  if (i >= total) return;
  const int m = (int)(i / perMat);
  const int idx = (int)(i % perMat);
  const int slice = idx >> 12;
  const int ksn = K >> 5;
  const int p = slice / ksn, ks = slice - p * ksn;
  const int r = (idx >> 5) & 127;
  const int s = (idx >> 3) & 3;
  const int e = idx & 7;
  const int k = ks * 32 + ((s ^ ((r >> 1) & 3)) << 3) + e;
  dst[(long)m * dstPerMat + dstOff + idx] = src[(long)m * perMat + (p * 128 + r) * K + k];
}

// ========== FUSED MAMBA LAYER v4: A in registers; DOUBLE-SLICE steps (22 barriers) ==========
__global__ __launch_bounds__(256, 3)
void mamba_fused(ushort* __restrict__ y, ushort* __restrict__ xP,
                 const ushort* __restrict__ Wk,
                 const float* __restrict__ gb, const float* __restrict__ db,
                 const float* __restrict__ lng, const float* __restrict__ lnb) {
  __shared__ __align__(16) char WsB[2 * 16384];  // double-buffered 16KB slice-pairs
  __shared__ __align__(16) ushort ab[32 * 136];
  __shared__ __align__(16) char HsB[4096];
  __shared__ float lsum[32][2], lsq[32][2];

  const int t = threadIdx.x, lane = t & 63, wid = t >> 6;
  const long m0 = (long)blockIdx.x * 32;
  const int wr = (wid >> 1) * 16, wc = (wid & 1) * 64;
  const int co4 = wid * 4;                       // 4 x 1KB chunks per wave per pair
  const char* Wb = (const char*)Wk;

  const int krow = lane & 15, kslot = lane >> 4;
  const int ar = wr + krow;

  bf16x8_t afr[8];
  {
    const char* yrow = (const char*)y + (m0 + ar) * 512 + kslot * 16;
#pragma unroll
    for (int ks = 0; ks < 8; ++ks) afr[ks] = *(const bf16x8_t*)(yrow + ks * 64);
  }
  // stage pair 0 into buf 0
#pragma unroll
  for (int c = 0; c < 4; ++c)
    gload_lds16(Wb + (co4 + c) * 1024 + lane * 16, WsB + (co4 + c) * 1024);

  int boff[4];
#pragma unroll
  for (int i = 0; i < 4; ++i) {
    const int br = wc + i * 16 + krow;
    boff[i] = br * 64 + ((kslot ^ ((br >> 1) & 3)) << 4);
  }
  const int rbase = (lane >> 4) * 4, cbase = lane & 15;

  const f32x4_t zero = {0.f, 0.f, 0.f, 0.f};
  f32x4_t acc[4];
#pragma unroll
  for (int i = 0; i < 4; ++i) acc[i] = zero;

  int pair = 0;
  auto kstep2 = [&](bf16x8_t afa, bf16x8_t afb) {
    __syncthreads();
    if (pair + 1 < 22) {
      const char* src = Wb + (long)(pair + 1) * 16384;
      char* dst = WsB + ((pair + 1) & 1) * 16384;
#pragma unroll
      for (int c = 0; c < 4; ++c)
        gload_lds16(src + (co4 + c) * 1024 + lane * 16, dst + (co4 + c) * 1024);
    }
    const char* Wc = WsB + (pair & 1) * 16384;
    bf16x8_t bva[4], bvb[4];
#pragma unroll
    for (int i = 0; i < 4; ++i) bva[i] = *(const bf16x8_t*)(Wc + boff[i]);
#pragma unroll
    for (int i = 0; i < 4; ++i) bvb[i] = *(const bf16x8_t*)(Wc + 8192 + boff[i]);
    __builtin_amdgcn_s_setprio(1);
#pragma unroll
    for (int ni = 0; ni < 4; ++ni)
      acc[ni] = __builtin_amdgcn_mfma_f32_16x16x32_bf16(afa, bva[ni], acc[ni], 0, 0, 0);
#pragma unroll
    for (int ni = 0; ni < 4; ++ni)
      acc[ni] = __builtin_amdgcn_mfma_f32_16x16x32_bf16(afb, bvb[ni], acc[ni], 0, 0, 0);
    __builtin_amdgcn_s_setprio(0);
    ++pair;
  };

  // ---- phase AB: pairs 0..3 ----
#pragma unroll
  for (int p = 0; p < 4; ++p) kstep2(afr[2 * p], afr[2 * p + 1]);
#pragma unroll
  for (int ni = 0; ni < 4; ++ni) {
    const int col = wc + ni * 16 + cbase;
#pragma unroll
    for (int j = 0; j < 4; ++j) {
      const int row = wr + rbase + j;
      const float v = acc[ni][j];
      ab[row * 136 + col] = f2bf(col < 64 ? tanhf(v) : v);
    }
    acc[ni] = zero;
  }
  __syncthreads();
  // ---- scan ----
  if (t < 128) {
    const int b = t >> 6, d = t & 63;
    float av[16], btv[16];
#pragma unroll
    for (int s = 0; s < 16; ++s) {
      const int row = b * 16 + s;
      av[s]  = bf2f(ab[row * 136 + d]);
      btv[s] = bf2f(ab[row * 136 + 64 + d]);
    }
    float h = 0.f;
#pragma unroll
    for (int s = 0; s < 16; ++s) {
      h = fmaf(av[s], h, btv[s]);
      const int row = b * 16 + s;
      *(ushort*)(HsB + row * 128 + (((d >> 3) ^ (row & 7)) << 4) + (d & 7) * 2) = f2bf(h);
    }
  }

  f32x4_t gsv[2][4], dsv[2][4], xnv[2][4];
  // ---- phase G: pairs 4..11 ----
#pragma unroll
  for (int pp = 0; pp < 2; ++pp) {
#pragma unroll
    for (int p = 0; p < 4; ++p) kstep2(afr[2 * p], afr[2 * p + 1]);
#pragma unroll
    for (int ni = 0; ni < 4; ++ni) {
      const int col = pp * 128 + wc + ni * 16 + cbase;
#pragma unroll
      for (int j = 0; j < 4; ++j) {
        const float s = acc[ni][j] + gb[col];
        gsv[pp][ni][j] = 1.f / (1.f + expf(-s));
      }
      acc[ni] = zero;
    }
  }
  // ---- phase D: pairs 12..19 ----
#pragma unroll
  for (int pp = 0; pp < 2; ++pp) {
#pragma unroll
    for (int p = 0; p < 4; ++p) kstep2(afr[2 * p], afr[2 * p + 1]);
#pragma unroll
    for (int ni = 0; ni < 4; ++ni) {
      const int col = pp * 128 + wc + ni * 16 + cbase;
#pragma unroll
      for (int j = 0; j < 4; ++j) dsv[pp][ni][j] = acc[ni][j] + db[col];
      acc[ni] = zero;
    }
  }
  // ---- phase YS: pairs 20..21 ----
  const long rq16 = (m0 >> 4) + (wr >> 4);
#pragma unroll
  for (int pp = 0; pp < 2; ++pp) {
    const bf16x8_t afh0 = *(const bf16x8_t*)(
        HsB + (ar << 7) + ((kslot ^ (ar & 7)) << 4));
    const bf16x8_t afh1 = *(const bf16x8_t*)(
        HsB + (ar << 7) + (((4 | kslot) ^ (ar & 7)) << 4));
    kstep2(afh0, afh1);
#pragma unroll
    for (int ni = 0; ni < 4; ++ni) {
      const int colq = pp * 8 + (wid & 1) * 4 + ni;
      const ushort4 x4 = *(const ushort4*)(xP + (rq16 * 16 + colq) * 256 + lane * 4);
#pragma unroll
      for (int j = 0; j < 4; ++j) {
        const float g = gsv[pp][ni][j], dv = dsv[pp][ni][j];
        const float xo = bf2f(j == 0 ? x4.x : (j == 1 ? x4.y : (j == 2 ? x4.z : x4.w)));
        xnv[pp][ni][j] = xo + acc[ni][j] * g + dv * (1.f - g);
      }
      acc[ni] = zero;
    }
  }
  // ---- LN stats ----
#pragma unroll
  for (int j = 0; j < 4; ++j) {
    float ps = 0.f, pq = 0.f;
#pragma unroll
    for (int pp = 0; pp < 2; ++pp)
#pragma unroll
      for (int ni = 0; ni < 4; ++ni) { const float v = xnv[pp][ni][j]; ps += v; pq += v * v; }
#pragma unroll
    for (int off = 1; off < 16; off <<= 1) {
      ps += __shfl_xor(ps, off, 64);
      pq += __shfl_xor(pq, off, 64);
    }
    if ((lane & 15) == 0) {
      const int row = wr + rbase + j;
      lsum[row][wid & 1] = ps;
      lsq[row][wid & 1] = pq;
    }
  }
  __syncthreads();
#pragma unroll
  for (int pp = 0; pp < 2; ++pp) {
#pragma unroll
    for (int ni = 0; ni < 4; ++ni) {
      const int colq = pp * 8 + (wid & 1) * 4 + ni;
      ushort4 o4;
      o4.x = f2bf(xnv[pp][ni][0]);
      o4.y = f2bf(xnv[pp][ni][1]);
      o4.z = f2bf(xnv[pp][ni][2]);
      o4.w = f2bf(xnv[pp][ni][3]);
      *(ushort4*)(xP + (rq16 * 16 + colq) * 256 + lane * 4) = o4;
    }
  }
#pragma unroll
  for (int j = 0; j < 4; ++j) {
    const int row = wr + rbase + j;
    const float sm = lsum[row][0] + lsum[row][1];
    const float q = lsq[row][0] + lsq[row][1];
    const float mean = sm * (1.f / 256.f);
    const float rstd = rsqrtf(q * (1.f / 256.f) - mean * mean + 1e-5f);
#pragma unroll
    for (int pp = 0; pp < 2; ++pp)
#pragma unroll
      for (int ni = 0; ni < 4; ++ni) {
        const int col = pp * 128 + wc + ni * 16 + cbase;
        *(ushort*)(WsB + row * 512 + col * 2) =
            f2bf((xnv[pp][ni][j] - mean) * rstd * lng[col] + lnb[col]);
      }
  }
  __syncthreads();
#pragma unroll
  for (int rr = 0; rr < 4; ++rr) {
    const int byte = rr * 4096 + t * 16;
    const int row = byte >> 9, off = byte & 511;
    const bf16x8_t v = *(const bf16x8_t*)(WsB + byte);
    *(bf16x8_t*)((char*)y + (m0 + row) * 512 + off) = v;
  }
}

// ========== gemm_ws v2: barrier-free. A LDS-resident; W k-sliced global->register
// (each fragment load = 1KB-contiguous region, L2-hot). MODE 2: gelu. MODE 3: relu.
template <int NP, int MODE>
__global__ __launch_bounds__(256)
void gemm_ws(const ushort* __restrict__ A, const ushort* __restrict__ Wks,
             const float* __restrict__ b1, ushort* __restrict__ outp) {
  constexpr int KS = 8;
  constexpr int N = NP * 128;
  constexpr int T = NP * KS;
  __shared__ __align__(16) char AsB[128 * 512];

  const int t = threadIdx.x, lane = t & 63, wid = t >> 6;
  const long m0 = (long)blockIdx.x * 128;
  const int wr = (wid >> 1) * 64, wc = (wid & 1) * 64;
  const char* Ab = (const char*)A;
  const char* Wb = (const char*)Wks;

  {
    const int arow = lane >> 5;
    const int aps  = lane & 31;
#pragma unroll
    for (int j = 0; j < 16; ++j) {
      const int r = j * 8 + wid * 2 + arow;
      gload_lds16(Ab + (m0 + r) * 512 + (long)((aps ^ (r & 7)) << 4),
                  AsB + (j * 8 + wid * 2) * 512);
    }
  }

  const int krow = lane & 15, kslot = lane >> 4;
  int abase[4], akey[4], boff[4];
#pragma unroll
  for (int i = 0; i < 4; ++i) {
    const int ar = wr + i * 16 + krow;
    abase[i] = ar * 512;
    akey[i] = ar & 7;
    const int br = wc + i * 16 + krow;
    boff[i] = br * 64 + ((kslot ^ ((br >> 1) & 3)) << 4);
  }

  const f32x4_t zero = {0.f, 0.f, 0.f, 0.f};
  f32x4_t acc[4][4];
#pragma unroll
  for (int i = 0; i < 4; ++i)
#pragma unroll
    for (int j = 0; j < 4; ++j) acc[i][j] = zero;

  const int rbase = (lane >> 4) * 4, cbase = lane & 15;

  __syncthreads();   // A staged; only block-wide barrier in the kernel

  bf16x8_t bv[4];
#pragma unroll
  for (int i = 0; i < 4; ++i) bv[i] = *(const bf16x8_t*)(Wb + boff[i]);

  for (int tau = 0; tau < T; ++tau) {
    bf16x8_t bw[4];
    if (tau + 1 < T) {
      const char* src = Wb + (long)(tau + 1) * 8192;
#pragma unroll
      for (int i = 0; i < 4; ++i) bw[i] = *(const bf16x8_t*)(src + boff[i]);
    } else {
#pragma unroll
      for (int i = 0; i < 4; ++i) bw[i] = bv[i];
    }
    const int ks = tau & 7;
    bf16x8_t af[4];
#pragma unroll
    for (int i = 0; i < 4; ++i)
      af[i] = *(const bf16x8_t*)(AsB + abase[i] + ((((ks << 2) | kslot) ^ akey[i]) << 4));
    __builtin_amdgcn_s_setprio(1);
#pragma unroll
    for (int mi = 0; mi < 4; ++mi)
#pragma unroll
      for (int ni = 0; ni < 4; ++ni)
        acc[mi][ni] = __builtin_amdgcn_mfma_f32_16x16x32_bf16(af[mi], bv[ni], acc[mi][ni], 0, 0, 0);
    __builtin_amdgcn_s_setprio(0);
#pragma unroll
    for (int i = 0; i < 4; ++i) bv[i] = bw[i];

    if (ks == KS - 1) {
      const int np = tau >> 3;
#pragma unroll
      for (int mi = 0; mi < 4; ++mi) {
#pragma unroll
        for (int ni = 0; ni < 4; ++ni) {
          const int col = np * 128 + wc + ni * 16 + cbase;
#pragma unroll
          for (int j = 0; j < 4; ++j) {
            const long row = m0 + wr + mi * 16 + rbase + j;
            float s = acc[mi][ni][j] + b1[col];
            float o;
            if constexpr (MODE == 2) o = 0.5f * s * (1.f + erff(s * 0.70710678118654752f));
            else                     o = fmaxf(s, 0.f);
            outp[row * N + col] = f2bf(o);
          }
          acc[mi][ni] = zero;
        }
      }
    }
  }
}

// ========== G3: N=256 GEMM + fused residual + LayerNorm; x packed, y row-major ==========
// AFP32: A is fp32 (raw input data); staged via reg-convert + ds_write to swizzled slots.
template <int K, int MODE, bool AFP32>
__global__ __launch_bounds__(512)
void gemm_ln(const void* __restrict__ Ap, const ushort* __restrict__ W,
             const float* __restrict__ b1, ushort* __restrict__ xP,
             const float* __restrict__ lng, const float* __restrict__ lnb,
             ushort* __restrict__ y, int writex) {
  constexpr int KS = K / 32;
  __shared__ __align__(16) char WsB[2 * 16384];
  __shared__ __align__(16) char AsB[2 * 8192];
  __shared__ float lsum4[128][4], lsq4[128][4];

  const int t = threadIdx.x, lane = t & 63, wid = t >> 6;
  const int wr = (wid >> 2) * 64, wc = (wid & 3) * 64;
  const int lr = lane >> 2, lc = lane & 3;
  const int ra = wid * 16 + lr;
  const int slog = lc ^ swzkey(ra);
  const int saA = slog << 4;
  const int rw0 = wid * 32 + lr, rw1 = rw0 + 16;
  const int sw0 = (lc ^ swzkey(rw0)) << 4;
  const int sw1 = (lc ^ swzkey(rw1)) << 4;
  const char* Ab = (const char*)Ap;
  const char* Wb = (const char*)W;
  constexpr long K2 = (long)K * 2;
  const long m0 = (long)blockIdx.x * 128;

  auto stageA = [&](int tau2) {
    char* dst = AsB + (tau2 & 1) * 8192 + wid * 1024 + lane * 16;
    if constexpr (AFP32) {
      const float* src = (const float*)Ap + (m0 + ra) * K + tau2 * 32 + slog * 8;
      const float4 q0 = ((const float4*)src)[0];
      const float4 q1 = ((const float4*)src)[1];
      bf16x8_t v;
      v[0] = (short)f2bf(q0.x); v[1] = (short)f2bf(q0.y);
      v[2] = (short)f2bf(q0.z); v[3] = (short)f2bf(q0.w);
      v[4] = (short)f2bf(q1.x); v[5] = (short)f2bf(q1.y);
      v[6] = (short)f2bf(q1.z); v[7] = (short)f2bf(q1.w);
      *(bf16x8_t*)dst = v;
    } else {
      gload_lds16(Ab + (m0 + ra) * K2 + (long)tau2 * 64 + saA,
                  AsB + (tau2 & 1) * 8192 + wid * 1024);
    }
  };

  gload_lds16(Wb + (long)rw0 * K2 + sw0, WsB + wid * 2048);
  gload_lds16(Wb + (long)rw1 * K2 + sw1, WsB + wid * 2048 + 1024);
  stageA(0);

  const int krow = lane & 15, kslot = lane >> 4;
  int aoff[4], boff[4];
#pragma unroll
  for (int i = 0; i < 4; ++i) {
    int ar = wr + i * 16 + krow;
    aoff[i] = ar * 64 + ((kslot ^ swzkey(ar)) << 4);
    int br = wc + i * 16 + krow;
    boff[i] = br * 64 + ((kslot ^ swzkey(br)) << 4);
  }

  const f32x4_t zero = {0.f, 0.f, 0.f, 0.f};
  f32x4_t acc[4][4];
#pragma unroll
  for (int i = 0; i < 4; ++i)
#pragma unroll
    for (int j = 0; j < 4; ++j) acc[i][j] = zero;

  for (int tau = 0; tau < KS; ++tau) {
    __syncthreads();
    if (tau + 1 < KS) {
      stageA(tau + 1);
      const long kb = (long)(tau + 1) * 64;
      char* wd = WsB + ((tau + 1) & 1) * 16384 + wid * 2048;
      gload_lds16(Wb + (long)rw0 * K2 + kb + sw0, wd);
      gload_lds16(Wb + (long)rw1 * K2 + kb + sw1, wd + 1024);
    }
    const char* Ac = AsB + (tau & 1) * 8192;
    const char* Wc = WsB + (tau & 1) * 16384;
    bf16x8_t af[4], bv[4];
#pragma unroll
    for (int i = 0; i < 4; ++i) af[i] = *(const bf16x8_t*)(Ac + aoff[i]);
#pragma unroll
    for (int i = 0; i < 4; ++i) bv[i] = *(const bf16x8_t*)(Wc + boff[i]);
#pragma unroll
    for (int mi = 0; mi < 4; ++mi)
#pragma unroll
      for (int ni = 0; ni < 4; ++ni)
        acc[mi][ni] = __builtin_amdgcn_mfma_f32_16x16x32_bf16(af[mi], bv[ni], acc[mi][ni], 0, 0, 0);
  }

  const int rbase = (lane >> 4) * 4;
  const int cbase = lane & 15;
  const long xbB = (long)blockIdx.x * 32768;
#pragma unroll
  for (int mi = 0; mi < 4; ++mi) {
    const int rq = (wid >> 2) * 4 + mi;
#pragma unroll
    for (int ni = 0; ni < 4; ++ni) {
      const int col = wc + ni * 16 + cbase;
      const int cq = (wid & 3) * 4 + ni;
      ushort4 x4;
      if constexpr (MODE == 3) x4 = *(const ushort4*)(xP + xbB + ((rq * 16 + cq) * 64 + lane) * 4);
#pragma unroll
      for (int j = 0; j < 4; ++j) {
        float v = acc[mi][ni][j] + b1[col];
        if constexpr (MODE == 3)
          v += bf2f(j == 0 ? x4.x : (j == 1 ? x4.y : (j == 2 ? x4.z : x4.w)));
        acc[mi][ni][j] = v;
      }
    }
  }
#pragma unroll
  for (int mi = 0; mi < 4; ++mi) {
#pragma unroll
    for (int j = 0; j < 4; ++j) {
      float ps = 0.f, pq = 0.f;
#pragma unroll
      for (int ni = 0; ni < 4; ++ni) { float v = acc[mi][ni][j]; ps += v; pq += v * v; }
#pragma unroll
      for (int off = 1; off < 16; off <<= 1) {
        ps += __shfl_xor(ps, off, 64);
        pq += __shfl_xor(pq, off, 64);
      }
      if ((lane & 15) == 0) {
        int r = wr + mi * 16 + (lane >> 4) * 4 + j;
        lsum4[r][wid & 3] = ps;
        lsq4[r][wid & 3] = pq;
      }
    }
  }
  __syncthreads();
#pragma unroll
  for (int mi = 0; mi < 4; ++mi) {
    const int rq = (wid >> 2) * 4 + mi;
#pragma unroll
    for (int ni = 0; ni < 4; ++ni) {
      const int cq = (wid & 3) * 4 + ni;
      if (writex) {
        ushort4 o4;
        o4.x = f2bf(acc[mi][ni][0]);
        o4.y = f2bf(acc[mi][ni][1]);
        o4.z = f2bf(acc[mi][ni][2]);
        o4.w = f2bf(acc[mi][ni][3]);
        *(ushort4*)(xP + xbB + ((rq * 16 + cq) * 64 + lane) * 4) = o4;
      }
    }
  }
#pragma unroll
  for (int mi = 0; mi < 4; ++mi) {
#pragma unroll
    for (int j = 0; j < 4; ++j) {
      const int r = wr + mi * 16 + rbase + j;
      const float s = lsum4[r][0] + lsum4[r][1] + lsum4[r][2] + lsum4[r][3];
      const float q = lsq4[r][0] + lsq4[r][1] + lsq4[r][2] + lsq4[r][3];
      const float mean = s * (1.f / 256.f);
      const float rstd = rsqrtf(q * (1.f / 256.f) - mean * mean + 1e-5f);
      const long row = m0 + r;
#pragma unroll
      for (int ni = 0; ni < 4; ++ni) {
        const int col = wc + ni * 16 + cbase;
        y[row * 256 + col] = f2bf((acc[mi][ni][j] - mean) * rstd * lng[col] + lnb[col]);
      }
    }
  }
}

// ========== head_agg: per-batch neighbor attention; v = node + agg (bf16) ==========
__global__ __launch_bounds__(256)
void head_agg(const ushort* __restrict__ y, const float* __restrict__ attw,
              ushort* __restrict__ vb) {
  const int t = threadIdx.x, lane = t & 63, w = t >> 6;
  const long b = (long)blockIdx.x * 4 + w;
  const ushort* yb = y + b * 16 * 256;
  const float4 w2 = *(const float4*)(attw + 256 + lane * 4);

  float4 rows[16];
  float lg[16];
#pragma unroll
  for (int r = 0; r < 16; ++r) {
    const ushort4 u = *(const ushort4*)(yb + r * 256 + lane * 4);
    float4 v4;
    v4.x = bf2f(u.x); v4.y = bf2f(u.y); v4.z = bf2f(u.z); v4.w = bf2f(u.w);
    rows[r] = v4;
    if (r >= 1) {
      float s = v4.x * w2.x + v4.y * w2.y + v4.z * w2.z + v4.w * w2.w;
#pragma unroll
      for (int off = 32; off > 0; off >>= 1) s += __shfl_xor(s, off, 64);
      lg[r] = s;
    }
  }
  float mx = -1e30f;
#pragma unroll
  for (int r = 1; r < 16; ++r) mx = fmaxf(mx, lg[r]);
  float den = 0.f;
#pragma unroll
  for (int r = 1; r < 16; ++r) { lg[r] = expf(lg[r] - mx); den += lg[r]; }
  const float inv = 1.f / den;
  float4 v = rows[0];
#pragma unroll
  for (int r = 1; r < 16; ++r) {
    const float a = lg[r] * inv;
    v.x += a * rows[r].x; v.y += a * rows[r].y;
    v.z += a * rows[r].z; v.w += a * rows[r].w;
  }
  ushort4 o;
  o.x = f2bf(v.x); o.y = f2bf(v.y); o.z = f2bf(v.z); o.w = f2bf(v.w);
  *(ushort4*)(vb + b * 256 + lane * 4) = o;
}

// ========== head_cls: logits = o1 @ cls_w^T + cb; log_softmax ==========
__global__ __launch_bounds__(256)
void head_cls(const ushort* __restrict__ o1b, const float* __restrict__ cw,
              const float* __restrict__ cb, float* __restrict__ out) {
  __shared__ float lw[4][40];
  const int t = threadIdx.x, lane = t & 63, w = t >> 6;
  const long b = (long)blockIdx.x * 4 + w;
  const ushort2 u = *(const ushort2*)(o1b + b * 128 + lane * 2);
  const float o1x = bf2f(u.x), o1y = bf2f(u.y);

#pragma unroll
  for (int o = 0; o < 40; ++o) {
    const float2 c = *(const float2*)(cw + o * 128 + lane * 2);
    float p = o1x * c.x + o1y * c.y;
#pragma unroll
    for (int off = 32; off > 0; off >>= 1) p += __shfl_xor(p, off, 64);
    if (lane == 0) lw[w][o] = p + cb[o];
  }
  const float v = (lane < 40) ? lw[w][lane] : -1e30f;
  float mx = v;
#pragma unroll
  for (int off = 32; off > 0; off >>= 1) mx = fmaxf(mx, __shfl_xor(mx, off, 64));
  float e = (lane < 40) ? expf(v - mx) : 0.f;
  float den = e;
#pragma unroll
  for (int off = 32; off > 0; off >>= 1) den += __shfl_xor(den, off, 64);
  if (lane < 40) out[b * 40 + lane] = v - mx - logf(den);
}

// ---------------- host ----------------
extern "C" void kernel_launch(void* const* d_in, const int* in_sizes, int n_in,
                              void* d_out, int out_size, void* d_ws, size_t ws_size,
                              hipStream_t stream) {
  const float* data   = (const float*)d_in[0];
  const float* in_w   = (const float*)d_in[1];
  const float* in_b   = (const float*)d_in[2];
  const float* norm_g = (const float*)d_in[3];
  const float* norm_b = (const float*)d_in[4];
  const float* A_w    = (const float*)d_in[5];
  const float* B_w    = (const float*)d_in[6];
  const float* C_w    = (const float*)d_in[7];
  const float* D_w    = (const float*)d_in[8];
  const float* D_b    = (const float*)d_in[9];
  const float* gate_w = (const float*)d_in[10];
  const float* gate_b = (const float*)d_in[11];
  const float* ffn_w1 = (const float*)d_in[12];
  const float* ffn_b1 = (const float*)d_in[13];
  const float* ffn_w2 = (const float*)d_in[14];
  const float* ffn_b2 = (const float*)d_in[15];
  const float* fln_g  = (const float*)d_in[16];
  const float* fln_b  = (const float*)d_in[17];
  const float* out_w  = (const float*)d_in[18];
  const float* out_b  = (const float*)d_in[19];
  const float* cls_w  = (const float*)d_in[20];
  const float* cls_b  = (const float*)d_in[21];
  const float* attn_w = (const float*)d_in[22];
  const float* attn_b = (const float*)d_in[23];
  (void)in_sizes; (void)n_in; (void)out_size; (void)ws_size; (void)attn_b;

  char* ws = (char*)d_ws;
  ushort* xP     = (ushort*)(ws + 0);           // packed x
  ushort* y      = (ushort*)(ws + 67108864);    // row-major y
  ushort* tzp    = (ushort*)(ws + 134217728);   // t / vb+o1b (time-shared)
  ushort* wcat   = (ushort*)(ws + 318767104);
  ushort* inwb   = (ushort*)(ws + 320733184);
  ushort* w1b    = (ushort*)(ws + 320995328);
  ushort* w2b    = (ushort*)(ws + 322568192);
  ushort* cwb    = (ushort*)(ws + 324141056);
  ushort* mslice = (ushort*)(ws + 324337664);   // 6 layers x 44 slices x 4096 elems
  ushort* w1k    = (ushort*)(ws + 326500352);   // 6*512*256*2 (k-sliced)
  ushort* owb    = (ushort*)(ws + 328073216);   // out_w bf16 (128x256)
  ushort* owk    = (ushort*)(ws + 328138752);   // out_w k-sliced
  ushort* vb     = tzp;                         // 8192*256 bf16 (after t dead)
  ushort* o1b    = tzp + 2097152;               // 8192*128 bf16

  cvt_kernel<<<512, 256, 0, stream>>>(in_w, inwb, 131072);
  cvt_kernel<<<3072, 256, 0, stream>>>(ffn_w1, w1b, 786432);
  cvt_kernel<<<3072, 256, 0, stream>>>(ffn_w2, w2b, 786432);
  cvt_kernel<<<384, 256, 0, stream>>>(C_w, cwb, 98304);
  cvt_kernel<<<128, 256, 0, stream>>>(out_w, owb, 32768);
  build_wcat<<<3840, 256, 0, stream>>>(A_w, B_w, gate_w, D_w, wcat);
  repack_gen<<<3840, 256, 0, stream>>>(wcat, mslice, 256, 163840, 180224, 0, 6L * 163840);
  repack_gen<<<384, 256, 0, stream>>>(cwb, mslice, 64, 16384, 180224, 163840, 6L * 16384);
  repack_gen<<<3072, 256, 0, stream>>>(w1b, w1k, 256, 131072, 131072, 0, 6L * 131072);
  repack_gen<<<128, 256, 0, stream>>>(owb, owk, 256, 32768, 32768, 0, 32768);

  // input proj (fp32 A, fused convert) + fused LN(layer0): xP (packed), y
  gemm_ln<512, 0, true><<<dim3(1024), 512, 0, stream>>>(
      data, inwb, in_b, xP, norm_g, norm_b, y, 1);

  for (int l = 0; l < 6; ++l) {
    mamba_fused<<<4096, 256, 0, stream>>>(
        y, xP, mslice + (size_t)l * 180224,
        gate_b + l * 256, D_b + l * 256, norm_g + l * 256, norm_b + l * 256);
    gemm_ws<4, 2><<<1024, 256, 0, stream>>>(
        y, w1k + (size_t)l * 131072, ffn_b1 + l * 512, tzp);
    const float* lg2 = (l < 5) ? (norm_g + (l + 1) * 256) : fln_g;
    const float* lb2 = (l < 5) ? (norm_b + (l + 1) * 256) : fln_b;
    gemm_ln<512, 3, false><<<dim3(1024), 512, 0, stream>>>(
        tzp, w2b + (size_t)l * 256 * 512, ffn_b2 + l * 256, xP, lg2, lb2, y, (l < 5) ? 1 : 0);
  }

  // head: attention-agg -> out-proj GEMM (relu) -> cls + log_softmax
  head_agg<<<2048, 256, 0, stream>>>(y, attn_w, vb);
  gemm_ws<1, 3><<<64, 256, 0, stream>>>(vb, owk, out_b, o1b);
  head_cls<<<2048, 256, 0, stream>>>(o1b, cls_w, cls_b, (float*)d_out);
}

// Round 19
// 1984.642 us; speedup vs baseline: 1.3072x; 1.0633x over previous
//
#include <hip/hip_runtime.h>

typedef __attribute__((ext_vector_type(8))) short bf16x8_t;
typedef __attribute__((ext_vector_type(4))) float f32x4_t;

__device__ __forceinline__ ushort f2bf(float x) {
  union { float f; unsigned u; } a; a.f = x;
  unsigned r = a.u + 0x7fffu + ((a.u >> 16) & 1u);
  return (ushort)(r >> 16);
}
__device__ __forceinline__ float bf2f(ushort s) {
  union { unsigned u; float f; } a; a.u = ((unsigned)s) << 16;
  return a.f;
}
__device__ __forceinline__ void gload_lds16(const void* g, void* l) {
  __builtin_amdgcn_global_load_lds(
      (const __attribute__((address_space(1))) unsigned int*)g,
      (__attribute__((address_space(3))) unsigned int*)l, 16, 0, 0);
}
__device__ __forceinline__ int swzkey(int r) { return ((r >> 2) ^ r) & 3; }

// ---------------- weight conversion ----------------
__global__ void cvt_kernel(const float* __restrict__ s, ushort* __restrict__ d, int n) {
  int i = blockIdx.x * 256 + threadIdx.x;
  if (i < n) d[i] = f2bf(s[i]);
}

// Wcat[l][r][c], r: 0-63 A_w, 64-127 B_w, 128-383 gate_w, 384-639 D_w
__global__ void build_wcat(const float* __restrict__ Aw, const float* __restrict__ Bw,
                           const float* __restrict__ gw, const float* __restrict__ Dw,
                           ushort* __restrict__ out) {
  int i = blockIdx.x * 256 + threadIdx.x;
  if (i >= 6 * 640 * 256) return;
  int l = i / (640 * 256), r = (i / 256) % 640, c = i % 256;
  float v;
  if (r < 64)        v = Aw[((l * 64 + r) * 256) + c];
  else if (r < 128)  v = Bw[((l * 64 + (r - 64)) * 256) + c];
  else if (r < 384)  v = gw[((l * 256 + (r - 128)) * 256) + c];
  else               v = Dw[((l * 256 + (r - 384)) * 256) + c];
  out[i] = f2bf(v);
}

// repack row-major [N][K] bf16 -> k-sliced [p][ks][r][s][e]; slice = 8KB contiguous.
__global__ void repack_gen(const ushort* __restrict__ src, ushort* __restrict__ dst,
                           int K, int perMat, int dstPerMat, int dstOff, long total) {
  const long i = (long)blockIdx.x * 256 + threadIdx.x;
  if (i >= total) return;
  const int m = (int)(i / perMat);
  const int idx = (int)(i % perMat);
  const int slice = idx >> 12;
  const int ksn = K >> 5;
  const int p = slice / ksn, ks = slice - p * ksn;
  const int r = (idx >> 5) & 127;
  const int s = (idx >> 3) & 3;
  const int e = idx & 7;
  const int k = ks * 32 + ((s ^ ((r >> 1) & 3)) << 3) + e;
  dst[(long)m * dstPerMat + dstOff + idx] = src[(long)m * perMat + (p * 128 + r) * K + k];
}

// ========== FUSED MAMBA LAYER v4 (R17-proven) ==========
__global__ __launch_bounds__(256, 3)
void mamba_fused(ushort* __restrict__ y, ushort* __restrict__ xP,
                 const ushort* __restrict__ Wk,
                 const float* __restrict__ gb, const float* __restrict__ db,
                 const float* __restrict__ lng, const float* __restrict__ lnb) {
  __shared__ __align__(16) char WsB[2 * 16384];
  __shared__ __align__(16) ushort ab[32 * 136];
  __shared__ __align__(16) char HsB[4096];
  __shared__ float lsum[32][2], lsq[32][2];

  const int t = threadIdx.x, lane = t & 63, wid = t >> 6;
  const long m0 = (long)blockIdx.x * 32;
  const int wr = (wid >> 1) * 16, wc = (wid & 1) * 64;
  const int co4 = wid * 4;
  const char* Wb = (const char*)Wk;

  const int krow = lane & 15, kslot = lane >> 4;
  const int ar = wr + krow;

  bf16x8_t afr[8];
  {
    const char* yrow = (const char*)y + (m0 + ar) * 512 + kslot * 16;
#pragma unroll
    for (int ks = 0; ks < 8; ++ks) afr[ks] = *(const bf16x8_t*)(yrow + ks * 64);
  }
#pragma unroll
  for (int c = 0; c < 4; ++c)
    gload_lds16(Wb + (co4 + c) * 1024 + lane * 16, WsB + (co4 + c) * 1024);

  int boff[4];
#pragma unroll
  for (int i = 0; i < 4; ++i) {
    const int br = wc + i * 16 + krow;
    boff[i] = br * 64 + ((kslot ^ ((br >> 1) & 3)) << 4);
  }
  const int rbase = (lane >> 4) * 4, cbase = lane & 15;

  const f32x4_t zero = {0.f, 0.f, 0.f, 0.f};
  f32x4_t acc[4];
#pragma unroll
  for (int i = 0; i < 4; ++i) acc[i] = zero;

  int pair = 0;
  auto kstep2 = [&](bf16x8_t afa, bf16x8_t afb) {
    __syncthreads();
    if (pair + 1 < 22) {
      const char* src = Wb + (long)(pair + 1) * 16384;
      char* dst = WsB + ((pair + 1) & 1) * 16384;
#pragma unroll
      for (int c = 0; c < 4; ++c)
        gload_lds16(src + (co4 + c) * 1024 + lane * 16, dst + (co4 + c) * 1024);
    }
    const char* Wc = WsB + (pair & 1) * 16384;
    bf16x8_t bva[4], bvb[4];
#pragma unroll
    for (int i = 0; i < 4; ++i) bva[i] = *(const bf16x8_t*)(Wc + boff[i]);
#pragma unroll
    for (int i = 0; i < 4; ++i) bvb[i] = *(const bf16x8_t*)(Wc + 8192 + boff[i]);
    __builtin_amdgcn_s_setprio(1);
#pragma unroll
    for (int ni = 0; ni < 4; ++ni)
      acc[ni] = __builtin_amdgcn_mfma_f32_16x16x32_bf16(afa, bva[ni], acc[ni], 0, 0, 0);
#pragma unroll
    for (int ni = 0; ni < 4; ++ni)
      acc[ni] = __builtin_amdgcn_mfma_f32_16x16x32_bf16(afb, bvb[ni], acc[ni], 0, 0, 0);
    __builtin_amdgcn_s_setprio(0);
    ++pair;
  };

#pragma unroll
  for (int p = 0; p < 4; ++p) kstep2(afr[2 * p], afr[2 * p + 1]);
#pragma unroll
  for (int ni = 0; ni < 4; ++ni) {
    const int col = wc + ni * 16 + cbase;
#pragma unroll
    for (int j = 0; j < 4; ++j) {
      const int row = wr + rbase + j;
      const float v = acc[ni][j];
      ab[row * 136 + col] = f2bf(col < 64 ? tanhf(v) : v);
    }
    acc[ni] = zero;
  }
  __syncthreads();
  if (t < 128) {
    const int b = t >> 6, d = t & 63;
    float av[16], btv[16];
#pragma unroll
    for (int s = 0; s < 16; ++s) {
      const int row = b * 16 + s;
      av[s]  = bf2f(ab[row * 136 + d]);
      btv[s] = bf2f(ab[row * 136 + 64 + d]);
    }
    float h = 0.f;
#pragma unroll
    for (int s = 0; s < 16; ++s) {
      h = fmaf(av[s], h, btv[s]);
      const int row = b * 16 + s;
      *(ushort*)(HsB + row * 128 + (((d >> 3) ^ (row & 7)) << 4) + (d & 7) * 2) = f2bf(h);
    }
  }

  f32x4_t gsv[2][4], dsv[2][4], xnv[2][4];
#pragma unroll
  for (int pp = 0; pp < 2; ++pp) {
#pragma unroll
    for (int p = 0; p < 4; ++p) kstep2(afr[2 * p], afr[2 * p + 1]);
#pragma unroll
    for (int ni = 0; ni < 4; ++ni) {
      const int col = pp * 128 + wc + ni * 16 + cbase;
#pragma unroll
      for (int j = 0; j < 4; ++j) {
        const float s = acc[ni][j] + gb[col];
        gsv[pp][ni][j] = 1.f / (1.f + expf(-s));
      }
      acc[ni] = zero;
    }
  }
#pragma unroll
  for (int pp = 0; pp < 2; ++pp) {
#pragma unroll
    for (int p = 0; p < 4; ++p) kstep2(afr[2 * p], afr[2 * p + 1]);
#pragma unroll
    for (int ni = 0; ni < 4; ++ni) {
      const int col = pp * 128 + wc + ni * 16 + cbase;
#pragma unroll
      for (int j = 0; j < 4; ++j) dsv[pp][ni][j] = acc[ni][j] + db[col];
      acc[ni] = zero;
    }
  }
  const long rq16 = (m0 >> 4) + (wr >> 4);
#pragma unroll
  for (int pp = 0; pp < 2; ++pp) {
    const bf16x8_t afh0 = *(const bf16x8_t*)(
        HsB + (ar << 7) + ((kslot ^ (ar & 7)) << 4));
    const bf16x8_t afh1 = *(const bf16x8_t*)(
        HsB + (ar << 7) + (((4 | kslot) ^ (ar & 7)) << 4));
    kstep2(afh0, afh1);
#pragma unroll
    for (int ni = 0; ni < 4; ++ni) {
      const int colq = pp * 8 + (wid & 1) * 4 + ni;
      const ushort4 x4 = *(const ushort4*)(xP + (rq16 * 16 + colq) * 256 + lane * 4);
#pragma unroll
      for (int j = 0; j < 4; ++j) {
        const float g = gsv[pp][ni][j], dv = dsv[pp][ni][j];
        const float xo = bf2f(j == 0 ? x4.x : (j == 1 ? x4.y : (j == 2 ? x4.z : x4.w)));
        xnv[pp][ni][j] = xo + acc[ni][j] * g + dv * (1.f - g);
      }
      acc[ni] = zero;
    }
  }
#pragma unroll
  for (int j = 0; j < 4; ++j) {
    float ps = 0.f, pq = 0.f;
#pragma unroll
    for (int pp = 0; pp < 2; ++pp)
#pragma unroll
      for (int ni = 0; ni < 4; ++ni) { const float v = xnv[pp][ni][j]; ps += v; pq += v * v; }
#pragma unroll
    for (int off = 1; off < 16; off <<= 1) {
      ps += __shfl_xor(ps, off, 64);
      pq += __shfl_xor(pq, off, 64);
    }
    if ((lane & 15) == 0) {
      const int row = wr + rbase + j;
      lsum[row][wid & 1] = ps;
      lsq[row][wid & 1] = pq;
    }
  }
  __syncthreads();
#pragma unroll
  for (int pp = 0; pp < 2; ++pp) {
#pragma unroll
    for (int ni = 0; ni < 4; ++ni) {
      const int colq = pp * 8 + (wid & 1) * 4 + ni;
      ushort4 o4;
      o4.x = f2bf(xnv[pp][ni][0]);
      o4.y = f2bf(xnv[pp][ni][1]);
      o4.z = f2bf(xnv[pp][ni][2]);
      o4.w = f2bf(xnv[pp][ni][3]);
      *(ushort4*)(xP + (rq16 * 16 + colq) * 256 + lane * 4) = o4;
    }
  }
#pragma unroll
  for (int j = 0; j < 4; ++j) {
    const int row = wr + rbase + j;
    const float sm = lsum[row][0] + lsum[row][1];
    const float q = lsq[row][0] + lsq[row][1];
    const float mean = sm * (1.f / 256.f);
    const float rstd = rsqrtf(q * (1.f / 256.f) - mean * mean + 1e-5f);
#pragma unroll
    for (int pp = 0; pp < 2; ++pp)
#pragma unroll
      for (int ni = 0; ni < 4; ++ni) {
        const int col = pp * 128 + wc + ni * 16 + cbase;
        *(ushort*)(WsB + row * 512 + col * 2) =
            f2bf((xnv[pp][ni][j] - mean) * rstd * lng[col] + lnb[col]);
      }
  }
  __syncthreads();
#pragma unroll
  for (int rr = 0; rr < 4; ++rr) {
    const int byte = rr * 4096 + t * 16;
    const int row = byte >> 9, off = byte & 511;
    const bf16x8_t v = *(const bf16x8_t*)(WsB + byte);
    *(bf16x8_t*)((char*)y + (m0 + row) * 512 + off) = v;
  }
}

// ========== FUSED FFN v2: barrier-free W streams; t in LDS; 3 barriers total ==========
// Block = 32 rows. y in registers; W1k (32 slices, K=256) and W2k (32 slices, K=512)
// stream global->reg; fused residual(packed xP)+LN epilogue.
__global__ __launch_bounds__(256, 3)
void ffn_fused2(ushort* __restrict__ y, ushort* __restrict__ xP,
                const ushort* __restrict__ W1k, const ushort* __restrict__ W2k,
                const float* __restrict__ b1, const float* __restrict__ b2,
                const float* __restrict__ lng, const float* __restrict__ lnb,
                int writex) {
  __shared__ __align__(16) char Ts[32768];   // t tile 32x512 bf16, slot-swizzled
  __shared__ float lsum[32][2], lsq[32][2];

  const int t = threadIdx.x, lane = t & 63, wid = t >> 6;
  const long m0 = (long)blockIdx.x * 32;
  const int wr = (wid >> 1) * 16, wc = (wid & 1) * 64;
  const int krow = lane & 15, kslot = lane >> 4;
  const int ar = wr + krow;
  const int rbase = (lane >> 4) * 4, cbase = lane & 15;

  // y rows -> registers
  bf16x8_t afr[8];
  {
    const char* yrow = (const char*)y + (m0 + ar) * 512 + kslot * 16;
#pragma unroll
    for (int ks = 0; ks < 8; ++ks) afr[ks] = *(const bf16x8_t*)(yrow + ks * 64);
  }

  int boff[4];
#pragma unroll
  for (int i = 0; i < 4; ++i) {
    const int br = wc + i * 16 + krow;
    boff[i] = br * 64 + ((kslot ^ ((br >> 1) & 3)) << 4);
  }

  const f32x4_t zero = {0.f, 0.f, 0.f, 0.f};
  f32x4_t acc[4];
#pragma unroll
  for (int i = 0; i < 4; ++i) acc[i] = zero;

  // ---- ffn1: 4 panels x 8 k-steps, W1->reg, gelu -> Ts ----
  const char* W1 = (const char*)W1k;
  bf16x8_t bv[4];
#pragma unroll
  for (int i = 0; i < 4; ++i) bv[i] = *(const bf16x8_t*)(W1 + boff[i]);
  for (int np = 0; np < 4; ++np) {
#pragma unroll
    for (int ks = 0; ks < 8; ++ks) {
      const int sl = np * 8 + ks;
      bf16x8_t bw[4];
      if (sl + 1 < 32) {
        const char* src = W1 + (long)(sl + 1) * 8192;
#pragma unroll
        for (int i = 0; i < 4; ++i) bw[i] = *(const bf16x8_t*)(src + boff[i]);
      } else {
#pragma unroll
        for (int i = 0; i < 4; ++i) bw[i] = bv[i];
      }
      __builtin_amdgcn_s_setprio(1);
#pragma unroll
      for (int ni = 0; ni < 4; ++ni)
        acc[ni] = __builtin_amdgcn_mfma_f32_16x16x32_bf16(afr[ks], bv[ni], acc[ni], 0, 0, 0);
      __builtin_amdgcn_s_setprio(0);
#pragma unroll
      for (int i = 0; i < 4; ++i) bv[i] = bw[i];
    }
#pragma unroll
    for (int ni = 0; ni < 4; ++ni) {
      const int col = np * 128 + wc + ni * 16 + cbase;
      const int slog = col >> 3;
#pragma unroll
      for (int j = 0; j < 4; ++j) {
        const int row = wr + rbase + j;
        const float s = acc[ni][j] + b1[col];
        const float o = 0.5f * s * (1.f + erff(s * 0.70710678118654752f));
        *(ushort*)(Ts + row * 1024 + ((slog ^ (row & 7)) << 4) + (col & 7) * 2) = f2bf(o);
      }
      acc[ni] = zero;
    }
  }
  __syncthreads();   // t tile complete

  // ---- ffn2: 2 panels x 16 k-steps, A from Ts, W2->reg ----
  const char* W2 = (const char*)W2k;
  f32x4_t xnv[2][4];
  const long rq16 = (m0 >> 4) + (wr >> 4);
  bf16x8_t bv2[4];
#pragma unroll
  for (int i = 0; i < 4; ++i) bv2[i] = *(const bf16x8_t*)(W2 + boff[i]);
  for (int pp = 0; pp < 2; ++pp) {
#pragma unroll
    for (int ks = 0; ks < 16; ++ks) {
      const int sl = pp * 16 + ks;
      bf16x8_t bw[4];
      if (sl + 1 < 32) {
        const char* src = W2 + (long)(sl + 1) * 8192;
#pragma unroll
        for (int i = 0; i < 4; ++i) bw[i] = *(const bf16x8_t*)(src + boff[i]);
      } else {
#pragma unroll
        for (int i = 0; i < 4; ++i) bw[i] = bv2[i];
      }
      const bf16x8_t af = *(const bf16x8_t*)(
          Ts + ar * 1024 + (((ks * 4 + kslot) ^ (ar & 7)) << 4));
      __builtin_amdgcn_s_setprio(1);
#pragma unroll
      for (int ni = 0; ni < 4; ++ni)
        acc[ni] = __builtin_amdgcn_mfma_f32_16x16x32_bf16(af, bv2[ni], acc[ni], 0, 0, 0);
      __builtin_amdgcn_s_setprio(0);
#pragma unroll
      for (int i = 0; i < 4; ++i) bv2[i] = bw[i];
    }
#pragma unroll
    for (int ni = 0; ni < 4; ++ni) {
      const int colq = pp * 8 + (wid & 1) * 4 + ni;
      const int col = pp * 128 + wc + ni * 16 + cbase;
      const ushort4 x4 = *(const ushort4*)(xP + (rq16 * 16 + colq) * 256 + lane * 4);
#pragma unroll
      for (int j = 0; j < 4; ++j) {
        const float xo = bf2f(j == 0 ? x4.x : (j == 1 ? x4.y : (j == 2 ? x4.z : x4.w)));
        xnv[pp][ni][j] = xo + acc[ni][j] + b2[col];
      }
      acc[ni] = zero;
    }
  }
  // ---- LN stats ----
#pragma unroll
  for (int j = 0; j < 4; ++j) {
    float ps = 0.f, pq = 0.f;
#pragma unroll
    for (int pp = 0; pp < 2; ++pp)
#pragma unroll
      for (int ni = 0; ni < 4; ++ni) { const float v = xnv[pp][ni][j]; ps += v; pq += v * v; }
#pragma unroll
    for (int off = 1; off < 16; off <<= 1) {
      ps += __shfl_xor(ps, off, 64);
      pq += __shfl_xor(pq, off, 64);
    }
    if ((lane & 15) == 0) {
      const int row = wr + rbase + j;
      lsum[row][wid & 1] = ps;
      lsq[row][wid & 1] = pq;
    }
  }
  __syncthreads();
  if (writex) {
#pragma unroll
    for (int pp = 0; pp < 2; ++pp) {
#pragma unroll
      for (int ni = 0; ni < 4; ++ni) {
        const int colq = pp * 8 + (wid & 1) * 4 + ni;
        ushort4 o4;
        o4.x = f2bf(xnv[pp][ni][0]);
        o4.y = f2bf(xnv[pp][ni][1]);
        o4.z = f2bf(xnv[pp][ni][2]);
        o4.w = f2bf(xnv[pp][ni][3]);
        *(ushort4*)(xP + (rq16 * 16 + colq) * 256 + lane * 4) = o4;
      }
    }
  }
#pragma unroll
  for (int j = 0; j < 4; ++j) {
    const int row = wr + rbase + j;
    const float sm = lsum[row][0] + lsum[row][1];
    const float q = lsq[row][0] + lsq[row][1];
    const float mean = sm * (1.f / 256.f);
    const float rstd = rsqrtf(q * (1.f / 256.f) - mean * mean + 1e-5f);
#pragma unroll
    for (int pp = 0; pp < 2; ++pp)
#pragma unroll
      for (int ni = 0; ni < 4; ++ni) {
        const int col = pp * 128 + wc + ni * 16 + cbase;
        *(ushort*)(Ts + row * 512 + col * 2) =
            f2bf((xnv[pp][ni][j] - mean) * rstd * lng[col] + lnb[col]);
      }
  }
  __syncthreads();
#pragma unroll
  for (int rr = 0; rr < 4; ++rr) {
    const int byte = rr * 4096 + t * 16;
    const int row = byte >> 9, off = byte & 511;
    const bf16x8_t v = *(const bf16x8_t*)(Ts + byte);
    *(bf16x8_t*)((char*)y + (m0 + row) * 512 + off) = v;
  }
}

// ========== gemm_ws v2 (head out-proj): barrier-free, MODE 3 relu ==========
template <int NP, int MODE>
__global__ __launch_bounds__(256)
void gemm_ws(const ushort* __restrict__ A, const ushort* __restrict__ Wks,
             const float* __restrict__ b1, ushort* __restrict__ outp) {
  constexpr int KS = 8;
  constexpr int N = NP * 128;
  constexpr int T = NP * KS;
  __shared__ __align__(16) char AsB[128 * 512];

  const int t = threadIdx.x, lane = t & 63, wid = t >> 6;
  const long m0 = (long)blockIdx.x * 128;
  const int wr = (wid >> 1) * 64, wc = (wid & 1) * 64;
  const char* Ab = (const char*)A;
  const char* Wb = (const char*)Wks;

  {
    const int arow = lane >> 5;
    const int aps  = lane & 31;
#pragma unroll
    for (int j = 0; j < 16; ++j) {
      const int r = j * 8 + wid * 2 + arow;
      gload_lds16(Ab + (m0 + r) * 512 + (long)((aps ^ (r & 7)) << 4),
                  AsB + (j * 8 + wid * 2) * 512);
    }
  }

  const int krow = lane & 15, kslot = lane >> 4;
  int abase[4], akey[4], boff[4];
#pragma unroll
  for (int i = 0; i < 4; ++i) {
    const int ar = wr + i * 16 + krow;
    abase[i] = ar * 512;
    akey[i] = ar & 7;
    const int br = wc + i * 16 + krow;
    boff[i] = br * 64 + ((kslot ^ ((br >> 1) & 3)) << 4);
  }

  const f32x4_t zero = {0.f, 0.f, 0.f, 0.f};
  f32x4_t acc[4][4];
#pragma unroll
  for (int i = 0; i < 4; ++i)
#pragma unroll
    for (int j = 0; j < 4; ++j) acc[i][j] = zero;

  const int rbase = (lane >> 4) * 4, cbase = lane & 15;

  __syncthreads();

  bf16x8_t bv[4];
#pragma unroll
  for (int i = 0; i < 4; ++i) bv[i] = *(const bf16x8_t*)(Wb + boff[i]);

  for (int tau = 0; tau < T; ++tau) {
    bf16x8_t bw[4];
    if (tau + 1 < T) {
      const char* src = Wb + (long)(tau + 1) * 8192;
#pragma unroll
      for (int i = 0; i < 4; ++i) bw[i] = *(const bf16x8_t*)(src + boff[i]);
    } else {
#pragma unroll
      for (int i = 0; i < 4; ++i) bw[i] = bv[i];
    }
    const int ks = tau & 7;
    bf16x8_t af[4];
#pragma unroll
    for (int i = 0; i < 4; ++i)
      af[i] = *(const bf16x8_t*)(AsB + abase[i] + ((((ks << 2) | kslot) ^ akey[i]) << 4));
    __builtin_amdgcn_s_setprio(1);
#pragma unroll
    for (int mi = 0; mi < 4; ++mi)
#pragma unroll
      for (int ni = 0; ni < 4; ++ni)
        acc[mi][ni] = __builtin_amdgcn_mfma_f32_16x16x32_bf16(af[mi], bv[ni], acc[mi][ni], 0, 0, 0);
    __builtin_amdgcn_s_setprio(0);
#pragma unroll
    for (int i = 0; i < 4; ++i) bv[i] = bw[i];

    if (ks == KS - 1) {
      const int np = tau >> 3;
#pragma unroll
      for (int mi = 0; mi < 4; ++mi) {
#pragma unroll
        for (int ni = 0; ni < 4; ++ni) {
          const int col = np * 128 + wc + ni * 16 + cbase;
#pragma unroll
          for (int j = 0; j < 4; ++j) {
            const long row = m0 + wr + mi * 16 + rbase + j;
            float s = acc[mi][ni][j] + b1[col];
            float o;
            if constexpr (MODE == 2) o = 0.5f * s * (1.f + erff(s * 0.70710678118654752f));
            else                     o = fmaxf(s, 0.f);
            outp[row * N + col] = f2bf(o);
          }
          acc[mi][ni] = zero;
        }
      }
    }
  }
}

// ========== input projection: N=256 GEMM (fp32 A fused convert) + LN ==========
template <int K, int MODE, bool AFP32>
__global__ __launch_bounds__(512)
void gemm_ln(const void* __restrict__ Ap, const ushort* __restrict__ W,
             const float* __restrict__ b1, ushort* __restrict__ xP,
             const float* __restrict__ lng, const float* __restrict__ lnb,
             ushort* __restrict__ y, int writex) {
  constexpr int KS = K / 32;
  __shared__ __align__(16) char WsB[2 * 16384];
  __shared__ __align__(16) char AsB[2 * 8192];
  __shared__ float lsum4[128][4], lsq4[128][4];

  const int t = threadIdx.x, lane = t & 63, wid = t >> 6;
  const int wr = (wid >> 2) * 64, wc = (wid & 3) * 64;
  const int lr = lane >> 2, lc = lane & 3;
  const int ra = wid * 16 + lr;
  const int slog = lc ^ swzkey(ra);
  const int saA = slog << 4;
  const int rw0 = wid * 32 + lr, rw1 = rw0 + 16;
  const int sw0 = (lc ^ swzkey(rw0)) << 4;
  const int sw1 = (lc ^ swzkey(rw1)) << 4;
  const char* Ab = (const char*)Ap;
  const char* Wb = (const char*)W;
  constexpr long K2 = (long)K * 2;
  const long m0 = (long)blockIdx.x * 128;

  auto stageA = [&](int tau2) {
    char* dst = AsB + (tau2 & 1) * 8192 + wid * 1024 + lane * 16;
    if constexpr (AFP32) {
      const float* src = (const float*)Ap + (m0 + ra) * K + tau2 * 32 + slog * 8;
      const float4 q0 = ((const float4*)src)[0];
      const float4 q1 = ((const float4*)src)[1];
      bf16x8_t v;
      v[0] = (short)f2bf(q0.x); v[1] = (short)f2bf(q0.y);
      v[2] = (short)f2bf(q0.z); v[3] = (short)f2bf(q0.w);
      v[4] = (short)f2bf(q1.x); v[5] = (short)f2bf(q1.y);
      v[6] = (short)f2bf(q1.z); v[7] = (short)f2bf(q1.w);
      *(bf16x8_t*)dst = v;
    } else {
      gload_lds16(Ab + (m0 + ra) * K2 + (long)tau2 * 64 + saA,
                  AsB + (tau2 & 1) * 8192 + wid * 1024);
    }
  };

  gload_lds16(Wb + (long)rw0 * K2 + sw0, WsB + wid * 2048);
  gload_lds16(Wb + (long)rw1 * K2 + sw1, WsB + wid * 2048 + 1024);
  stageA(0);

  const int krow = lane & 15, kslot = lane >> 4;
  int aoff[4], boff[4];
#pragma unroll
  for (int i = 0; i < 4; ++i) {
    int ar = wr + i * 16 + krow;
    aoff[i] = ar * 64 + ((kslot ^ swzkey(ar)) << 4);
    int br = wc + i * 16 + krow;
    boff[i] = br * 64 + ((kslot ^ swzkey(br)) << 4);
  }

  const f32x4_t zero = {0.f, 0.f, 0.f, 0.f};
  f32x4_t acc[4][4];
#pragma unroll
  for (int i = 0; i < 4; ++i)
#pragma unroll
    for (int j = 0; j < 4; ++j) acc[i][j] = zero;

  for (int tau = 0; tau < KS; ++tau) {
    __syncthreads();
    if (tau + 1 < KS) {
      stageA(tau + 1);
      const long kb = (long)(tau + 1) * 64;
      char* wd = WsB + ((tau + 1) & 1) * 16384 + wid * 2048;
      gload_lds16(Wb + (long)rw0 * K2 + kb + sw0, wd);
      gload_lds16(Wb + (long)rw1 * K2 + kb + sw1, wd + 1024);
    }
    const char* Ac = AsB + (tau & 1) * 8192;
    const char* Wc = WsB + (tau & 1) * 16384;
    bf16x8_t af[4], bv[4];
#pragma unroll
    for (int i = 0; i < 4; ++i) af[i] = *(const bf16x8_t*)(Ac + aoff[i]);
#pragma unroll
    for (int i = 0; i < 4; ++i) bv[i] = *(const bf16x8_t*)(Wc + boff[i]);
#pragma unroll
    for (int mi = 0; mi < 4; ++mi)
#pragma unroll
      for (int ni = 0; ni < 4; ++ni)
        acc[mi][ni] = __builtin_amdgcn_mfma_f32_16x16x32_bf16(af[mi], bv[ni], acc[mi][ni], 0, 0, 0);
  }

  const int rbase = (lane >> 4) * 4;
  const int cbase = lane & 15;
  const long xbB = (long)blockIdx.x * 32768;
#pragma unroll
  for (int mi = 0; mi < 4; ++mi) {
    const int rq = (wid >> 2) * 4 + mi;
#pragma unroll
    for (int ni = 0; ni < 4; ++ni) {
      const int col = wc + ni * 16 + cbase;
      const int cq = (wid & 3) * 4 + ni;
      ushort4 x4;
      if constexpr (MODE == 3) x4 = *(const ushort4*)(xP + xbB + ((rq * 16 + cq) * 64 + lane) * 4);
#pragma unroll
      for (int j = 0; j < 4; ++j) {
        float v = acc[mi][ni][j] + b1[col];
        if constexpr (MODE == 3)
          v += bf2f(j == 0 ? x4.x : (j == 1 ? x4.y : (j == 2 ? x4.z : x4.w)));
        acc[mi][ni][j] = v;
      }
    }
  }
#pragma unroll
  for (int mi = 0; mi < 4; ++mi) {
#pragma unroll
    for (int j = 0; j < 4; ++j) {
      float ps = 0.f, pq = 0.f;
#pragma unroll
      for (int ni = 0; ni < 4; ++ni) { float v = acc[mi][ni][j]; ps += v; pq += v * v; }
#pragma unroll
      for (int off = 1; off < 16; off <<= 1) {
        ps += __shfl_xor(ps, off, 64);
        pq += __shfl_xor(pq, off, 64);
      }
      if ((lane & 15) == 0) {
        int r = wr + mi * 16 + (lane >> 4) * 4 + j;
        lsum4[r][wid & 3] = ps;
        lsq4[r][wid & 3] = pq;
      }
    }
  }
  __syncthreads();
#pragma unroll
  for (int mi = 0; mi < 4; ++mi) {
    const int rq = (wid >> 2) * 4 + mi;
#pragma unroll
    for (int ni = 0; ni < 4; ++ni) {
      const int cq = (wid & 3) * 4 + ni;
      if (writex) {
        ushort4 o4;
        o4.x = f2bf(acc[mi][ni][0]);
        o4.y = f2bf(acc[mi][ni][1]);
        o4.z = f2bf(acc[mi][ni][2]);
        o4.w = f2bf(acc[mi][ni][3]);
        *(ushort4*)(xP + xbB + ((rq * 16 + cq) * 64 + lane) * 4) = o4;
      }
    }
  }
#pragma unroll
  for (int mi = 0; mi < 4; ++mi) {
#pragma unroll
    for (int j = 0; j < 4; ++j) {
      const int r = wr + mi * 16 + rbase + j;
      const float s = lsum4[r][0] + lsum4[r][1] + lsum4[r][2] + lsum4[r][3];
      const float q = lsq4[r][0] + lsq4[r][1] + lsq4[r][2] + lsq4[r][3];
      const float mean = s * (1.f / 256.f);
      const float rstd = rsqrtf(q * (1.f / 256.f) - mean * mean + 1e-5f);
      const long row = m0 + r;
#pragma unroll
      for (int ni = 0; ni < 4; ++ni) {
        const int col = wc + ni * 16 + cbase;
        y[row * 256 + col] = f2bf((acc[mi][ni][j] - mean) * rstd * lng[col] + lnb[col]);
      }
    }
  }
}

// ========== head_agg ==========
__global__ __launch_bounds__(256)
void head_agg(const ushort* __restrict__ y, const float* __restrict__ attw,
              ushort* __restrict__ vb) {
  const int t = threadIdx.x, lane = t & 63, w = t >> 6;
  const long b = (long)blockIdx.x * 4 + w;
  const ushort* yb = y + b * 16 * 256;
  const float4 w2 = *(const float4*)(attw + 256 + lane * 4);

  float4 rows[16];
  float lg[16];
#pragma unroll
  for (int r = 0; r < 16; ++r) {
    const ushort4 u = *(const ushort4*)(yb + r * 256 + lane * 4);
    float4 v4;
    v4.x = bf2f(u.x); v4.y = bf2f(u.y); v4.z = bf2f(u.z); v4.w = bf2f(u.w);
    rows[r] = v4;
    if (r >= 1) {
      float s = v4.x * w2.x + v4.y * w2.y + v4.z * w2.z + v4.w * w2.w;
#pragma unroll
      for (int off = 32; off > 0; off >>= 1) s += __shfl_xor(s, off, 64);
      lg[r] = s;
    }
  }
  float mx = -1e30f;
#pragma unroll
  for (int r = 1; r < 16; ++r) mx = fmaxf(mx, lg[r]);
  float den = 0.f;
#pragma unroll
  for (int r = 1; r < 16; ++r) { lg[r] = expf(lg[r] - mx); den += lg[r]; }
  const float inv = 1.f / den;
  float4 v = rows[0];
#pragma unroll
  for (int r = 1; r < 16; ++r) {
    const float a = lg[r] * inv;
    v.x += a * rows[r].x; v.y += a * rows[r].y;
    v.z += a * rows[r].z; v.w += a * rows[r].w;
  }
  ushort4 o;
  o.x = f2bf(v.x); o.y = f2bf(v.y); o.z = f2bf(v.z); o.w = f2bf(v.w);
  *(ushort4*)(vb + b * 256 + lane * 4) = o;
}

// ========== head_cls ==========
__global__ __launch_bounds__(256)
void head_cls(const ushort* __restrict__ o1b, const float* __restrict__ cw,
              const float* __restrict__ cb, float* __restrict__ out) {
  __shared__ float lw[4][40];
  const int t = threadIdx.x, lane = t & 63, w = t >> 6;
  const long b = (long)blockIdx.x * 4 + w;
  const ushort2 u = *(const ushort2*)(o1b + b * 128 + lane * 2);
  const float o1x = bf2f(u.x), o1y = bf2f(u.y);

#pragma unroll
  for (int o = 0; o < 40; ++o) {
    const float2 c = *(const float2*)(cw + o * 128 + lane * 2);
    float p = o1x * c.x + o1y * c.y;
#pragma unroll
    for (int off = 32; off > 0; off >>= 1) p += __shfl_xor(p, off, 64);
    if (lane == 0) lw[w][o] = p + cb[o];
  }
  const float v = (lane < 40) ? lw[w][lane] : -1e30f;
  float mx = v;
#pragma unroll
  for (int off = 32; off > 0; off >>= 1) mx = fmaxf(mx, __shfl_xor(mx, off, 64));
  float e = (lane < 40) ? expf(v - mx) : 0.f;
  float den = e;
#pragma unroll
  for (int off = 32; off > 0; off >>= 1) den += __shfl_xor(den, off, 64);
  if (lane < 40) out[b * 40 + lane] = v - mx - logf(den);
}

// ---------------- host ----------------
extern "C" void kernel_launch(void* const* d_in, const int* in_sizes, int n_in,
                              void* d_out, int out_size, void* d_ws, size_t ws_size,
                              hipStream_t stream) {
  const float* data   = (const float*)d_in[0];
  const float* in_w   = (const float*)d_in[1];
  const float* in_b   = (const float*)d_in[2];
  const float* norm_g = (const float*)d_in[3];
  const float* norm_b = (const float*)d_in[4];
  const float* A_w    = (const float*)d_in[5];
  const float* B_w    = (const float*)d_in[6];
  const float* C_w    = (const float*)d_in[7];
  const float* D_w    = (const float*)d_in[8];
  const float* D_b    = (const float*)d_in[9];
  const float* gate_w = (const float*)d_in[10];
  const float* gate_b = (const float*)d_in[11];
  const float* ffn_w1 = (const float*)d_in[12];
  const float* ffn_b1 = (const float*)d_in[13];
  const float* ffn_w2 = (const float*)d_in[14];
  const float* ffn_b2 = (const float*)d_in[15];
  const float* fln_g  = (const float*)d_in[16];
  const float* fln_b  = (const float*)d_in[17];
  const float* out_w  = (const float*)d_in[18];
  const float* out_b  = (const float*)d_in[19];
  const float* cls_w  = (const float*)d_in[20];
  const float* cls_b  = (const float*)d_in[21];
  const float* attn_w = (const float*)d_in[22];
  const float* attn_b = (const float*)d_in[23];
  (void)in_sizes; (void)n_in; (void)out_size; (void)ws_size; (void)attn_b;

  char* ws = (char*)d_ws;
  ushort* xP     = (ushort*)(ws + 0);           // packed x
  ushort* y      = (ushort*)(ws + 67108864);    // row-major y
  ushort* tzp    = (ushort*)(ws + 134217728);   // vb+o1b scratch
  ushort* wcat   = (ushort*)(ws + 318767104);
  ushort* inwb   = (ushort*)(ws + 320733184);
  ushort* w1b    = (ushort*)(ws + 320995328);
  ushort* w2b    = (ushort*)(ws + 322568192);
  ushort* cwb    = (ushort*)(ws + 324141056);
  ushort* mslice = (ushort*)(ws + 324337664);   // 6 x 44 slices
  ushort* w1k    = (ushort*)(ws + 326500352);   // 6*512*256 (k-sliced)
  ushort* owb    = (ushort*)(ws + 328073216);
  ushort* owk    = (ushort*)(ws + 328138752);
  ushort* w2k    = (ushort*)(ws + 328204288);   // 6*256*512 (k-sliced K=512)
  ushort* vb     = tzp;
  ushort* o1b    = tzp + 2097152;

  cvt_kernel<<<512, 256, 0, stream>>>(in_w, inwb, 131072);
  cvt_kernel<<<3072, 256, 0, stream>>>(ffn_w1, w1b, 786432);
  cvt_kernel<<<3072, 256, 0, stream>>>(ffn_w2, w2b, 786432);
  cvt_kernel<<<384, 256, 0, stream>>>(C_w, cwb, 98304);
  cvt_kernel<<<128, 256, 0, stream>>>(out_w, owb, 32768);
  build_wcat<<<3840, 256, 0, stream>>>(A_w, B_w, gate_w, D_w, wcat);
  repack_gen<<<3840, 256, 0, stream>>>(wcat, mslice, 256, 163840, 180224, 0, 6L * 163840);
  repack_gen<<<384, 256, 0, stream>>>(cwb, mslice, 64, 16384, 180224, 163840, 6L * 16384);
  repack_gen<<<3072, 256, 0, stream>>>(w1b, w1k, 256, 131072, 131072, 0, 6L * 131072);
  repack_gen<<<3072, 256, 0, stream>>>(w2b, w2k, 512, 131072, 131072, 0, 6L * 131072);
  repack_gen<<<128, 256, 0, stream>>>(owb, owk, 256, 32768, 32768, 0, 32768);

  // input proj (fp32 A, fused convert) + fused LN(layer0): xP (packed), y
  gemm_ln<512, 0, true><<<dim3(1024), 512, 0, stream>>>(
      data, inwb, in_b, xP, norm_g, norm_b, y, 1);

  for (int l = 0; l < 6; ++l) {
    mamba_fused<<<4096, 256, 0, stream>>>(
        y, xP, mslice + (size_t)l * 180224,
        gate_b + l * 256, D_b + l * 256, norm_g + l * 256, norm_b + l * 256);
    const float* lg2 = (l < 5) ? (norm_g + (l + 1) * 256) : fln_g;
    const float* lb2 = (l < 5) ? (norm_b + (l + 1) * 256) : fln_b;
    ffn_fused2<<<4096, 256, 0, stream>>>(
        y, xP, w1k + (size_t)l * 131072, w2k + (size_t)l * 131072,
        ffn_b1 + l * 512, ffn_b2 + l * 256, lg2, lb2, (l < 5) ? 1 : 0);
  }

  // head: attention-agg -> out-proj GEMM (relu) -> cls + log_softmax
  head_agg<<<2048, 256, 0, stream>>>(y, attn_w, vb);
  gemm_ws<1, 3><<<64, 256, 0, stream>>>(vb, owk, out_b, o1b);
  head_cls<<<2048, 256, 0, stream>>>(o1b, cls_w, cls_b, (float*)d_out);
}

// Round 20
// 1981.492 us; speedup vs baseline: 1.3093x; 1.0016x over previous
//
#include <hip/hip_runtime.h>

typedef __attribute__((ext_vector_type(8))) short bf16x8_t;
typedef __attribute__((ext_vector_type(4))) float f32x4_t;

__device__ __forceinline__ ushort f2bf(float x) {
  union { float f; unsigned u; } a; a.f = x;
  unsigned r = a.u + 0x7fffu + ((a.u >> 16) & 1u);
  return (ushort)(r >> 16);
}
__device__ __forceinline__ float bf2f(ushort s) {
  union { unsigned u; float f; } a; a.u = ((unsigned)s) << 16;
  return a.f;
}
__device__ __forceinline__ void gload_lds16(const void* g, void* l) {
  __builtin_amdgcn_global_load_lds(
      (const __attribute__((address_space(1))) unsigned int*)g,
      (__attribute__((address_space(3))) unsigned int*)l, 16, 0, 0);
}
__device__ __forceinline__ int swzkey(int r) { return ((r >> 2) ^ r) & 3; }

// ---------------- weight conversion ----------------
__global__ void cvt_kernel(const float* __restrict__ s, ushort* __restrict__ d, int n) {
  int i = blockIdx.x * 256 + threadIdx.x;
  if (i < n) d[i] = f2bf(s[i]);
}

// Wcat[l][r][c], r: 0-63 A_w, 64-127 B_w, 128-383 gate_w, 384-639 D_w
__global__ void build_wcat(const float* __restrict__ Aw, const float* __restrict__ Bw,
                           const float* __restrict__ gw, const float* __restrict__ Dw,
                           ushort* __restrict__ out) {
  int i = blockIdx.x * 256 + threadIdx.x;
  if (i >= 6 * 640 * 256) return;
  int l = i / (640 * 256), r = (i / 256) % 640, c = i % 256;
  float v;
  if (r < 64)        v = Aw[((l * 64 + r) * 256) + c];
  else if (r < 128)  v = Bw[((l * 64 + (r - 64)) * 256) + c];
  else if (r < 384)  v = gw[((l * 256 + (r - 128)) * 256) + c];
  else               v = Dw[((l * 256 + (r - 384)) * 256) + c];
  out[i] = f2bf(v);
}

// repack row-major [N][K] bf16 -> k-sliced [p][ks][r][s][e]; slice = 8KB contiguous.
__global__ void repack_gen(const ushort* __restrict__ src, ushort* __restrict__ dst,
                           int K, int perMat, int dstPerMat, int dstOff, long total) {
  const long i = (long)blockIdx.x * 256 + threadIdx.x;
  if (i >= total) return;
  const int m = (int)(i / perMat);
  const int idx = (int)(i % perMat);
  const int slice = idx >> 12;
  const int ksn = K >> 5;
  const int p = slice / ksn, ks = slice - p * ksn;
  const int r = (idx >> 5) & 127;
  const int s = (idx >> 3) & 3;
  const int e = idx & 7;
  const int k = ks * 32 + ((s ^ ((r >> 1) & 3)) << 3) + e;
  dst[(long)m * dstPerMat + dstOff + idx] = src[(long)m * perMat + (p * 128 + r) * K + k];
}

// ========== FUSED MAMBA LAYER v4 (R17-proven) ==========
__global__ __launch_bounds__(256, 3)
void mamba_fused(ushort* __restrict__ y, ushort* __restrict__ xP,
                 const ushort* __restrict__ Wk,
                 const float* __restrict__ gb, const float* __restrict__ db,
                 const float* __restrict__ lng, const float* __restrict__ lnb) {
  __shared__ __align__(16) char WsB[2 * 16384];
  __shared__ __align__(16) ushort ab[32 * 136];
  __shared__ __align__(16) char HsB[4096];
  __shared__ float lsum[32][2], lsq[32][2];

  const int t = threadIdx.x, lane = t & 63, wid = t >> 6;
  const long m0 = (long)blockIdx.x * 32;
  const int wr = (wid >> 1) * 16, wc = (wid & 1) * 64;
  const int co4 = wid * 4;
  const char* Wb = (const char*)Wk;

  const int krow = lane & 15, kslot = lane >> 4;
  const int ar = wr + krow;

  bf16x8_t afr[8];
  {
    const char* yrow = (const char*)y + (m0 + ar) * 512 + kslot * 16;
#pragma unroll
    for (int ks = 0; ks < 8; ++ks) afr[ks] = *(const bf16x8_t*)(yrow + ks * 64);
  }
#pragma unroll
  for (int c = 0; c < 4; ++c)
    gload_lds16(Wb + (co4 + c) * 1024 + lane * 16, WsB + (co4 + c) * 1024);

  int boff[4];
#pragma unroll
  for (int i = 0; i < 4; ++i) {
    const int br = wc + i * 16 + krow;
    boff[i] = br * 64 + ((kslot ^ ((br >> 1) & 3)) << 4);
  }
  const int rbase = (lane >> 4) * 4, cbase = lane & 15;

  const f32x4_t zero = {0.f, 0.f, 0.f, 0.f};
  f32x4_t acc[4];
#pragma unroll
  for (int i = 0; i < 4; ++i) acc[i] = zero;

  int pair = 0;
  auto kstep2 = [&](bf16x8_t afa, bf16x8_t afb) {
    __syncthreads();
    if (pair + 1 < 22) {
      const char* src = Wb + (long)(pair + 1) * 16384;
      char* dst = WsB + ((pair + 1) & 1) * 16384;
#pragma unroll
      for (int c = 0; c < 4; ++c)
        gload_lds16(src + (co4 + c) * 1024 + lane * 16, dst + (co4 + c) * 1024);
    }
    const char* Wc = WsB + (pair & 1) * 16384;
    bf16x8_t bva[4], bvb[4];
#pragma unroll
    for (int i = 0; i < 4; ++i) bva[i] = *(const bf16x8_t*)(Wc + boff[i]);
#pragma unroll
    for (int i = 0; i < 4; ++i) bvb[i] = *(const bf16x8_t*)(Wc + 8192 + boff[i]);
    __builtin_amdgcn_s_setprio(1);
#pragma unroll
    for (int ni = 0; ni < 4; ++ni)
      acc[ni] = __builtin_amdgcn_mfma_f32_16x16x32_bf16(afa, bva[ni], acc[ni], 0, 0, 0);
#pragma unroll
    for (int ni = 0; ni < 4; ++ni)
      acc[ni] = __builtin_amdgcn_mfma_f32_16x16x32_bf16(afb, bvb[ni], acc[ni], 0, 0, 0);
    __builtin_amdgcn_s_setprio(0);
    ++pair;
  };

#pragma unroll
  for (int p = 0; p < 4; ++p) kstep2(afr[2 * p], afr[2 * p + 1]);
#pragma unroll
  for (int ni = 0; ni < 4; ++ni) {
    const int col = wc + ni * 16 + cbase;
#pragma unroll
    for (int j = 0; j < 4; ++j) {
      const int row = wr + rbase + j;
      const float v = acc[ni][j];
      ab[row * 136 + col] = f2bf(col < 64 ? tanhf(v) : v);
    }
    acc[ni] = zero;
  }
  __syncthreads();
  if (t < 128) {
    const int b = t >> 6, d = t & 63;
    float av[16], btv[16];
#pragma unroll
    for (int s = 0; s < 16; ++s) {
      const int row = b * 16 + s;
      av[s]  = bf2f(ab[row * 136 + d]);
      btv[s] = bf2f(ab[row * 136 + 64 + d]);
    }
    float h = 0.f;
#pragma unroll
    for (int s = 0; s < 16; ++s) {
      h = fmaf(av[s], h, btv[s]);
      const int row = b * 16 + s;
      *(ushort*)(HsB + row * 128 + (((d >> 3) ^ (row & 7)) << 4) + (d & 7) * 2) = f2bf(h);
    }
  }

  f32x4_t gsv[2][4], dsv[2][4], xnv[2][4];
#pragma unroll
  for (int pp = 0; pp < 2; ++pp) {
#pragma unroll
    for (int p = 0; p < 4; ++p) kstep2(afr[2 * p], afr[2 * p + 1]);
#pragma unroll
    for (int ni = 0; ni < 4; ++ni) {
      const int col = pp * 128 + wc + ni * 16 + cbase;
#pragma unroll
      for (int j = 0; j < 4; ++j) {
        const float s = acc[ni][j] + gb[col];
        gsv[pp][ni][j] = 1.f / (1.f + expf(-s));
      }
      acc[ni] = zero;
    }
  }
#pragma unroll
  for (int pp = 0; pp < 2; ++pp) {
#pragma unroll
    for (int p = 0; p < 4; ++p) kstep2(afr[2 * p], afr[2 * p + 1]);
#pragma unroll
    for (int ni = 0; ni < 4; ++ni) {
      const int col = pp * 128 + wc + ni * 16 + cbase;
#pragma unroll
      for (int j = 0; j < 4; ++j) dsv[pp][ni][j] = acc[ni][j] + db[col];
      acc[ni] = zero;
    }
  }
  const long rq16 = (m0 >> 4) + (wr >> 4);
#pragma unroll
  for (int pp = 0; pp < 2; ++pp) {
    const bf16x8_t afh0 = *(const bf16x8_t*)(
        HsB + (ar << 7) + ((kslot ^ (ar & 7)) << 4));
    const bf16x8_t afh1 = *(const bf16x8_t*)(
        HsB + (ar << 7) + (((4 | kslot) ^ (ar & 7)) << 4));
    kstep2(afh0, afh1);
#pragma unroll
    for (int ni = 0; ni < 4; ++ni) {
      const int colq = pp * 8 + (wid & 1) * 4 + ni;
      const ushort4 x4 = *(const ushort4*)(xP + (rq16 * 16 + colq) * 256 + lane * 4);
#pragma unroll
      for (int j = 0; j < 4; ++j) {
        const float g = gsv[pp][ni][j], dv = dsv[pp][ni][j];
        const float xo = bf2f(j == 0 ? x4.x : (j == 1 ? x4.y : (j == 2 ? x4.z : x4.w)));
        xnv[pp][ni][j] = xo + acc[ni][j] * g + dv * (1.f - g);
      }
      acc[ni] = zero;
    }
  }
#pragma unroll
  for (int j = 0; j < 4; ++j) {
    float ps = 0.f, pq = 0.f;
#pragma unroll
    for (int pp = 0; pp < 2; ++pp)
#pragma unroll
      for (int ni = 0; ni < 4; ++ni) { const float v = xnv[pp][ni][j]; ps += v; pq += v * v; }
#pragma unroll
    for (int off = 1; off < 16; off <<= 1) {
      ps += __shfl_xor(ps, off, 64);
      pq += __shfl_xor(pq, off, 64);
    }
    if ((lane & 15) == 0) {
      const int row = wr + rbase + j;
      lsum[row][wid & 1] = ps;
      lsq[row][wid & 1] = pq;
    }
  }
  __syncthreads();
#pragma unroll
  for (int pp = 0; pp < 2; ++pp) {
#pragma unroll
    for (int ni = 0; ni < 4; ++ni) {
      const int colq = pp * 8 + (wid & 1) * 4 + ni;
      ushort4 o4;
      o4.x = f2bf(xnv[pp][ni][0]);
      o4.y = f2bf(xnv[pp][ni][1]);
      o4.z = f2bf(xnv[pp][ni][2]);
      o4.w = f2bf(xnv[pp][ni][3]);
      *(ushort4*)(xP + (rq16 * 16 + colq) * 256 + lane * 4) = o4;
    }
  }
#pragma unroll
  for (int j = 0; j < 4; ++j) {
    const int row = wr + rbase + j;
    const float sm = lsum[row][0] + lsum[row][1];
    const float q = lsq[row][0] + lsq[row][1];
    const float mean = sm * (1.f / 256.f);
    const float rstd = rsqrtf(q * (1.f / 256.f) - mean * mean + 1e-5f);
#pragma unroll
    for (int pp = 0; pp < 2; ++pp)
#pragma unroll
      for (int ni = 0; ni < 4; ++ni) {
        const int col = pp * 128 + wc + ni * 16 + cbase;
        *(ushort*)(WsB + row * 512 + col * 2) =
            f2bf((xnv[pp][ni][j] - mean) * rstd * lng[col] + lnb[col]);
      }
  }
  __syncthreads();
#pragma unroll
  for (int rr = 0; rr < 4; ++rr) {
    const int byte = rr * 4096 + t * 16;
    const int row = byte >> 9, off = byte & 511;
    const bf16x8_t v = *(const bf16x8_t*)(WsB + byte);
    *(bf16x8_t*)((char*)y + (m0 + row) * 512 + off) = v;
  }
}

// ========== FUSED FFN v2: barrier-free W streams; t in LDS; 3 barriers total ==========
// Block = 32 rows. y in registers; W1k (32 slices, K=256) and W2k (32 slices, K=512)
// stream global->reg; fused residual(packed xP)+LN epilogue.
__global__ __launch_bounds__(256, 3)
void ffn_fused2(ushort* __restrict__ y, ushort* __restrict__ xP,
                const ushort* __restrict__ W1k, const ushort* __restrict__ W2k,
                const float* __restrict__ b1, const float* __restrict__ b2,
                const float* __restrict__ lng, const float* __restrict__ lnb,
                int writex) {
  __shared__ __align__(16) char Ts[32768];   // t tile 32x512 bf16, slot-swizzled
  __shared__ float lsum[32][2], lsq[32][2];

  const int t = threadIdx.x, lane = t & 63, wid = t >> 6;
  const long m0 = (long)blockIdx.x * 32;
  const int wr = (wid >> 1) * 16, wc = (wid & 1) * 64;
  const int krow = lane & 15, kslot = lane >> 4;
  const int ar = wr + krow;
  const int rbase = (lane >> 4) * 4, cbase = lane & 15;

  // y rows -> registers
  bf16x8_t afr[8];
  {
    const char* yrow = (const char*)y + (m0 + ar) * 512 + kslot * 16;
#pragma unroll
    for (int ks = 0; ks < 8; ++ks) afr[ks] = *(const bf16x8_t*)(yrow + ks * 64);
  }

  int boff[4];
#pragma unroll
  for (int i = 0; i < 4; ++i) {
    const int br = wc + i * 16 + krow;
    boff[i] = br * 64 + ((kslot ^ ((br >> 1) & 3)) << 4);
  }

  const f32x4_t zero = {0.f, 0.f, 0.f, 0.f};
  f32x4_t acc[4];
#pragma unroll
  for (int i = 0; i < 4; ++i) acc[i] = zero;

  // ---- ffn1: 4 panels x 8 k-steps, W1->reg, gelu -> Ts ----
  const char* W1 = (const char*)W1k;
  bf16x8_t bv[4];
#pragma unroll
  for (int i = 0; i < 4; ++i) bv[i] = *(const bf16x8_t*)(W1 + boff[i]);
  for (int np = 0; np < 4; ++np) {
#pragma unroll
    for (int ks = 0; ks < 8; ++ks) {
      const int sl = np * 8 + ks;
      bf16x8_t bw[4];
      if (sl + 1 < 32) {
        const char* src = W1 + (long)(sl + 1) * 8192;
#pragma unroll
        for (int i = 0; i < 4; ++i) bw[i] = *(const bf16x8_t*)(src + boff[i]);
      } else {
#pragma unroll
        for (int i = 0; i < 4; ++i) bw[i] = bv[i];
      }
      __builtin_amdgcn_s_setprio(1);
#pragma unroll
      for (int ni = 0; ni < 4; ++ni)
        acc[ni] = __builtin_amdgcn_mfma_f32_16x16x32_bf16(afr[ks], bv[ni], acc[ni], 0, 0, 0);
      __builtin_amdgcn_s_setprio(0);
#pragma unroll
      for (int i = 0; i < 4; ++i) bv[i] = bw[i];
    }
#pragma unroll
    for (int ni = 0; ni < 4; ++ni) {
      const int col = np * 128 + wc + ni * 16 + cbase;
      const int slog = col >> 3;
#pragma unroll
      for (int j = 0; j < 4; ++j) {
        const int row = wr + rbase + j;
        const float s = acc[ni][j] + b1[col];
        const float o = 0.5f * s * (1.f + erff(s * 0.70710678118654752f));
        *(ushort*)(Ts + row * 1024 + ((slog ^ (row & 7)) << 4) + (col & 7) * 2) = f2bf(o);
      }
      acc[ni] = zero;
    }
  }
  __syncthreads();   // t tile complete

  // ---- ffn2: 2 panels x 16 k-steps, A from Ts, W2->reg ----
  const char* W2 = (const char*)W2k;
  f32x4_t xnv[2][4];
  const long rq16 = (m0 >> 4) + (wr >> 4);
  bf16x8_t bv2[4];
#pragma unroll
  for (int i = 0; i < 4; ++i) bv2[i] = *(const bf16x8_t*)(W2 + boff[i]);
  for (int pp = 0; pp < 2; ++pp) {
#pragma unroll
    for (int ks = 0; ks < 16; ++ks) {
      const int sl = pp * 16 + ks;
      bf16x8_t bw[4];
      if (sl + 1 < 32) {
        const char* src = W2 + (long)(sl + 1) * 8192;
#pragma unroll
        for (int i = 0; i < 4; ++i) bw[i] = *(const bf16x8_t*)(src + boff[i]);
      } else {
#pragma unroll
        for (int i = 0; i < 4; ++i) bw[i] = bv2[i];
      }
      const bf16x8_t af = *(const bf16x8_t*)(
          Ts + ar * 1024 + (((ks * 4 + kslot) ^ (ar & 7)) << 4));
      __builtin_amdgcn_s_setprio(1);
#pragma unroll
      for (int ni = 0; ni < 4; ++ni)
        acc[ni] = __builtin_amdgcn_mfma_f32_16x16x32_bf16(af, bv2[ni], acc[ni], 0, 0, 0);
      __builtin_amdgcn_s_setprio(0);
#pragma unroll
      for (int i = 0; i < 4; ++i) bv2[i] = bw[i];
    }
#pragma unroll
    for (int ni = 0; ni < 4; ++ni) {
      const int colq = pp * 8 + (wid & 1) * 4 + ni;
      const int col = pp * 128 + wc + ni * 16 + cbase;
      const ushort4 x4 = *(const ushort4*)(xP + (rq16 * 16 + colq) * 256 + lane * 4);
#pragma unroll
      for (int j = 0; j < 4; ++j) {
        const float xo = bf2f(j == 0 ? x4.x : (j == 1 ? x4.y : (j == 2 ? x4.z : x4.w)));
        xnv[pp][ni][j] = xo + acc[ni][j] + b2[col];
      }
      acc[ni] = zero;
    }
  }
  // ---- LN stats ----
#pragma unroll
  for (int j = 0; j < 4; ++j) {
    float ps = 0.f, pq = 0.f;
#pragma unroll
    for (int pp = 0; pp < 2; ++pp)
#pragma unroll
      for (int ni = 0; ni < 4; ++ni) { const float v = xnv[pp][ni][j]; ps += v; pq += v * v; }
#pragma unroll
    for (int off = 1; off < 16; off <<= 1) {
      ps += __shfl_xor(ps, off, 64);
      pq += __shfl_xor(pq, off, 64);
    }
    if ((lane & 15) == 0) {
      const int row = wr + rbase + j;
      lsum[row][wid & 1] = ps;
      lsq[row][wid & 1] = pq;
    }
  }
  __syncthreads();
  if (writex) {
#pragma unroll
    for (int pp = 0; pp < 2; ++pp) {
#pragma unroll
      for (int ni = 0; ni < 4; ++ni) {
        const int colq = pp * 8 + (wid & 1) * 4 + ni;
        ushort4 o4;
        o4.x = f2bf(xnv[pp][ni][0]);
        o4.y = f2bf(xnv[pp][ni][1]);
        o4.z = f2bf(xnv[pp][ni][2]);
        o4.w = f2bf(xnv[pp][ni][3]);
        *(ushort4*)(xP + (rq16 * 16 + colq) * 256 + lane * 4) = o4;
      }
    }
  }
#pragma unroll
  for (int j = 0; j < 4; ++j) {
    const int row = wr + rbase + j;
    const float sm = lsum[row][0] + lsum[row][1];
    const float q = lsq[row][0] + lsq[row][1];
    const float mean = sm * (1.f / 256.f);
    const float rstd = rsqrtf(q * (1.f / 256.f) - mean * mean + 1e-5f);
#pragma unroll
    for (int pp = 0; pp < 2; ++pp)
#pragma unroll
      for (int ni = 0; ni < 4; ++ni) {
        const int col = pp * 128 + wc + ni * 16 + cbase;
        *(ushort*)(Ts + row * 512 + col * 2) =
            f2bf((xnv[pp][ni][j] - mean) * rstd * lng[col] + lnb[col]);
      }
  }
  __syncthreads();
#pragma unroll
  for (int rr = 0; rr < 4; ++rr) {
    const int byte = rr * 4096 + t * 16;
    const int row = byte >> 9, off = byte & 511;
    const bf16x8_t v = *(const bf16x8_t*)(Ts + byte);
    *(bf16x8_t*)((char*)y + (m0 + row) * 512 + off) = v;
  }
}

// ========== gemm_ws v2 (head out-proj): barrier-free, MODE 3 relu ==========
template <int NP, int MODE>
__global__ __launch_bounds__(256)
void gemm_ws(const ushort* __restrict__ A, const ushort* __restrict__ Wks,
             const float* __restrict__ b1, ushort* __restrict__ outp) {
  constexpr int KS = 8;
  constexpr int N = NP * 128;
  constexpr int T = NP * KS;
  __shared__ __align__(16) char AsB[128 * 512];

  const int t = threadIdx.x, lane = t & 63, wid = t >> 6;
  const long m0 = (long)blockIdx.x * 128;
  const int wr = (wid >> 1) * 64, wc = (wid & 1) * 64;
  const char* Ab = (const char*)A;
  const char* Wb = (const char*)Wks;

  {
    const int arow = lane >> 5;
    const int aps  = lane & 31;
#pragma unroll
    for (int j = 0; j < 16; ++j) {
      const int r = j * 8 + wid * 2 + arow;
      gload_lds16(Ab + (m0 + r) * 512 + (long)((aps ^ (r & 7)) << 4),
                  AsB + (j * 8 + wid * 2) * 512);
    }
  }

  const int krow = lane & 15, kslot = lane >> 4;
  int abase[4], akey[4], boff[4];
#pragma unroll
  for (int i = 0; i < 4; ++i) {
    const int ar = wr + i * 16 + krow;
    abase[i] = ar * 512;
    akey[i] = ar & 7;
    const int br = wc + i * 16 + krow;
    boff[i] = br * 64 + ((kslot ^ ((br >> 1) & 3)) << 4);
  }

  const f32x4_t zero = {0.f, 0.f, 0.f, 0.f};
  f32x4_t acc[4][4];
#pragma unroll
  for (int i = 0; i < 4; ++i)
#pragma unroll
    for (int j = 0; j < 4; ++j) acc[i][j] = zero;

  const int rbase = (lane >> 4) * 4, cbase = lane & 15;

  __syncthreads();

  bf16x8_t bv[4];
#pragma unroll
  for (int i = 0; i < 4; ++i) bv[i] = *(const bf16x8_t*)(Wb + boff[i]);

  for (int tau = 0; tau < T; ++tau) {
    bf16x8_t bw[4];
    if (tau + 1 < T) {
      const char* src = Wb + (long)(tau + 1) * 8192;
#pragma unroll
      for (int i = 0; i < 4; ++i) bw[i] = *(const bf16x8_t*)(src + boff[i]);
    } else {
#pragma unroll
      for (int i = 0; i < 4; ++i) bw[i] = bv[i];
    }
    const int ks = tau & 7;
    bf16x8_t af[4];
#pragma unroll
    for (int i = 0; i < 4; ++i)
      af[i] = *(const bf16x8_t*)(AsB + abase[i] + ((((ks << 2) | kslot) ^ akey[i]) << 4));
    __builtin_amdgcn_s_setprio(1);
#pragma unroll
    for (int mi = 0; mi < 4; ++mi)
#pragma unroll
      for (int ni = 0; ni < 4; ++ni)
        acc[mi][ni] = __builtin_amdgcn_mfma_f32_16x16x32_bf16(af[mi], bv[ni], acc[mi][ni], 0, 0, 0);
    __builtin_amdgcn_s_setprio(0);
#pragma unroll
    for (int i = 0; i < 4; ++i) bv[i] = bw[i];

    if (ks == KS - 1) {
      const int np = tau >> 3;
#pragma unroll
      for (int mi = 0; mi < 4; ++mi) {
#pragma unroll
        for (int ni = 0; ni < 4; ++ni) {
          const int col = np * 128 + wc + ni * 16 + cbase;
#pragma unroll
          for (int j = 0; j < 4; ++j) {
            const long row = m0 + wr + mi * 16 + rbase + j;
            float s = acc[mi][ni][j] + b1[col];
            float o;
            if constexpr (MODE == 2) o = 0.5f * s * (1.f + erff(s * 0.70710678118654752f));
            else                     o = fmaxf(s, 0.f);
            outp[row * N + col] = f2bf(o);
          }
          acc[mi][ni] = zero;
        }
      }
    }
  }
}

// ========== input projection: N=256 GEMM (fp32 A fused convert) + LN ==========
template <int K, int MODE, bool AFP32>
__global__ __launch_bounds__(512)
void gemm_ln(const void* __restrict__ Ap, const ushort* __restrict__ W,
             const float* __restrict__ b1, ushort* __restrict__ xP,
             const float* __restrict__ lng, const float* __restrict__ lnb,
             ushort* __restrict__ y, int writex) {
  constexpr int KS = K / 32;
  __shared__ __align__(16) char WsB[2 * 16384];
  __shared__ __align__(16) char AsB[2 * 8192];
  __shared__ float lsum4[128][4], lsq4[128][4];

  const int t = threadIdx.x, lane = t & 63, wid = t >> 6;
  const int wr = (wid >> 2) * 64, wc = (wid & 3) * 64;
  const int lr = lane >> 2, lc = lane & 3;
  const int ra = wid * 16 + lr;
  const int slog = lc ^ swzkey(ra);
  const int saA = slog << 4;
  const int rw0 = wid * 32 + lr, rw1 = rw0 + 16;
  const int sw0 = (lc ^ swzkey(rw0)) << 4;
  const int sw1 = (lc ^ swzkey(rw1)) << 4;
  const char* Ab = (const char*)Ap;
  const char* Wb = (const char*)W;
  constexpr long K2 = (long)K * 2;
  const long m0 = (long)blockIdx.x * 128;

  auto stageA = [&](int tau2) {
    char* dst = AsB + (tau2 & 1) * 8192 + wid * 1024 + lane * 16;
    if constexpr (AFP32) {
      const float* src = (const float*)Ap + (m0 + ra) * K + tau2 * 32 + slog * 8;
      const float4 q0 = ((const float4*)src)[0];
      const float4 q1 = ((const float4*)src)[1];
      bf16x8_t v;
      v[0] = (short)f2bf(q0.x); v[1] = (short)f2bf(q0.y);
      v[2] = (short)f2bf(q0.z); v[3] = (short)f2bf(q0.w);
      v[4] = (short)f2bf(q1.x); v[5] = (short)f2bf(q1.y);
      v[6] = (short)f2bf(q1.z); v[7] = (short)f2bf(q1.w);
      *(bf16x8_t*)dst = v;
    } else {
      gload_lds16(Ab + (m0 + ra) * K2 + (long)tau2 * 64 + saA,
                  AsB + (tau2 & 1) * 8192 + wid * 1024);
    }
  };

  gload_lds16(Wb + (long)rw0 * K2 + sw0, WsB + wid * 2048);
  gload_lds16(Wb + (long)rw1 * K2 + sw1, WsB + wid * 2048 + 1024);
  stageA(0);

  const int krow = lane & 15, kslot = lane >> 4;
  int aoff[4], boff[4];
#pragma unroll
  for (int i = 0; i < 4; ++i) {
    int ar = wr + i * 16 + krow;
    aoff[i] = ar * 64 + ((kslot ^ swzkey(ar)) << 4);
    int br = wc + i * 16 + krow;
    boff[i] = br * 64 + ((kslot ^ swzkey(br)) << 4);
  }

  const f32x4_t zero = {0.f, 0.f, 0.f, 0.f};
  f32x4_t acc[4][4];
#pragma unroll
  for (int i = 0; i < 4; ++i)
#pragma unroll
    for (int j = 0; j < 4; ++j) acc[i][j] = zero;

  for (int tau = 0; tau < KS; ++tau) {
    __syncthreads();
    if (tau + 1 < KS) {
      stageA(tau + 1);
      const long kb = (long)(tau + 1) * 64;
      char* wd = WsB + ((tau + 1) & 1) * 16384 + wid * 2048;
      gload_lds16(Wb + (long)rw0 * K2 + kb + sw0, wd);
      gload_lds16(Wb + (long)rw1 * K2 + kb + sw1, wd + 1024);
    }
    const char* Ac = AsB + (tau & 1) * 8192;
    const char* Wc = WsB + (tau & 1) * 16384;
    bf16x8_t af[4], bv[4];
#pragma unroll
    for (int i = 0; i < 4; ++i) af[i] = *(const bf16x8_t*)(Ac + aoff[i]);
#pragma unroll
    for (int i = 0; i < 4; ++i) bv[i] = *(const bf16x8_t*)(Wc + boff[i]);
#pragma unroll
    for (int mi = 0; mi < 4; ++mi)
#pragma unroll
      for (int ni = 0; ni < 4; ++ni)
        acc[mi][ni] = __builtin_amdgcn_mfma_f32_16x16x32_bf16(af[mi], bv[ni], acc[mi][ni], 0, 0, 0);
  }

  const int rbase = (lane >> 4) * 4;
  const int cbase = lane & 15;
  const long xbB = (long)blockIdx.x * 32768;
#pragma unroll
  for (int mi = 0; mi < 4; ++mi) {
    const int rq = (wid >> 2) * 4 + mi;
#pragma unroll
    for (int ni = 0; ni < 4; ++ni) {
      const int col = wc + ni * 16 + cbase;
      const int cq = (wid & 3) * 4 + ni;
      ushort4 x4;
      if constexpr (MODE == 3) x4 = *(const ushort4*)(xP + xbB + ((rq * 16 + cq) * 64 + lane) * 4);
#pragma unroll
      for (int j = 0; j < 4; ++j) {
        float v = acc[mi][ni][j] + b1[col];
        if constexpr (MODE == 3)
          v += bf2f(j == 0 ? x4.x : (j == 1 ? x4.y : (j == 2 ? x4.z : x4.w)));
        acc[mi][ni][j] = v;
      }
    }
  }
#pragma unroll
  for (int mi = 0; mi < 4; ++mi) {
#pragma unroll
    for (int j = 0; j < 4; ++j) {
      float ps = 0.f, pq = 0.f;
#pragma unroll
      for (int ni = 0; ni < 4; ++ni) { float v = acc[mi][ni][j]; ps += v; pq += v * v; }
#pragma unroll
      for (int off = 1; off < 16; off <<= 1) {
        ps += __shfl_xor(ps, off, 64);
        pq += __shfl_xor(pq, off, 64);
      }
      if ((lane & 15) == 0) {
        int r = wr + mi * 16 + (lane >> 4) * 4 + j;
        lsum4[r][wid & 3] = ps;
        lsq4[r][wid & 3] = pq;
      }
    }
  }
  __syncthreads();
#pragma unroll
  for (int mi = 0; mi < 4; ++mi) {
    const int rq = (wid >> 2) * 4 + mi;
#pragma unroll
    for (int ni = 0; ni < 4; ++ni) {
      const int cq = (wid & 3) * 4 + ni;
      if (writex) {
        ushort4 o4;
        o4.x = f2bf(acc[mi][ni][0]);
        o4.y = f2bf(acc[mi][ni][1]);
        o4.z = f2bf(acc[mi][ni][2]);
        o4.w = f2bf(acc[mi][ni][3]);
        *(ushort4*)(xP + xbB + ((rq * 16 + cq) * 64 + lane) * 4) = o4;
      }
    }
  }
#pragma unroll
  for (int mi = 0; mi < 4; ++mi) {
#pragma unroll
    for (int j = 0; j < 4; ++j) {
      const int r = wr + mi * 16 + rbase + j;
      const float s = lsum4[r][0] + lsum4[r][1] + lsum4[r][2] + lsum4[r][3];
      const float q = lsq4[r][0] + lsq4[r][1] + lsq4[r][2] + lsq4[r][3];
      const float mean = s * (1.f / 256.f);
      const float rstd = rsqrtf(q * (1.f / 256.f) - mean * mean + 1e-5f);
      const long row = m0 + r;
#pragma unroll
      for (int ni = 0; ni < 4; ++ni) {
        const int col = wc + ni * 16 + cbase;
        y[row * 256 + col] = f2bf((acc[mi][ni][j] - mean) * rstd * lng[col] + lnb[col]);
      }
    }
  }
}

// ========== head_agg ==========
__global__ __launch_bounds__(256)
void head_agg(const ushort* __restrict__ y, const float* __restrict__ attw,
              ushort* __restrict__ vb) {
  const int t = threadIdx.x, lane = t & 63, w = t >> 6;
  const long b = (long)blockIdx.x * 4 + w;
  const ushort* yb = y + b * 16 * 256;
  const float4 w2 = *(const float4*)(attw + 256 + lane * 4);

  float4 rows[16];
  float lg[16];
#pragma unroll
  for (int r = 0; r < 16; ++r) {
    const ushort4 u = *(const ushort4*)(yb + r * 256 + lane * 4);
    float4 v4;
    v4.x = bf2f(u.x); v4.y = bf2f(u.y); v4.z = bf2f(u.z); v4.w = bf2f(u.w);
    rows[r] = v4;
    if (r >= 1) {
      float s = v4.x * w2.x + v4.y * w2.y + v4.z * w2.z + v4.w * w2.w;
#pragma unroll
      for (int off = 32; off > 0; off >>= 1) s += __shfl_xor(s, off, 64);
      lg[r] = s;
    }
  }
  float mx = -1e30f;
#pragma unroll
  for (int r = 1; r < 16; ++r) mx = fmaxf(mx, lg[r]);
  float den = 0.f;
#pragma unroll
  for (int r = 1; r < 16; ++r) { lg[r] = expf(lg[r] - mx); den += lg[r]; }
  const float inv = 1.f / den;
  float4 v = rows[0];
#pragma unroll
  for (int r = 1; r < 16; ++r) {
    const float a = lg[r] * inv;
    v.x += a * rows[r].x; v.y += a * rows[r].y;
    v.z += a * rows[r].z; v.w += a * rows[r].w;
  }
  ushort4 o;
  o.x = f2bf(v.x); o.y = f2bf(v.y); o.z = f2bf(v.z); o.w = f2bf(v.w);
  *(ushort4*)(vb + b * 256 + lane * 4) = o;
}

// ========== head_cls ==========
__global__ __launch_bounds__(256)
void head_cls(const ushort* __restrict__ o1b, const float* __restrict__ cw,
              const float* __restrict__ cb, float* __restrict__ out) {
  __shared__ float lw[4][40];
  const int t = threadIdx.x, lane = t & 63, w = t >> 6;
  const long b = (long)blockIdx.x * 4 + w;
  const ushort2 u = *(const ushort2*)(o1b + b * 128 + lane * 2);
  const float o1x = bf2f(u.x), o1y = bf2f(u.y);

#pragma unroll
  for (int o = 0; o < 40; ++o) {
    const float2 c = *(const float2*)(cw + o * 128 + lane * 2);
    float p = o1x * c.x + o1y * c.y;
#pragma unroll
    for (int off = 32; off > 0; off >>= 1) p += __shfl_xor(p, off, 64);
    if (lane == 0) lw[w][o] = p + cb[o];
  }
  const float v = (lane < 40) ? lw[w][lane] : -1e30f;
  float mx = v;
#pragma unroll
  for (int off = 32; off > 0; off >>= 1) mx = fmaxf(mx, __shfl_xor(mx, off, 64));
  float e = (lane < 40) ? expf(v - mx) : 0.f;
  float den = e;
#pragma unroll
  for (int off = 32; off > 0; off >>= 1) den += __shfl_xor(den, off, 64);
  if (lane < 40) out[b * 40 + lane] = v - mx - logf(den);
}

// ---------------- host ----------------
extern "C" void kernel_launch(void* const* d_in, const int* in_sizes, int n_in,
                              void* d_out, int out_size, void* d_ws, size_t ws_size,
                              hipStream_t stream) {
  const float* data   = (const float*)d_in[0];
  const float* in_w   = (const float*)d_in[1];
  const float* in_b   = (const float*)d_in[2];
  const float* norm_g = (const float*)d_in[3];
  const float* norm_b = (const float*)d_in[4];
  const float* A_w    = (const float*)d_in[5];
  const float* B_w    = (const float*)d_in[6];
  const float* C_w    = (const float*)d_in[7];
  const float* D_w    = (const float*)d_in[8];
  const float* D_b    = (const float*)d_in[9];
  const float* gate_w = (const float*)d_in[10];
  const float* gate_b = (const float*)d_in[11];
  const float* ffn_w1 = (const float*)d_in[12];
  const float* ffn_b1 = (const float*)d_in[13];
  const float* ffn_w2 = (const float*)d_in[14];
  const float* ffn_b2 = (const float*)d_in[15];
  const float* fln_g  = (const float*)d_in[16];
  const float* fln_b  = (const float*)d_in[17];
  const float* out_w  = (const float*)d_in[18];
  const float* out_b  = (const float*)d_in[19];
  const float* cls_w  = (const float*)d_in[20];
  const float* cls_b  = (const float*)d_in[21];
  const float* attn_w = (const float*)d_in[22];
  const float* attn_b = (const float*)d_in[23];
  (void)in_sizes; (void)n_in; (void)out_size; (void)ws_size; (void)attn_b;

  char* ws = (char*)d_ws;
  ushort* xP     = (ushort*)(ws + 0);           // packed x
  ushort* y      = (ushort*)(ws + 67108864);    // row-major y
  ushort* tzp    = (ushort*)(ws + 134217728);   // vb+o1b scratch
  ushort* wcat   = (ushort*)(ws + 318767104);
  ushort* inwb   = (ushort*)(ws + 320733184);
  ushort* w1b    = (ushort*)(ws + 320995328);
  ushort* w2b    = (ushort*)(ws + 322568192);
  ushort* cwb    = (ushort*)(ws + 324141056);
  ushort* mslice = (ushort*)(ws + 324337664);   // 6 x 44 slices
  ushort* w1k    = (ushort*)(ws + 326500352);   // 6*512*256 (k-sliced)
  ushort* owb    = (ushort*)(ws + 328073216);
  ushort* owk    = (ushort*)(ws + 328138752);
  ushort* w2k    = (ushort*)(ws + 328204288);   // 6*256*512 (k-sliced K=512)
  ushort* vb     = tzp;
  ushort* o1b    = tzp + 2097152;

  cvt_kernel<<<512, 256, 0, stream>>>(in_w, inwb, 131072);
  cvt_kernel<<<3072, 256, 0, stream>>>(ffn_w1, w1b, 786432);
  cvt_kernel<<<3072, 256, 0, stream>>>(ffn_w2, w2b, 786432);
  cvt_kernel<<<384, 256, 0, stream>>>(C_w, cwb, 98304);
  cvt_kernel<<<128, 256, 0, stream>>>(out_w, owb, 32768);
  build_wcat<<<3840, 256, 0, stream>>>(A_w, B_w, gate_w, D_w, wcat);
  repack_gen<<<3840, 256, 0, stream>>>(wcat, mslice, 256, 163840, 180224, 0, 6L * 163840);
  repack_gen<<<384, 256, 0, stream>>>(cwb, mslice, 64, 16384, 180224, 163840, 6L * 16384);
  repack_gen<<<3072, 256, 0, stream>>>(w1b, w1k, 256, 131072, 131072, 0, 6L * 131072);
  repack_gen<<<3072, 256, 0, stream>>>(w2b, w2k, 512, 131072, 131072, 0, 6L * 131072);
  repack_gen<<<128, 256, 0, stream>>>(owb, owk, 256, 32768, 32768, 0, 32768);

  // input proj (fp32 A, fused convert) + fused LN(layer0): xP (packed), y
  gemm_ln<512, 0, true><<<dim3(1024), 512, 0, stream>>>(
      data, inwb, in_b, xP, norm_g, norm_b, y, 1);

  for (int l = 0; l < 6; ++l) {
    mamba_fused<<<4096, 256, 0, stream>>>(
        y, xP, mslice + (size_t)l * 180224,
        gate_b + l * 256, D_b + l * 256, norm_g + l * 256, norm_b + l * 256);
    const float* lg2 = (l < 5) ? (norm_g + (l + 1) * 256) : fln_g;
    const float* lb2 = (l < 5) ? (norm_b + (l + 1) * 256) : fln_b;
    ffn_fused2<<<4096, 256, 0, stream>>>(
        y, xP, w1k + (size_t)l * 131072, w2k + (size_t)l * 131072,
        ffn_b1 + l * 512, ffn_b2 + l * 256, lg2, lb2, (l < 5) ? 1 : 0);
  }

  // head: attention-agg -> out-proj GEMM (relu) -> cls + log_softmax
  head_agg<<<2048, 256, 0, stream>>>(y, attn_w, vb);
  gemm_ws<1, 3><<<64, 256, 0, stream>>>(vb, owk, out_b, o1b);
  head_cls<<<2048, 256, 0, stream>>>(o1b, cls_w, cls_b, (float*)d_out);
}

// Round 21
// 1973.253 us; speedup vs baseline: 1.3147x; 1.0042x over previous
//
#include <hip/hip_runtime.h>

typedef __attribute__((ext_vector_type(8))) short bf16x8_t;
typedef __attribute__((ext_vector_type(4))) float f32x4_t;

__device__ __forceinline__ ushort f2bf(float x) {
  union { float f; unsigned u; } a; a.f = x;
  unsigned r = a.u + 0x7fffu + ((a.u >> 16) & 1u);
  return (ushort)(r >> 16);
}
__device__ __forceinline__ float bf2f(ushort s) {
  union { unsigned u; float f; } a; a.u = ((unsigned)s) << 16;
  return a.f;
}
__device__ __forceinline__ void gload_lds16(const void* g, void* l) {
  __builtin_amdgcn_global_load_lds(
      (const __attribute__((address_space(1))) unsigned int*)g,
      (__attribute__((address_space(3))) unsigned int*)l, 16, 0, 0);
}
__device__ __forceinline__ int swzkey(int r) { return ((r >> 2) ^ r) & 3; }

// ---------------- weight conversion ----------------
__global__ void cvt_kernel(const float* __restrict__ s, ushort* __restrict__ d, int n) {
  int i = blockIdx.x * 256 + threadIdx.x;
  if (i < n) d[i] = f2bf(s[i]);
}

// Wcat[l][r][c], r: 0-63 A_w, 64-127 B_w, 128-383 gate_w, 384-639 D_w
__global__ void build_wcat(const float* __restrict__ Aw, const float* __restrict__ Bw,
                           const float* __restrict__ gw, const float* __restrict__ Dw,
                           ushort* __restrict__ out) {
  int i = blockIdx.x * 256 + threadIdx.x;
  if (i >= 6 * 640 * 256) return;
  int l = i / (640 * 256), r = (i / 256) % 640, c = i % 256;
  float v;
  if (r < 64)        v = Aw[((l * 64 + r) * 256) + c];
  else if (r < 128)  v = Bw[((l * 64 + (r - 64)) * 256) + c];
  else if (r < 384)  v = gw[((l * 256 + (r - 128)) * 256) + c];
  else               v = Dw[((l * 256 + (r - 384)) * 256) + c];
  out[i] = f2bf(v);
}

// repack row-major [N][K] bf16 -> k-sliced [p][ks][r][s][e]; slice = 8KB contiguous.
__global__ void repack_gen(const ushort* __restrict__ src, ushort* __restrict__ dst,
                           int K, int perMat, int dstPerMat, int dstOff, long total) {
  const long i = (long)blockIdx.x * 256 + threadIdx.x;
  if (i >= total) return;
  const int m = (int)(i / perMat);
  const int idx = (int)(i % perMat);
  const int slice = idx >> 12;
  const int ksn = K >> 5;
  const int p = slice / ksn, ks = slice - p * ksn;
  const int r = (idx >> 5) & 127;
  const int s = (idx >> 3) & 3;
  const int e = idx & 7;
  const int k = ks * 32 + ((s ^ ((r >> 1) & 3)) << 3) + e;
  dst[(long)m * dstPerMat + dstOff + idx] = src[(long)m * perMat + (p * 128 + r) * K + k];
}

// ========== FUSED MAMBA LAYER v4 (R17-proven) ==========
__global__ __launch_bounds__(256, 3)
void mamba_fused(ushort* __restrict__ y, ushort* __restrict__ xP,
                 const ushort* __restrict__ Wk,
                 const float* __restrict__ gb, const float* __restrict__ db,
                 const float* __restrict__ lng, const float* __restrict__ lnb) {
  __shared__ __align__(16) char WsB[2 * 16384];
  __shared__ __align__(16) ushort ab[32 * 136];
  __shared__ __align__(16) char HsB[4096];
  __shared__ float lsum[32][2], lsq[32][2];

  const int t = threadIdx.x, lane = t & 63, wid = t >> 6;
  const long m0 = (long)blockIdx.x * 32;
  const int wr = (wid >> 1) * 16, wc = (wid & 1) * 64;
  const int co4 = wid * 4;
  const char* Wb = (const char*)Wk;

  const int krow = lane & 15, kslot = lane >> 4;
  const int ar = wr + krow;

  bf16x8_t afr[8];
  {
    const char* yrow = (const char*)y + (m0 + ar) * 512 + kslot * 16;
#pragma unroll
    for (int ks = 0; ks < 8; ++ks) afr[ks] = *(const bf16x8_t*)(yrow + ks * 64);
  }
#pragma unroll
  for (int c = 0; c < 4; ++c)
    gload_lds16(Wb + (co4 + c) * 1024 + lane * 16, WsB + (co4 + c) * 1024);

  int boff[4];
#pragma unroll
  for (int i = 0; i < 4; ++i) {
    const int br = wc + i * 16 + krow;
    boff[i] = br * 64 + ((kslot ^ ((br >> 1) & 3)) << 4);
  }
  const int rbase = (lane >> 4) * 4, cbase = lane & 15;

  const f32x4_t zero = {0.f, 0.f, 0.f, 0.f};
  f32x4_t acc[4];
#pragma unroll
  for (int i = 0; i < 4; ++i) acc[i] = zero;

  int pair = 0;
  auto kstep2 = [&](bf16x8_t afa, bf16x8_t afb) {
    __syncthreads();
    if (pair + 1 < 22) {
      const char* src = Wb + (long)(pair + 1) * 16384;
      char* dst = WsB + ((pair + 1) & 1) * 16384;
#pragma unroll
      for (int c = 0; c < 4; ++c)
        gload_lds16(src + (co4 + c) * 1024 + lane * 16, dst + (co4 + c) * 1024);
    }
    const char* Wc = WsB + (pair & 1) * 16384;
    bf16x8_t bva[4], bvb[4];
#pragma unroll
    for (int i = 0; i < 4; ++i) bva[i] = *(const bf16x8_t*)(Wc + boff[i]);
#pragma unroll
    for (int i = 0; i < 4; ++i) bvb[i] = *(const bf16x8_t*)(Wc + 8192 + boff[i]);
    __builtin_amdgcn_s_setprio(1);
#pragma unroll
    for (int ni = 0; ni < 4; ++ni)
      acc[ni] = __builtin_amdgcn_mfma_f32_16x16x32_bf16(afa, bva[ni], acc[ni], 0, 0, 0);
#pragma unroll
    for (int ni = 0; ni < 4; ++ni)
      acc[ni] = __builtin_amdgcn_mfma_f32_16x16x32_bf16(afb, bvb[ni], acc[ni], 0, 0, 0);
    __builtin_amdgcn_s_setprio(0);
    ++pair;
  };

#pragma unroll
  for (int p = 0; p < 4; ++p) kstep2(afr[2 * p], afr[2 * p + 1]);
#pragma unroll
  for (int ni = 0; ni < 4; ++ni) {
    const int col = wc + ni * 16 + cbase;
#pragma unroll
    for (int j = 0; j < 4; ++j) {
      const int row = wr + rbase + j;
      const float v = acc[ni][j];
      ab[row * 136 + col] = f2bf(col < 64 ? tanhf(v) : v);
    }
    acc[ni] = zero;
  }
  __syncthreads();
  if (t < 128) {
    const int b = t >> 6, d = t & 63;
    float av[16], btv[16];
#pragma unroll
    for (int s = 0; s < 16; ++s) {
      const int row = b * 16 + s;
      av[s]  = bf2f(ab[row * 136 + d]);
      btv[s] = bf2f(ab[row * 136 + 64 + d]);
    }
    float h = 0.f;
#pragma unroll
    for (int s = 0; s < 16; ++s) {
      h = fmaf(av[s], h, btv[s]);
      const int row = b * 16 + s;
      *(ushort*)(HsB + row * 128 + (((d >> 3) ^ (row & 7)) << 4) + (d & 7) * 2) = f2bf(h);
    }
  }

  f32x4_t gsv[2][4], dsv[2][4], xnv[2][4];
#pragma unroll
  for (int pp = 0; pp < 2; ++pp) {
#pragma unroll
    for (int p = 0; p < 4; ++p) kstep2(afr[2 * p], afr[2 * p + 1]);
#pragma unroll
    for (int ni = 0; ni < 4; ++ni) {
      const int col = pp * 128 + wc + ni * 16 + cbase;
#pragma unroll
      for (int j = 0; j < 4; ++j) {
        const float s = acc[ni][j] + gb[col];
        gsv[pp][ni][j] = 1.f / (1.f + expf(-s));
      }
      acc[ni] = zero;
    }
  }
#pragma unroll
  for (int pp = 0; pp < 2; ++pp) {
#pragma unroll
    for (int p = 0; p < 4; ++p) kstep2(afr[2 * p], afr[2 * p + 1]);
#pragma unroll
    for (int ni = 0; ni < 4; ++ni) {
      const int col = pp * 128 + wc + ni * 16 + cbase;
#pragma unroll
      for (int j = 0; j < 4; ++j) dsv[pp][ni][j] = acc[ni][j] + db[col];
      acc[ni] = zero;
    }
  }
  const long rq16 = (m0 >> 4) + (wr >> 4);
#pragma unroll
  for (int pp = 0; pp < 2; ++pp) {
    const bf16x8_t afh0 = *(const bf16x8_t*)(
        HsB + (ar << 7) + ((kslot ^ (ar & 7)) << 4));
    const bf16x8_t afh1 = *(const bf16x8_t*)(
        HsB + (ar << 7) + (((4 | kslot) ^ (ar & 7)) << 4));
    kstep2(afh0, afh1);
#pragma unroll
    for (int ni = 0; ni < 4; ++ni) {
      const int colq = pp * 8 + (wid & 1) * 4 + ni;
      const ushort4 x4 = *(const ushort4*)(xP + (rq16 * 16 + colq) * 256 + lane * 4);
#pragma unroll
      for (int j = 0; j < 4; ++j) {
        const float g = gsv[pp][ni][j], dv = dsv[pp][ni][j];
        const float xo = bf2f(j == 0 ? x4.x : (j == 1 ? x4.y : (j == 2 ? x4.z : x4.w)));
        xnv[pp][ni][j] = xo + acc[ni][j] * g + dv * (1.f - g);
      }
      acc[ni] = zero;
    }
  }
#pragma unroll
  for (int j = 0; j < 4; ++j) {
    float ps = 0.f, pq = 0.f;
#pragma unroll
    for (int pp = 0; pp < 2; ++pp)
#pragma unroll
      for (int ni = 0; ni < 4; ++ni) { const float v = xnv[pp][ni][j]; ps += v; pq += v * v; }
#pragma unroll
    for (int off = 1; off < 16; off <<= 1) {
      ps += __shfl_xor(ps, off, 64);
      pq += __shfl_xor(pq, off, 64);
    }
    if ((lane & 15) == 0) {
      const int row = wr + rbase + j;
      lsum[row][wid & 1] = ps;
      lsq[row][wid & 1] = pq;
    }
  }
  __syncthreads();
#pragma unroll
  for (int pp = 0; pp < 2; ++pp) {
#pragma unroll
    for (int ni = 0; ni < 4; ++ni) {
      const int colq = pp * 8 + (wid & 1) * 4 + ni;
      ushort4 o4;
      o4.x = f2bf(xnv[pp][ni][0]);
      o4.y = f2bf(xnv[pp][ni][1]);
      o4.z = f2bf(xnv[pp][ni][2]);
      o4.w = f2bf(xnv[pp][ni][3]);
      *(ushort4*)(xP + (rq16 * 16 + colq) * 256 + lane * 4) = o4;
    }
  }
#pragma unroll
  for (int j = 0; j < 4; ++j) {
    const int row = wr + rbase + j;
    const float sm = lsum[row][0] + lsum[row][1];
    const float q = lsq[row][0] + lsq[row][1];
    const float mean = sm * (1.f / 256.f);
    const float rstd = rsqrtf(q * (1.f / 256.f) - mean * mean + 1e-5f);
#pragma unroll
    for (int pp = 0; pp < 2; ++pp)
#pragma unroll
      for (int ni = 0; ni < 4; ++ni) {
        const int col = pp * 128 + wc + ni * 16 + cbase;
        *(ushort*)(WsB + row * 512 + col * 2) =
            f2bf((xnv[pp][ni][j] - mean) * rstd * lng[col] + lnb[col]);
      }
  }
  __syncthreads();
#pragma unroll
  for (int rr = 0; rr < 4; ++rr) {
    const int byte = rr * 4096 + t * 16;
    const int row = byte >> 9, off = byte & 511;
    const bf16x8_t v = *(const bf16x8_t*)(WsB + byte);
    *(bf16x8_t*)((char*)y + (m0 + row) * 512 + off) = v;
  }
}

// ========== FUSED FFN v3: ring-3 W register prefetch (distance 2); t in LDS ==========
__global__ __launch_bounds__(256, 3)
void ffn_fused2(ushort* __restrict__ y, ushort* __restrict__ xP,
                const ushort* __restrict__ W1k, const ushort* __restrict__ W2k,
                const float* __restrict__ b1, const float* __restrict__ b2,
                const float* __restrict__ lng, const float* __restrict__ lnb,
                int writex) {
  __shared__ __align__(16) char Ts[32768];
  __shared__ float lsum[32][2], lsq[32][2];

  const int t = threadIdx.x, lane = t & 63, wid = t >> 6;
  const long m0 = (long)blockIdx.x * 32;
  const int wr = (wid >> 1) * 16, wc = (wid & 1) * 64;
  const int krow = lane & 15, kslot = lane >> 4;
  const int ar = wr + krow;
  const int rbase = (lane >> 4) * 4, cbase = lane & 15;

  bf16x8_t afr[8];
  {
    const char* yrow = (const char*)y + (m0 + ar) * 512 + kslot * 16;
#pragma unroll
    for (int ks = 0; ks < 8; ++ks) afr[ks] = *(const bf16x8_t*)(yrow + ks * 64);
  }

  int boff[4];
#pragma unroll
  for (int i = 0; i < 4; ++i) {
    const int br = wc + i * 16 + krow;
    boff[i] = br * 64 + ((kslot ^ ((br >> 1) & 3)) << 4);
  }

  const f32x4_t zero = {0.f, 0.f, 0.f, 0.f};
  f32x4_t acc[4];
#pragma unroll
  for (int i = 0; i < 4; ++i) acc[i] = zero;

  // ---- ffn1: flat 32 slices, ring-3 W prefetch (distance 2) ----
  const char* W1 = (const char*)W1k;
  bf16x8_t bvr[3][4];
#pragma unroll
  for (int i = 0; i < 4; ++i) bvr[0][i] = *(const bf16x8_t*)(W1 + boff[i]);
#pragma unroll
  for (int i = 0; i < 4; ++i) bvr[1][i] = *(const bf16x8_t*)(W1 + 8192 + boff[i]);
#pragma unroll
  for (int sl = 0; sl < 32; ++sl) {
    if (sl + 2 < 32) {
      const char* src = W1 + (long)(sl + 2) * 8192;
#pragma unroll
      for (int i = 0; i < 4; ++i) bvr[(sl + 2) % 3][i] = *(const bf16x8_t*)(src + boff[i]);
    }
    const int ks = sl & 7;
    __builtin_amdgcn_s_setprio(1);
#pragma unroll
    for (int ni = 0; ni < 4; ++ni)
      acc[ni] = __builtin_amdgcn_mfma_f32_16x16x32_bf16(afr[ks], bvr[sl % 3][ni], acc[ni], 0, 0, 0);
    __builtin_amdgcn_s_setprio(0);
    if (ks == 7) {
      const int np = sl >> 3;
#pragma unroll
      for (int ni = 0; ni < 4; ++ni) {
        const int col = np * 128 + wc + ni * 16 + cbase;
        const int slog = col >> 3;
#pragma unroll
        for (int j = 0; j < 4; ++j) {
          const int row = wr + rbase + j;
          const float s = acc[ni][j] + b1[col];
          const float o = 0.5f * s * (1.f + erff(s * 0.70710678118654752f));
          *(ushort*)(Ts + row * 1024 + ((slog ^ (row & 7)) << 4) + (col & 7) * 2) = f2bf(o);
        }
        acc[ni] = zero;
      }
    }
  }
  __syncthreads();   // t tile complete

  // ---- ffn2: flat 32 slices (K=512), ring-3 W prefetch, A from Ts ----
  const char* W2 = (const char*)W2k;
  f32x4_t xnv[2][4];
  const long rq16 = (m0 >> 4) + (wr >> 4);
#pragma unroll
  for (int i = 0; i < 4; ++i) bvr[0][i] = *(const bf16x8_t*)(W2 + boff[i]);
#pragma unroll
  for (int i = 0; i < 4; ++i) bvr[1][i] = *(const bf16x8_t*)(W2 + 8192 + boff[i]);
#pragma unroll
  for (int sl = 0; sl < 32; ++sl) {
    if (sl + 2 < 32) {
      const char* src = W2 + (long)(sl + 2) * 8192;
#pragma unroll
      for (int i = 0; i < 4; ++i) bvr[(sl + 2) % 3][i] = *(const bf16x8_t*)(src + boff[i]);
    }
    const int ks = sl & 15;
    const bf16x8_t af = *(const bf16x8_t*)(
        Ts + ar * 1024 + (((ks * 4 + kslot) ^ (ar & 7)) << 4));
    __builtin_amdgcn_s_setprio(1);
#pragma unroll
    for (int ni = 0; ni < 4; ++ni)
      acc[ni] = __builtin_amdgcn_mfma_f32_16x16x32_bf16(af, bvr[sl % 3][ni], acc[ni], 0, 0, 0);
    __builtin_amdgcn_s_setprio(0);
    if (ks == 15) {
      const int pp = sl >> 4;
#pragma unroll
      for (int ni = 0; ni < 4; ++ni) {
        const int colq = pp * 8 + (wid & 1) * 4 + ni;
        const int col = pp * 128 + wc + ni * 16 + cbase;
        const ushort4 x4 = *(const ushort4*)(xP + (rq16 * 16 + colq) * 256 + lane * 4);
#pragma unroll
        for (int j = 0; j < 4; ++j) {
          const float xo = bf2f(j == 0 ? x4.x : (j == 1 ? x4.y : (j == 2 ? x4.z : x4.w)));
          xnv[pp][ni][j] = xo + acc[ni][j] + b2[col];
        }
        acc[ni] = zero;
      }
    }
  }
  // ---- LN stats ----
#pragma unroll
  for (int j = 0; j < 4; ++j) {
    float ps = 0.f, pq = 0.f;
#pragma unroll
    for (int pp = 0; pp < 2; ++pp)
#pragma unroll
      for (int ni = 0; ni < 4; ++ni) { const float v = xnv[pp][ni][j]; ps += v; pq += v * v; }
#pragma unroll
    for (int off = 1; off < 16; off <<= 1) {
      ps += __shfl_xor(ps, off, 64);
      pq += __shfl_xor(pq, off, 64);
    }
    if ((lane & 15) == 0) {
      const int row = wr + rbase + j;
      lsum[row][wid & 1] = ps;
      lsq[row][wid & 1] = pq;
    }
  }
  __syncthreads();
  if (writex) {
#pragma unroll
    for (int pp = 0; pp < 2; ++pp) {
#pragma unroll
      for (int ni = 0; ni < 4; ++ni) {
        const int colq = pp * 8 + (wid & 1) * 4 + ni;
        ushort4 o4;
        o4.x = f2bf(xnv[pp][ni][0]);
        o4.y = f2bf(xnv[pp][ni][1]);
        o4.z = f2bf(xnv[pp][ni][2]);
        o4.w = f2bf(xnv[pp][ni][3]);
        *(ushort4*)(xP + (rq16 * 16 + colq) * 256 + lane * 4) = o4;
      }
    }
  }
#pragma unroll
  for (int j = 0; j < 4; ++j) {
    const int row = wr + rbase + j;
    const float sm = lsum[row][0] + lsum[row][1];
    const float q = lsq[row][0] + lsq[row][1];
    const float mean = sm * (1.f / 256.f);
    const float rstd = rsqrtf(q * (1.f / 256.f) - mean * mean + 1e-5f);
#pragma unroll
    for (int pp = 0; pp < 2; ++pp)
#pragma unroll
      for (int ni = 0; ni < 4; ++ni) {
        const int col = pp * 128 + wc + ni * 16 + cbase;
        *(ushort*)(Ts + row * 512 + col * 2) =
            f2bf((xnv[pp][ni][j] - mean) * rstd * lng[col] + lnb[col]);
      }
  }
  __syncthreads();
#pragma unroll
  for (int rr = 0; rr < 4; ++rr) {
    const int byte = rr * 4096 + t * 16;
    const int row = byte >> 9, off = byte & 511;
    const bf16x8_t v = *(const bf16x8_t*)(Ts + byte);
    *(bf16x8_t*)((char*)y + (m0 + row) * 512 + off) = v;
  }
}

// ========== gemm_ws v2 (head out-proj): barrier-free, MODE 3 relu ==========
template <int NP, int MODE>
__global__ __launch_bounds__(256)
void gemm_ws(const ushort* __restrict__ A, const ushort* __restrict__ Wks,
             const float* __restrict__ b1, ushort* __restrict__ outp) {
  constexpr int KS = 8;
  constexpr int N = NP * 128;
  constexpr int T = NP * KS;
  __shared__ __align__(16) char AsB[128 * 512];

  const int t = threadIdx.x, lane = t & 63, wid = t >> 6;
  const long m0 = (long)blockIdx.x * 128;
  const int wr = (wid >> 1) * 64, wc = (wid & 1) * 64;
  const char* Ab = (const char*)A;
  const char* Wb = (const char*)Wks;

  {
    const int arow = lane >> 5;
    const int aps  = lane & 31;
#pragma unroll
    for (int j = 0; j < 16; ++j) {
      const int r = j * 8 + wid * 2 + arow;
      gload_lds16(Ab + (m0 + r) * 512 + (long)((aps ^ (r & 7)) << 4),
                  AsB + (j * 8 + wid * 2) * 512);
    }
  }

  const int krow = lane & 15, kslot = lane >> 4;
  int abase[4], akey[4], boff[4];
#pragma unroll
  for (int i = 0; i < 4; ++i) {
    const int ar = wr + i * 16 + krow;
    abase[i] = ar * 512;
    akey[i] = ar & 7;
    const int br = wc + i * 16 + krow;
    boff[i] = br * 64 + ((kslot ^ ((br >> 1) & 3)) << 4);
  }

  const f32x4_t zero = {0.f, 0.f, 0.f, 0.f};
  f32x4_t acc[4][4];
#pragma unroll
  for (int i = 0; i < 4; ++i)
#pragma unroll
    for (int j = 0; j < 4; ++j) acc[i][j] = zero;

  const int rbase = (lane >> 4) * 4, cbase = lane & 15;

  __syncthreads();

  bf16x8_t bv[4];
#pragma unroll
  for (int i = 0; i < 4; ++i) bv[i] = *(const bf16x8_t*)(Wb + boff[i]);

  for (int tau = 0; tau < T; ++tau) {
    bf16x8_t bw[4];
    if (tau + 1 < T) {
      const char* src = Wb + (long)(tau + 1) * 8192;
#pragma unroll
      for (int i = 0; i < 4; ++i) bw[i] = *(const bf16x8_t*)(src + boff[i]);
    } else {
#pragma unroll
      for (int i = 0; i < 4; ++i) bw[i] = bv[i];
    }
    const int ks = tau & 7;
    bf16x8_t af[4];
#pragma unroll
    for (int i = 0; i < 4; ++i)
      af[i] = *(const bf16x8_t*)(AsB + abase[i] + ((((ks << 2) | kslot) ^ akey[i]) << 4));
    __builtin_amdgcn_s_setprio(1);
#pragma unroll
    for (int mi = 0; mi < 4; ++mi)
#pragma unroll
      for (int ni = 0; ni < 4; ++ni)
        acc[mi][ni] = __builtin_amdgcn_mfma_f32_16x16x32_bf16(af[mi], bv[ni], acc[mi][ni], 0, 0, 0);
    __builtin_amdgcn_s_setprio(0);
#pragma unroll
    for (int i = 0; i < 4; ++i) bv[i] = bw[i];

    if (ks == KS - 1) {
      const int np = tau >> 3;
#pragma unroll
      for (int mi = 0; mi < 4; ++mi) {
#pragma unroll
        for (int ni = 0; ni < 4; ++ni) {
          const int col = np * 128 + wc + ni * 16 + cbase;
#pragma unroll
          for (int j = 0; j < 4; ++j) {
            const long row = m0 + wr + mi * 16 + rbase + j;
            float s = acc[mi][ni][j] + b1[col];
            float o;
            if constexpr (MODE == 2) o = 0.5f * s * (1.f + erff(s * 0.70710678118654752f));
            else                     o = fmaxf(s, 0.f);
            outp[row * N + col] = f2bf(o);
          }
          acc[mi][ni] = zero;
        }
      }
    }
  }
}

// ========== input projection: N=256 GEMM (fp32 A fused convert) + LN ==========
template <int K, int MODE, bool AFP32>
__global__ __launch_bounds__(512)
void gemm_ln(const void* __restrict__ Ap, const ushort* __restrict__ W,
             const float* __restrict__ b1, ushort* __restrict__ xP,
             const float* __restrict__ lng, const float* __restrict__ lnb,
             ushort* __restrict__ y, int writex) {
  constexpr int KS = K / 32;
  __shared__ __align__(16) char WsB[2 * 16384];
  __shared__ __align__(16) char AsB[2 * 8192];
  __shared__ float lsum4[128][4], lsq4[128][4];

  const int t = threadIdx.x, lane = t & 63, wid = t >> 6;
  const int wr = (wid >> 2) * 64, wc = (wid & 3) * 64;
  const int lr = lane >> 2, lc = lane & 3;
  const int ra = wid * 16 + lr;
  const int slog = lc ^ swzkey(ra);
  const int saA = slog << 4;
  const int rw0 = wid * 32 + lr, rw1 = rw0 + 16;
  const int sw0 = (lc ^ swzkey(rw0)) << 4;
  const int sw1 = (lc ^ swzkey(rw1)) << 4;
  const char* Ab = (const char*)Ap;
  const char* Wb = (const char*)W;
  constexpr long K2 = (long)K * 2;
  const long m0 = (long)blockIdx.x * 128;

  auto stageA = [&](int tau2) {
    char* dst = AsB + (tau2 & 1) * 8192 + wid * 1024 + lane * 16;
    if constexpr (AFP32) {
      const float* src = (const float*)Ap + (m0 + ra) * K + tau2 * 32 + slog * 8;
      const float4 q0 = ((const float4*)src)[0];
      const float4 q1 = ((const float4*)src)[1];
      bf16x8_t v;
      v[0] = (short)f2bf(q0.x); v[1] = (short)f2bf(q0.y);
      v[2] = (short)f2bf(q0.z); v[3] = (short)f2bf(q0.w);
      v[4] = (short)f2bf(q1.x); v[5] = (short)f2bf(q1.y);
      v[6] = (short)f2bf(q1.z); v[7] = (short)f2bf(q1.w);
      *(bf16x8_t*)dst = v;
    } else {
      gload_lds16(Ab + (m0 + ra) * K2 + (long)tau2 * 64 + saA,
                  AsB + (tau2 & 1) * 8192 + wid * 1024);
    }
  };

  gload_lds16(Wb + (long)rw0 * K2 + sw0, WsB + wid * 2048);
  gload_lds16(Wb + (long)rw1 * K2 + sw1, WsB + wid * 2048 + 1024);
  stageA(0);

  const int krow = lane & 15, kslot = lane >> 4;
  int aoff[4], boff[4];
#pragma unroll
  for (int i = 0; i < 4; ++i) {
    int ar = wr + i * 16 + krow;
    aoff[i] = ar * 64 + ((kslot ^ swzkey(ar)) << 4);
    int br = wc + i * 16 + krow;
    boff[i] = br * 64 + ((kslot ^ swzkey(br)) << 4);
  }

  const f32x4_t zero = {0.f, 0.f, 0.f, 0.f};
  f32x4_t acc[4][4];
#pragma unroll
  for (int i = 0; i < 4; ++i)
#pragma unroll
    for (int j = 0; j < 4; ++j) acc[i][j] = zero;

  for (int tau = 0; tau < KS; ++tau) {
    __syncthreads();
    if (tau + 1 < KS) {
      stageA(tau + 1);
      const long kb = (long)(tau + 1) * 64;
      char* wd = WsB + ((tau + 1) & 1) * 16384 + wid * 2048;
      gload_lds16(Wb + (long)rw0 * K2 + kb + sw0, wd);
      gload_lds16(Wb + (long)rw1 * K2 + kb + sw1, wd + 1024);
    }
    const char* Ac = AsB + (tau & 1) * 8192;
    const char* Wc = WsB + (tau & 1) * 16384;
    bf16x8_t af[4], bv[4];
#pragma unroll
    for (int i = 0; i < 4; ++i) af[i] = *(const bf16x8_t*)(Ac + aoff[i]);
#pragma unroll
    for (int i = 0; i < 4; ++i) bv[i] = *(const bf16x8_t*)(Wc + boff[i]);
#pragma unroll
    for (int mi = 0; mi < 4; ++mi)
#pragma unroll
      for (int ni = 0; ni < 4; ++ni)
        acc[mi][ni] = __builtin_amdgcn_mfma_f32_16x16x32_bf16(af[mi], bv[ni], acc[mi][ni], 0, 0, 0);
  }

  const int rbase = (lane >> 4) * 4;
  const int cbase = lane & 15;
  const long xbB = (long)blockIdx.x * 32768;
#pragma unroll
  for (int mi = 0; mi < 4; ++mi) {
    const int rq = (wid >> 2) * 4 + mi;
#pragma unroll
    for (int ni = 0; ni < 4; ++ni) {
      const int col = wc + ni * 16 + cbase;
      const int cq = (wid & 3) * 4 + ni;
      ushort4 x4;
      if constexpr (MODE == 3) x4 = *(const ushort4*)(xP + xbB + ((rq * 16 + cq) * 64 + lane) * 4);
#pragma unroll
      for (int j = 0; j < 4; ++j) {
        float v = acc[mi][ni][j] + b1[col];
        if constexpr (MODE == 3)
          v += bf2f(j == 0 ? x4.x : (j == 1 ? x4.y : (j == 2 ? x4.z : x4.w)));
        acc[mi][ni][j] = v;
      }
    }
  }
#pragma unroll
  for (int mi = 0; mi < 4; ++mi) {
#pragma unroll
    for (int j = 0; j < 4; ++j) {
      float ps = 0.f, pq = 0.f;
#pragma unroll
      for (int ni = 0; ni < 4; ++ni) { float v = acc[mi][ni][j]; ps += v; pq += v * v; }
#pragma unroll
      for (int off = 1; off < 16; off <<= 1) {
        ps += __shfl_xor(ps, off, 64);
        pq += __shfl_xor(pq, off, 64);
      }
      if ((lane & 15) == 0) {
        int r = wr + mi * 16 + (lane >> 4) * 4 + j;
        lsum4[r][wid & 3] = ps;
        lsq4[r][wid & 3] = pq;
      }
    }
  }
  __syncthreads();
#pragma unroll
  for (int mi = 0; mi < 4; ++mi) {
    const int rq = (wid >> 2) * 4 + mi;
#pragma unroll
    for (int ni = 0; ni < 4; ++ni) {
      const int cq = (wid & 3) * 4 + ni;
      if (writex) {
        ushort4 o4;
        o4.x = f2bf(acc[mi][ni][0]);
        o4.y = f2bf(acc[mi][ni][1]);
        o4.z = f2bf(acc[mi][ni][2]);
        o4.w = f2bf(acc[mi][ni][3]);
        *(ushort4*)(xP + xbB + ((rq * 16 + cq) * 64 + lane) * 4) = o4;
      }
    }
  }
#pragma unroll
  for (int mi = 0; mi < 4; ++mi) {
#pragma unroll
    for (int j = 0; j < 4; ++j) {
      const int r = wr + mi * 16 + rbase + j;
      const float s = lsum4[r][0] + lsum4[r][1] + lsum4[r][2] + lsum4[r][3];
      const float q = lsq4[r][0] + lsq4[r][1] + lsq4[r][2] + lsq4[r][3];
      const float mean = s * (1.f / 256.f);
      const float rstd = rsqrtf(q * (1.f / 256.f) - mean * mean + 1e-5f);
      const long row = m0 + r;
#pragma unroll
      for (int ni = 0; ni < 4; ++ni) {
        const int col = wc + ni * 16 + cbase;
        y[row * 256 + col] = f2bf((acc[mi][ni][j] - mean) * rstd * lng[col] + lnb[col]);
      }
    }
  }
}

// ========== head_agg ==========
__global__ __launch_bounds__(256)
void head_agg(const ushort* __restrict__ y, const float* __restrict__ attw,
              ushort* __restrict__ vb) {
  const int t = threadIdx.x, lane = t & 63, w = t >> 6;
  const long b = (long)blockIdx.x * 4 + w;
  const ushort* yb = y + b * 16 * 256;
  const float4 w2 = *(const float4*)(attw + 256 + lane * 4);

  float4 rows[16];
  float lg[16];
#pragma unroll
  for (int r = 0; r < 16; ++r) {
    const ushort4 u = *(const ushort4*)(yb + r * 256 + lane * 4);
    float4 v4;
    v4.x = bf2f(u.x); v4.y = bf2f(u.y); v4.z = bf2f(u.z); v4.w = bf2f(u.w);
    rows[r] = v4;
    if (r >= 1) {
      float s = v4.x * w2.x + v4.y * w2.y + v4.z * w2.z + v4.w * w2.w;
#pragma unroll
      for (int off = 32; off > 0; off >>= 1) s += __shfl_xor(s, off, 64);
      lg[r] = s;
    }
  }
  float mx = -1e30f;
#pragma unroll
  for (int r = 1; r < 16; ++r) mx = fmaxf(mx, lg[r]);
  float den = 0.f;
#pragma unroll
  for (int r = 1; r < 16; ++r) { lg[r] = expf(lg[r] - mx); den += lg[r]; }
  const float inv = 1.f / den;
  float4 v = rows[0];
#pragma unroll
  for (int r = 1; r < 16; ++r) {
    const float a = lg[r] * inv;
    v.x += a * rows[r].x; v.y += a * rows[r].y;
    v.z += a * rows[r].z; v.w += a * rows[r].w;
  }
  ushort4 o;
  o.x = f2bf(v.x); o.y = f2bf(v.y); o.z = f2bf(v.z); o.w = f2bf(v.w);
  *(ushort4*)(vb + b * 256 + lane * 4) = o;
}

// ========== head_cls ==========
__global__ __launch_bounds__(256)
void head_cls(const ushort* __restrict__ o1b, const float* __restrict__ cw,
              const float* __restrict__ cb, float* __restrict__ out) {
  __shared__ float lw[4][40];
  const int t = threadIdx.x, lane = t & 63, w = t >> 6;
  const long b = (long)blockIdx.x * 4 + w;
  const ushort2 u = *(const ushort2*)(o1b + b * 128 + lane * 2);
  const float o1x = bf2f(u.x), o1y = bf2f(u.y);

#pragma unroll
  for (int o = 0; o < 40; ++o) {
    const float2 c = *(const float2*)(cw + o * 128 + lane * 2);
    float p = o1x * c.x + o1y * c.y;
#pragma unroll
    for (int off = 32; off > 0; off >>= 1) p += __shfl_xor(p, off, 64);
    if (lane == 0) lw[w][o] = p + cb[o];
  }
  const float v = (lane < 40) ? lw[w][lane] : -1e30f;
  float mx = v;
#pragma unroll
  for (int off = 32; off > 0; off >>= 1) mx = fmaxf(mx, __shfl_xor(mx, off, 64));
  float e = (lane < 40) ? expf(v - mx) : 0.f;
  float den = e;
#pragma unroll
  for (int off = 32; off > 0; off >>= 1) den += __shfl_xor(den, off, 64);
  if (lane < 40) out[b * 40 + lane] = v - mx - logf(den);
}

// ---------------- host ----------------
extern "C" void kernel_launch(void* const* d_in, const int* in_sizes, int n_in,
                              void* d_out, int out_size, void* d_ws, size_t ws_size,
                              hipStream_t stream) {
  const float* data   = (const float*)d_in[0];
  const float* in_w   = (const float*)d_in[1];
  const float* in_b   = (const float*)d_in[2];
  const float* norm_g = (const float*)d_in[3];
  const float* norm_b = (const float*)d_in[4];
  const float* A_w    = (const float*)d_in[5];
  const float* B_w    = (const float*)d_in[6];
  const float* C_w    = (const float*)d_in[7];
  const float* D_w    = (const float*)d_in[8];
  const float* D_b    = (const float*)d_in[9];
  const float* gate_w = (const float*)d_in[10];
  const float* gate_b = (const float*)d_in[11];
  const float* ffn_w1 = (const float*)d_in[12];
  const float* ffn_b1 = (const float*)d_in[13];
  const float* ffn_w2 = (const float*)d_in[14];
  const float* ffn_b2 = (const float*)d_in[15];
  const float* fln_g  = (const float*)d_in[16];
  const float* fln_b  = (const float*)d_in[17];
  const float* out_w  = (const float*)d_in[18];
  const float* out_b  = (const float*)d_in[19];
  const float* cls_w  = (const float*)d_in[20];
  const float* cls_b  = (const float*)d_in[21];
  const float* attn_w = (const float*)d_in[22];
  const float* attn_b = (const float*)d_in[23];
  (void)in_sizes; (void)n_in; (void)out_size; (void)ws_size; (void)attn_b;

  char* ws = (char*)d_ws;
  ushort* xP     = (ushort*)(ws + 0);
  ushort* y      = (ushort*)(ws + 67108864);
  ushort* tzp    = (ushort*)(ws + 134217728);
  ushort* wcat   = (ushort*)(ws + 318767104);
  ushort* inwb   = (ushort*)(ws + 320733184);
  ushort* w1b    = (ushort*)(ws + 320995328);
  ushort* w2b    = (ushort*)(ws + 322568192);
  ushort* cwb    = (ushort*)(ws + 324141056);
  ushort* mslice = (ushort*)(ws + 324337664);
  ushort* w1k    = (ushort*)(ws + 326500352);
  ushort* owb    = (ushort*)(ws + 328073216);
  ushort* owk    = (ushort*)(ws + 328138752);
  ushort* w2k    = (ushort*)(ws + 328204288);
  ushort* vb     = tzp;
  ushort* o1b    = tzp + 2097152;

  cvt_kernel<<<512, 256, 0, stream>>>(in_w, inwb, 131072);
  cvt_kernel<<<3072, 256, 0, stream>>>(ffn_w1, w1b, 786432);
  cvt_kernel<<<3072, 256, 0, stream>>>(ffn_w2, w2b, 786432);
  cvt_kernel<<<384, 256, 0, stream>>>(C_w, cwb, 98304);
  cvt_kernel<<<128, 256, 0, stream>>>(out_w, owb, 32768);
  build_wcat<<<3840, 256, 0, stream>>>(A_w, B_w, gate_w, D_w, wcat);
  repack_gen<<<3840, 256, 0, stream>>>(wcat, mslice, 256, 163840, 180224, 0, 6L * 163840);
  repack_gen<<<384, 256, 0, stream>>>(cwb, mslice, 64, 16384, 180224, 163840, 6L * 16384);
  repack_gen<<<3072, 256, 0, stream>>>(w1b, w1k, 256, 131072, 131072, 0, 6L * 131072);
  repack_gen<<<3072, 256, 0, stream>>>(w2b, w2k, 512, 131072, 131072, 0, 6L * 131072);
  repack_gen<<<128, 256, 0, stream>>>(owb, owk, 256, 32768, 32768, 0, 32768);

  // input proj (fp32 A, fused convert) + fused LN(layer0): xP (packed), y
  gemm_ln<512, 0, true><<<dim3(1024), 512, 0, stream>>>(
      data, inwb, in_b, xP, norm_g, norm_b, y, 1);

  for (int l = 0; l < 6; ++l) {
    mamba_fused<<<4096, 256, 0, stream>>>(
        y, xP, mslice + (size_t)l * 180224,
        gate_b + l * 256, D_b + l * 256, norm_g + l * 256, norm_b + l * 256);
    const float* lg2 = (l < 5) ? (norm_g + (l + 1) * 256) : fln_g;
    const float* lb2 = (l < 5) ? (norm_b + (l + 1) * 256) : fln_b;
    ffn_fused2<<<4096, 256, 0, stream>>>(
        y, xP, w1k + (size_t)l * 131072, w2k + (size_t)l * 131072,
        ffn_b1 + l * 512, ffn_b2 + l * 256, lg2, lb2, (l < 5) ? 1 : 0);
  }

  // head: attention-agg -> out-proj GEMM (relu) -> cls + log_softmax
  head_agg<<<2048, 256, 0, stream>>>(y, attn_w, vb);
  gemm_ws<1, 3><<<64, 256, 0, stream>>>(vb, owk, out_b, o1b);
  head_cls<<<2048, 256, 0, stream>>>(o1b, cls_w, cls_b, (float*)d_out);
}